// Round 1
// baseline (932.528 us; speedup 1.0000x reference)
//
#include <hip/hip_runtime.h>

#define NNODE 50000
#define NEDGE 800000
#define DIM   128
#define HEADD 64
#define NEG   0.2f

__device__ __forceinline__ float wmax(float v){
  #pragma unroll
  for (int m = 32; m > 0; m >>= 1) v = fmaxf(v, __shfl_xor(v, m));
  return v;
}
__device__ __forceinline__ float wsum(float v){
  #pragma unroll
  for (int m = 32; m > 0; m >>= 1) v += __shfl_xor(v, m);
  return v;
}

// ---------------- CSR build ----------------
__global__ void hist_k(const int* __restrict__ dst, int* __restrict__ cnt){
  int e = blockIdx.x * 256 + threadIdx.x;
  if (e < NEDGE) atomicAdd(&cnt[dst[e]], 1);
}

// single block, 1024 threads; cnt may alias cur
__global__ __launch_bounds__(1024) void scan_k(const int* __restrict__ cnt,
                                               int* __restrict__ rp,
                                               int* __restrict__ cur){
  __shared__ int sd[1024];
  const int CH = (NNODE + 1023) / 1024;   // 49
  int t = threadIdx.x;
  int lo = t * CH, hi = min(lo + CH, NNODE);
  int s = 0;
  for (int i = lo; i < hi; ++i) s += cnt[i];
  sd[t] = s; __syncthreads();
  for (int off = 1; off < 1024; off <<= 1){
    int v = (t >= off) ? sd[t - off] : 0;
    __syncthreads();
    sd[t] += v;
    __syncthreads();
  }
  int run = sd[t] - s;                    // exclusive prefix
  for (int i = lo; i < hi; ++i){
    int d = cnt[i];                       // read BEFORE overwriting (cnt==cur)
    rp[i] = run; cur[i] = run;
    run += d;
  }
  if (t == 1023) rp[NNODE] = sd[1023];
}

__global__ void scatter_k(const int* __restrict__ ei, int* __restrict__ cur,
                          int* __restrict__ es){
  int e = blockIdx.x * 256 + threadIdx.x;
  if (e < NEDGE){
    int s = ei[e], d = ei[NEDGE + e];
    int p = atomicAdd(&cur[d], 1);
    es[p] = s;
  }
}

// ---------------- GEMM: out[N,BN] = X[N,128] @ W[128,BN] (+bias) ----------------
template<int BN, int TM>
__global__ __launch_bounds__(256) void gemm_k(const float* __restrict__ X,
                                              const float* __restrict__ W,
                                              const float* __restrict__ bias,
                                              float* __restrict__ out){
  const int TX  = BN / 8;          // threads across cols
  const int TY  = 256 / TX;
  const int BM  = TY * TM;         // rows per block
  const int STR = BM + 4;          // padded LDS stride
  __shared__ float xs[128 * STR];  // x tile, transposed [k][m]
  int tid = threadIdx.x;
  int bm0 = blockIdx.x * BM;

  const int NF4 = BM * 32 / 256;   // float4 loads per thread
  #pragma unroll
  for (int i = 0; i < NF4; ++i){
    int gi = i * 256 + tid;
    int r  = gi >> 5;              // tile row
    int c4 = gi & 31;              // float4 index within row
    int grow = bm0 + r;
    float4 v = make_float4(0.f, 0.f, 0.f, 0.f);
    if (grow < NNODE) v = ((const float4*)X)[grow * 32 + c4];
    int k = c4 * 4;
    xs[(k + 0) * STR + r] = v.x;
    xs[(k + 1) * STR + r] = v.y;
    xs[(k + 2) * STR + r] = v.z;
    xs[(k + 3) * STR + r] = v.w;
  }
  __syncthreads();

  int tx = tid % TX, ty = tid / TX;
  int n0 = tx * 8, m0 = ty * TM;
  float acc[TM][8];
  #pragma unroll
  for (int i = 0; i < TM; ++i)
    #pragma unroll
    for (int j = 0; j < 8; ++j) acc[i][j] = 0.f;

  const float4* W4 = (const float4*)W;
  for (int k = 0; k < 128; ++k){
    float av[TM];
    #pragma unroll
    for (int i = 0; i < TM; ++i) av[i] = xs[k * STR + m0 + i];
    float4 b0 = W4[k * (BN / 4) + tx * 2];
    float4 b1 = W4[k * (BN / 4) + tx * 2 + 1];
    float bv[8] = {b0.x, b0.y, b0.z, b0.w, b1.x, b1.y, b1.z, b1.w};
    #pragma unroll
    for (int i = 0; i < TM; ++i)
      #pragma unroll
      for (int j = 0; j < 8; ++j) acc[i][j] = fmaf(av[i], bv[j], acc[i][j]);
  }

  float bb[8];
  #pragma unroll
  for (int j = 0; j < 8; ++j) bb[j] = bias ? bias[n0 + j] : 0.f;
  #pragma unroll
  for (int i = 0; i < TM; ++i){
    int row = bm0 + m0 + i;
    if (row < NNODE){
      float4 o0 = make_float4(acc[i][0] + bb[0], acc[i][1] + bb[1],
                              acc[i][2] + bb[2], acc[i][3] + bb[3]);
      float4 o1 = make_float4(acc[i][4] + bb[4], acc[i][5] + bb[5],
                              acc[i][6] + bb[6], acc[i][7] + bb[7]);
      ((float4*)out)[row * (BN / 4) + tx * 2]     = o0;
      ((float4*)out)[row * (BN / 4) + tx * 2 + 1] = o1;
    }
  }
}

// ---------------- small matvec: v[i] = dot(W[i,:], a) ----------------
__global__ void matvec_k(const float* __restrict__ W, const float* __restrict__ a,
                         float* __restrict__ v){
  int lane = threadIdx.x & 63;
  int r = blockIdx.x * 4 + (threadIdx.x >> 6);
  if (r >= DIM) return;
  const float2* W2 = (const float2*)(W + r * DIM);
  const float2* a2 = (const float2*)a;
  float2 w = W2[lane], aa = a2[lane];
  float s = wsum(w.x * aa.x + w.y * aa.y);
  if (lane == 0) v[r] = s;
}

// ---------------- attention logits per node ----------------
__global__ __launch_bounds__(256) void al_k(const float* __restrict__ A,
                                            const float* __restrict__ asrc,
                                            const float* __restrict__ P,
                                            const float* __restrict__ q,
                                            float* __restrict__ als,
                                            float* __restrict__ ald){
  int lane = threadIdx.x & 63;
  int n = blockIdx.x * 4 + (threadIdx.x >> 6);
  if (n >= NNODE) return;
  const float2* A2 = (const float2*)(A + n * DIM);
  const float2* P2 = (const float2*)(P + n * DIM);
  const float2* s2 = (const float2*)asrc;
  const float2* q2 = (const float2*)q;
  float2 a = A2[lane], sa = s2[lane];
  float2 p = P2[lane], qq = q2[lane];
  float vs = wsum(a.x * sa.x + a.y * sa.y);
  float vd = wsum(p.x * qq.x + p.y * qq.y);
  if (lane == 0){ als[n] = vs; ald[n] = vd; }
}

// ---------------- GAT softmax-aggregate, one wave per dst node ----------------
__global__ __launch_bounds__(256) void gat_k(const int* __restrict__ rp,
                                             const int* __restrict__ es,
                                             const float* __restrict__ als,
                                             const float* __restrict__ ald,
                                             const float* __restrict__ A,
                                             const float* __restrict__ L,
                                             const float* __restrict__ bc,
                                             float* __restrict__ H, int relu){
  int lane = threadIdx.x & 63;
  int n = blockIdx.x * 4 + (threadIdx.x >> 6);
  if (n >= NNODE) return;
  int start = rp[n], end = rp[n + 1];
  float ad = ald[n];

  float mloc = -3.0e38f;
  for (int i = start + lane; i < end; i += 64){
    int s = es[i];
    float z = als[s] + ad;
    z = z > 0.f ? z : NEG * z;
    mloc = fmaxf(mloc, z);
  }
  float m = wmax(mloc);

  float dloc = 0.f;
  for (int i = start + lane; i < end; i += 64){
    int s = es[i];
    float z = als[s] + ad;
    z = z > 0.f ? z : NEG * z;
    dloc += __expf(z - m);
  }
  float denom = wsum(dloc);
  float rinv = (end > start) ? 1.f / denom : 0.f;

  float2 acc = make_float2(0.f, 0.f);
  const float2* A2 = (const float2*)A;
  for (int i = start; i < end; ++i){
    int s = es[i];
    float z = als[s] + ad;
    z = z > 0.f ? z : NEG * z;
    float w = __expf(z - m) * rinv;
    float2 v = A2[s * 64 + lane];
    acc.x = fmaf(w, v.x, acc.x);
    acc.y = fmaf(w, v.y, acc.y);
  }

  int c = lane * 2;
  float2 l2 = ((const float2*)(L + n * DIM))[lane];
  float ox = acc.x + l2.x + bc[c];
  float oy = acc.y + l2.y + bc[c + 1];
  if (relu){ ox = fmaxf(ox, 0.f); oy = fmaxf(oy, 0.f); }
  ((float2*)(H + n * DIM))[lane] = make_float2(ox, oy);
}

extern "C" void kernel_launch(void* const* d_in, const int* in_sizes, int n_in,
                              void* d_out, int out_size, void* d_ws, size_t ws_size,
                              hipStream_t stream){
  const float* x   = (const float*)d_in[0];
  const int*   ei  = (const int*)d_in[1];
  const float* w0s = (const float*)d_in[2];
  const float* w0d = (const float*)d_in[3];
  const float* a0s = (const float*)d_in[4];
  const float* a0d = (const float*)d_in[5];
  const float* bc0 = (const float*)d_in[6];
  const float* wl0 = (const float*)d_in[7];
  const float* bl0 = (const float*)d_in[8];
  const float* w1  = (const float*)d_in[9];
  const float* a1s = (const float*)d_in[10];
  const float* a1d = (const float*)d_in[11];
  const float* bc1 = (const float*)d_in[12];
  const float* wl1 = (const float*)d_in[13];
  const float* bl1 = (const float*)d_in[14];
  const float* w2  = (const float*)d_in[15];
  const float* a2s = (const float*)d_in[16];
  const float* a2d = (const float*)d_in[17];
  const float* bc2 = (const float*)d_in[18];
  const float* wl2 = (const float*)d_in[19];
  const float* bl2 = (const float*)d_in[20];
  const float* wh  = (const float*)d_in[21];
  const float* bh  = (const float*)d_in[22];
  float* out = (float*)d_out;

  float* H    = (float*)d_ws;
  float* A    = H + (size_t)NNODE * DIM;
  float* L    = A + (size_t)NNODE * DIM;
  float* als  = L + (size_t)NNODE * DIM;
  float* ald  = als + NNODE;
  float* vec0 = ald + NNODE;
  int*   rp   = (int*)(vec0 + DIM);
  int*   cur  = rp + (NNODE + 1);
  int*   es   = cur + NNODE;

  // ---- CSR by dst (per-launch; ws is re-poisoned every call) ----
  hipMemsetAsync(cur, 0, NNODE * sizeof(int), stream);
  hist_k<<<(NEDGE + 255) / 256, 256, 0, stream>>>(ei + NEDGE, cur);
  scan_k<<<1, 1024, 0, stream>>>(cur, rp, cur);
  scatter_k<<<(NEDGE + 255) / 256, 256, 0, stream>>>(ei, cur, es);

  dim3 b(256);
  dim3 g64((NNODE + 63) / 64);
  dim3 gn((NNODE + 3) / 4);

  // ---- layer 0 ----
  gemm_k<128, 4><<<g64, b, 0, stream>>>(x, w0s, nullptr, A);     // h_src
  gemm_k<128, 4><<<g64, b, 0, stream>>>(x, wl0, bl0, L);         // lin
  matvec_k<<<32, 256, 0, stream>>>(w0d, a0d, vec0);              // w0_dst @ a0_dst
  al_k<<<gn, b, 0, stream>>>(A, a0s, x, vec0, als, ald);
  gat_k<<<gn, b, 0, stream>>>(rp, es, als, ald, A, L, bc0, H, 1);

  // ---- layer 1 ----
  gemm_k<128, 4><<<g64, b, 0, stream>>>(H, w1, nullptr, A);      // hs
  gemm_k<128, 4><<<g64, b, 0, stream>>>(H, wl1, bl1, L);
  al_k<<<gn, b, 0, stream>>>(A, a1s, A, a1d, als, ald);
  gat_k<<<gn, b, 0, stream>>>(rp, es, als, ald, A, L, bc1, H, 1);

  // ---- layer 2 (no relu) ----
  gemm_k<128, 4><<<g64, b, 0, stream>>>(H, w2, nullptr, A);
  gemm_k<128, 4><<<g64, b, 0, stream>>>(H, wl2, bl2, L);
  al_k<<<gn, b, 0, stream>>>(A, a2s, A, a2d, als, ald);
  gat_k<<<gn, b, 0, stream>>>(rp, es, als, ald, A, L, bc2, H, 0);

  // ---- head ----
  gemm_k<64, 2><<<g64, b, 0, stream>>>(H, wh, bh, out);
}

// Round 2
// 831.333 us; speedup vs baseline: 1.1217x; 1.1217x over previous
//
#include <hip/hip_runtime.h>

#define NNODE 50000
#define NEDGE 800000
#define DIM   128
#define HEADD 64
#define NEG   0.2f
#define SCANB 256   // blocks in grid-scan; 256*256 = 65536 >= NNODE

__device__ __forceinline__ float wmax(float v){
  #pragma unroll
  for (int m = 32; m > 0; m >>= 1) v = fmaxf(v, __shfl_xor(v, m));
  return v;
}
__device__ __forceinline__ float wsum(float v){
  #pragma unroll
  for (int m = 32; m > 0; m >>= 1) v += __shfl_xor(v, m);
  return v;
}

// ---------------- CSR build ----------------
__global__ void hist_k(const int* __restrict__ dst, int* __restrict__ cnt){
  int e = blockIdx.x * 256 + threadIdx.x;
  if (e < NEDGE) atomicAdd(&cnt[dst[e]], 1);
}

// stage 1: per-block sums of cnt
__global__ __launch_bounds__(256) void partial_k(const int* __restrict__ cnt,
                                                 int* __restrict__ bsum){
  __shared__ int sd[256];
  int idx = blockIdx.x * 256 + threadIdx.x;
  int v = (idx < NNODE) ? cnt[idx] : 0;
  sd[threadIdx.x] = v; __syncthreads();
  #pragma unroll
  for (int off = 128; off > 0; off >>= 1){
    if (threadIdx.x < off) sd[threadIdx.x] += sd[threadIdx.x + off];
    __syncthreads();
  }
  if (threadIdx.x == 0) bsum[blockIdx.x] = sd[0];
}

// stage 2: single block scans the 256 block sums -> exclusive offsets
__global__ __launch_bounds__(256) void scanb_k(const int* __restrict__ bsum,
                                               int* __restrict__ boff,
                                               int* __restrict__ rp){
  __shared__ int sd[256];
  int t = threadIdx.x;
  int v = bsum[t];
  sd[t] = v; __syncthreads();
  #pragma unroll
  for (int off = 1; off < 256; off <<= 1){
    int u = (t >= off) ? sd[t - off] : 0;
    __syncthreads();
    sd[t] += u;
    __syncthreads();
  }
  boff[t] = sd[t] - v;                 // exclusive
  if (t == 255) rp[NNODE] = sd[255];   // total edge count
}

// stage 3: in-block exclusive scan + block offset -> rp, cur
__global__ __launch_bounds__(256) void emit_k(const int* __restrict__ cnt,
                                              const int* __restrict__ boff,
                                              int* __restrict__ rp,
                                              int* __restrict__ cur){
  __shared__ int sd[256];
  int t = threadIdx.x;
  int idx = blockIdx.x * 256 + t;
  int v = (idx < NNODE) ? cnt[idx] : 0;
  sd[t] = v; __syncthreads();
  #pragma unroll
  for (int off = 1; off < 256; off <<= 1){
    int u = (t >= off) ? sd[t - off] : 0;
    __syncthreads();
    sd[t] += u;
    __syncthreads();
  }
  if (idx < NNODE){
    int pos = boff[blockIdx.x] + sd[t] - v;
    rp[idx] = pos; cur[idx] = pos;
  }
}

__global__ void scatter_k(const int* __restrict__ ei, int* __restrict__ cur,
                          int* __restrict__ es){
  int e = blockIdx.x * 256 + threadIdx.x;
  if (e < NEDGE){
    int s = ei[e], d = ei[NEDGE + e];
    int p = atomicAdd(&cur[d], 1);
    es[p] = s;
  }
}

// ---------------- GEMM: out[N,BN] = X[N,128] @ W[128,BN] (+bias) ----------------
template<int BN, int TM>
__global__ __launch_bounds__(256) void gemm_k(const float* __restrict__ X,
                                              const float* __restrict__ W,
                                              const float* __restrict__ bias,
                                              float* __restrict__ out){
  const int TX  = BN / 8;          // threads across cols
  const int TY  = 256 / TX;
  const int BM  = TY * TM;         // rows per block
  const int STR = BM + 4;          // padded LDS stride
  __shared__ float xs[128 * STR];  // x tile, transposed [k][m]
  int tid = threadIdx.x;
  int bm0 = blockIdx.x * BM;

  const int NF4 = BM * 32 / 256;   // float4 loads per thread
  #pragma unroll
  for (int i = 0; i < NF4; ++i){
    int gi = i * 256 + tid;
    int r  = gi >> 5;              // tile row
    int c4 = gi & 31;              // float4 index within row
    int grow = bm0 + r;
    float4 v = make_float4(0.f, 0.f, 0.f, 0.f);
    if (grow < NNODE) v = ((const float4*)X)[grow * 32 + c4];
    int k = c4 * 4;
    xs[(k + 0) * STR + r] = v.x;
    xs[(k + 1) * STR + r] = v.y;
    xs[(k + 2) * STR + r] = v.z;
    xs[(k + 3) * STR + r] = v.w;
  }
  __syncthreads();

  int tx = tid % TX, ty = tid / TX;
  int n0 = tx * 8, m0 = ty * TM;
  float acc[TM][8];
  #pragma unroll
  for (int i = 0; i < TM; ++i)
    #pragma unroll
    for (int j = 0; j < 8; ++j) acc[i][j] = 0.f;

  const float4* W4 = (const float4*)W;
  for (int k = 0; k < 128; ++k){
    float av[TM];
    #pragma unroll
    for (int i = 0; i < TM; ++i) av[i] = xs[k * STR + m0 + i];
    float4 b0 = W4[k * (BN / 4) + tx * 2];
    float4 b1 = W4[k * (BN / 4) + tx * 2 + 1];
    float bv[8] = {b0.x, b0.y, b0.z, b0.w, b1.x, b1.y, b1.z, b1.w};
    #pragma unroll
    for (int i = 0; i < TM; ++i)
      #pragma unroll
      for (int j = 0; j < 8; ++j) acc[i][j] = fmaf(av[i], bv[j], acc[i][j]);
  }

  float bb[8];
  #pragma unroll
  for (int j = 0; j < 8; ++j) bb[j] = bias ? bias[n0 + j] : 0.f;
  #pragma unroll
  for (int i = 0; i < TM; ++i){
    int row = bm0 + m0 + i;
    if (row < NNODE){
      float4 o0 = make_float4(acc[i][0] + bb[0], acc[i][1] + bb[1],
                              acc[i][2] + bb[2], acc[i][3] + bb[3]);
      float4 o1 = make_float4(acc[i][4] + bb[4], acc[i][5] + bb[5],
                              acc[i][6] + bb[6], acc[i][7] + bb[7]);
      ((float4*)out)[row * (BN / 4) + tx * 2]     = o0;
      ((float4*)out)[row * (BN / 4) + tx * 2 + 1] = o1;
    }
  }
}

// ---------------- small matvec: v[i] = dot(W[i,:], a) ----------------
__global__ void matvec_k(const float* __restrict__ W, const float* __restrict__ a,
                         float* __restrict__ v){
  int lane = threadIdx.x & 63;
  int r = blockIdx.x * 4 + (threadIdx.x >> 6);
  if (r >= DIM) return;
  const float2* W2 = (const float2*)(W + r * DIM);
  const float2* a2 = (const float2*)a;
  float2 w = W2[lane], aa = a2[lane];
  float s = wsum(w.x * aa.x + w.y * aa.y);
  if (lane == 0) v[r] = s;
}

// ---------------- attention logits per node ----------------
__global__ __launch_bounds__(256) void al_k(const float* __restrict__ A,
                                            const float* __restrict__ asrc,
                                            const float* __restrict__ P,
                                            const float* __restrict__ q,
                                            float* __restrict__ als,
                                            float* __restrict__ ald){
  int lane = threadIdx.x & 63;
  int n = blockIdx.x * 4 + (threadIdx.x >> 6);
  if (n >= NNODE) return;
  const float2* A2 = (const float2*)(A + n * DIM);
  const float2* P2 = (const float2*)(P + n * DIM);
  const float2* s2 = (const float2*)asrc;
  const float2* q2 = (const float2*)q;
  float2 a = A2[lane], sa = s2[lane];
  float2 p = P2[lane], qq = q2[lane];
  float vs = wsum(a.x * sa.x + a.y * sa.y);
  float vd = wsum(p.x * qq.x + p.y * qq.y);
  if (lane == 0){ als[n] = vs; ald[n] = vd; }
}

// ---------------- GAT softmax-aggregate, one wave per dst node ----------------
__global__ __launch_bounds__(256) void gat_k(const int* __restrict__ rp,
                                             const int* __restrict__ es,
                                             const float* __restrict__ als,
                                             const float* __restrict__ ald,
                                             const float* __restrict__ A,
                                             const float* __restrict__ L,
                                             const float* __restrict__ bc,
                                             float* __restrict__ H, int relu){
  int lane = threadIdx.x & 63;
  int n = blockIdx.x * 4 + (threadIdx.x >> 6);
  if (n >= NNODE) return;
  int start = rp[n], end = rp[n + 1];
  float ad = ald[n];

  float mloc = -3.0e38f;
  for (int i = start + lane; i < end; i += 64){
    int s = es[i];
    float z = als[s] + ad;
    z = z > 0.f ? z : NEG * z;
    mloc = fmaxf(mloc, z);
  }
  float m = wmax(mloc);

  float dloc = 0.f;
  for (int i = start + lane; i < end; i += 64){
    int s = es[i];
    float z = als[s] + ad;
    z = z > 0.f ? z : NEG * z;
    dloc += __expf(z - m);
  }
  float denom = wsum(dloc);
  float rinv = (end > start) ? 1.f / denom : 0.f;

  float2 acc = make_float2(0.f, 0.f);
  const float2* A2 = (const float2*)A;
  for (int i = start; i < end; ++i){
    int s = es[i];
    float z = als[s] + ad;
    z = z > 0.f ? z : NEG * z;
    float w = __expf(z - m) * rinv;
    float2 v = A2[s * 64 + lane];
    acc.x = fmaf(w, v.x, acc.x);
    acc.y = fmaf(w, v.y, acc.y);
  }

  int c = lane * 2;
  float2 l2 = ((const float2*)(L + n * DIM))[lane];
  float ox = acc.x + l2.x + bc[c];
  float oy = acc.y + l2.y + bc[c + 1];
  if (relu){ ox = fmaxf(ox, 0.f); oy = fmaxf(oy, 0.f); }
  ((float2*)(H + n * DIM))[lane] = make_float2(ox, oy);
}

extern "C" void kernel_launch(void* const* d_in, const int* in_sizes, int n_in,
                              void* d_out, int out_size, void* d_ws, size_t ws_size,
                              hipStream_t stream){
  const float* x   = (const float*)d_in[0];
  const int*   ei  = (const int*)d_in[1];
  const float* w0s = (const float*)d_in[2];
  const float* w0d = (const float*)d_in[3];
  const float* a0s = (const float*)d_in[4];
  const float* a0d = (const float*)d_in[5];
  const float* bc0 = (const float*)d_in[6];
  const float* wl0 = (const float*)d_in[7];
  const float* bl0 = (const float*)d_in[8];
  const float* w1  = (const float*)d_in[9];
  const float* a1s = (const float*)d_in[10];
  const float* a1d = (const float*)d_in[11];
  const float* bc1 = (const float*)d_in[12];
  const float* wl1 = (const float*)d_in[13];
  const float* bl1 = (const float*)d_in[14];
  const float* w2  = (const float*)d_in[15];
  const float* a2s = (const float*)d_in[16];
  const float* a2d = (const float*)d_in[17];
  const float* bc2 = (const float*)d_in[18];
  const float* wl2 = (const float*)d_in[19];
  const float* bl2 = (const float*)d_in[20];
  const float* wh  = (const float*)d_in[21];
  const float* bh  = (const float*)d_in[22];
  float* out = (float*)d_out;

  float* H    = (float*)d_ws;
  float* A    = H + (size_t)NNODE * DIM;
  float* L    = A + (size_t)NNODE * DIM;
  float* als  = L + (size_t)NNODE * DIM;
  float* ald  = als + NNODE;
  float* vec0 = ald + NNODE;
  int*   rp   = (int*)(vec0 + DIM);
  int*   cur  = rp + (NNODE + 1);
  int*   cnt  = cur + NNODE;
  int*   bsum = cnt + NNODE;
  int*   boff = bsum + SCANB;
  int*   es   = boff + SCANB;

  // ---- CSR by dst (rebuilt every launch; ws is re-poisoned) ----
  hipMemsetAsync(cnt, 0, NNODE * sizeof(int), stream);
  hist_k<<<(NEDGE + 255) / 256, 256, 0, stream>>>(ei + NEDGE, cnt);
  partial_k<<<SCANB, 256, 0, stream>>>(cnt, bsum);
  scanb_k<<<1, 256, 0, stream>>>(bsum, boff, rp);
  emit_k<<<SCANB, 256, 0, stream>>>(cnt, boff, rp, cur);
  scatter_k<<<(NEDGE + 255) / 256, 256, 0, stream>>>(ei, cur, es);

  dim3 b(256);
  dim3 g64((NNODE + 63) / 64);
  dim3 gn((NNODE + 3) / 4);

  // ---- layer 0 ----
  gemm_k<128, 4><<<g64, b, 0, stream>>>(x, w0s, nullptr, A);     // h_src
  gemm_k<128, 4><<<g64, b, 0, stream>>>(x, wl0, bl0, L);         // lin
  matvec_k<<<32, 256, 0, stream>>>(w0d, a0d, vec0);              // w0_dst @ a0_dst
  al_k<<<gn, b, 0, stream>>>(A, a0s, x, vec0, als, ald);
  gat_k<<<gn, b, 0, stream>>>(rp, es, als, ald, A, L, bc0, H, 1);

  // ---- layer 1 ----
  gemm_k<128, 4><<<g64, b, 0, stream>>>(H, w1, nullptr, A);      // hs
  gemm_k<128, 4><<<g64, b, 0, stream>>>(H, wl1, bl1, L);
  al_k<<<gn, b, 0, stream>>>(A, a1s, A, a1d, als, ald);
  gat_k<<<gn, b, 0, stream>>>(rp, es, als, ald, A, L, bc1, H, 1);

  // ---- layer 2 (no relu) ----
  gemm_k<128, 4><<<g64, b, 0, stream>>>(H, w2, nullptr, A);
  gemm_k<128, 4><<<g64, b, 0, stream>>>(H, wl2, bl2, L);
  al_k<<<gn, b, 0, stream>>>(A, a2s, A, a2d, als, ald);
  gat_k<<<gn, b, 0, stream>>>(rp, es, als, ald, A, L, bc2, H, 0);

  // ---- head ----
  gemm_k<64, 2><<<g64, b, 0, stream>>>(H, wh, bh, out);
}

// Round 3
// 704.040 us; speedup vs baseline: 1.3245x; 1.1808x over previous
//
#include <hip/hip_runtime.h>

#define NNODE 50000
#define NEDGE 800000
#define DIM   128
#define HEADD 64
#define NEG   0.2f
#define SCANB 256   // blocks in grid-scan; 256*256 = 65536 >= NNODE

__device__ __forceinline__ float wmax(float v){
  #pragma unroll
  for (int m = 32; m > 0; m >>= 1) v = fmaxf(v, __shfl_xor(v, m));
  return v;
}
__device__ __forceinline__ float wsum(float v){
  #pragma unroll
  for (int m = 32; m > 0; m >>= 1) v += __shfl_xor(v, m);
  return v;
}

// ---------------- CSR build ----------------
__global__ void hist_k(const int* __restrict__ dst, int* __restrict__ cnt){
  int e = blockIdx.x * 256 + threadIdx.x;
  if (e < NEDGE) atomicAdd(&cnt[dst[e]], 1);
}

// stage 1: per-block sums of cnt
__global__ __launch_bounds__(256) void partial_k(const int* __restrict__ cnt,
                                                 int* __restrict__ bsum){
  __shared__ int sd[256];
  int idx = blockIdx.x * 256 + threadIdx.x;
  int v = (idx < NNODE) ? cnt[idx] : 0;
  sd[threadIdx.x] = v; __syncthreads();
  #pragma unroll
  for (int off = 128; off > 0; off >>= 1){
    if (threadIdx.x < off) sd[threadIdx.x] += sd[threadIdx.x + off];
    __syncthreads();
  }
  if (threadIdx.x == 0) bsum[blockIdx.x] = sd[0];
}

// stage 2: single block scans the 256 block sums -> exclusive offsets
__global__ __launch_bounds__(256) void scanb_k(const int* __restrict__ bsum,
                                               int* __restrict__ boff,
                                               int* __restrict__ rp){
  __shared__ int sd[256];
  int t = threadIdx.x;
  int v = bsum[t];
  sd[t] = v; __syncthreads();
  #pragma unroll
  for (int off = 1; off < 256; off <<= 1){
    int u = (t >= off) ? sd[t - off] : 0;
    __syncthreads();
    sd[t] += u;
    __syncthreads();
  }
  boff[t] = sd[t] - v;                 // exclusive
  if (t == 255) rp[NNODE] = sd[255];   // total edge count
}

// stage 3: in-block exclusive scan + block offset -> rp, cur
__global__ __launch_bounds__(256) void emit_k(const int* __restrict__ cnt,
                                              const int* __restrict__ boff,
                                              int* __restrict__ rp,
                                              int* __restrict__ cur){
  __shared__ int sd[256];
  int t = threadIdx.x;
  int idx = blockIdx.x * 256 + t;
  int v = (idx < NNODE) ? cnt[idx] : 0;
  sd[t] = v; __syncthreads();
  #pragma unroll
  for (int off = 1; off < 256; off <<= 1){
    int u = (t >= off) ? sd[t - off] : 0;
    __syncthreads();
    sd[t] += u;
    __syncthreads();
  }
  if (idx < NNODE){
    int pos = boff[blockIdx.x] + sd[t] - v;
    rp[idx] = pos; cur[idx] = pos;
  }
}

__global__ void scatter_k(const int* __restrict__ ei, int* __restrict__ cur,
                          int* __restrict__ es){
  int e = blockIdx.x * 256 + threadIdx.x;
  if (e < NEDGE){
    int s = ei[e], d = ei[NEDGE + e];
    int p = atomicAdd(&cur[d], 1);
    es[p] = s;
  }
}

// ---------------- GEMM: out[N,BN] = X[N,128] @ W[128,BN] (+bias) ----------------
template<int BN, int TM>
__global__ __launch_bounds__(256) void gemm_k(const float* __restrict__ X,
                                              const float* __restrict__ W,
                                              const float* __restrict__ bias,
                                              float* __restrict__ out){
  const int TX  = BN / 8;          // threads across cols
  const int TY  = 256 / TX;
  const int BM  = TY * TM;         // rows per block
  const int STR = BM + 4;          // padded LDS stride
  __shared__ float xs[128 * STR];  // x tile, transposed [k][m]
  int tid = threadIdx.x;
  int bm0 = blockIdx.x * BM;

  const int NF4 = BM * 32 / 256;   // float4 loads per thread
  #pragma unroll
  for (int i = 0; i < NF4; ++i){
    int gi = i * 256 + tid;
    int r  = gi >> 5;              // tile row
    int c4 = gi & 31;              // float4 index within row
    int grow = bm0 + r;
    float4 v = make_float4(0.f, 0.f, 0.f, 0.f);
    if (grow < NNODE) v = ((const float4*)X)[grow * 32 + c4];
    int k = c4 * 4;
    xs[(k + 0) * STR + r] = v.x;
    xs[(k + 1) * STR + r] = v.y;
    xs[(k + 2) * STR + r] = v.z;
    xs[(k + 3) * STR + r] = v.w;
  }
  __syncthreads();

  int tx = tid % TX, ty = tid / TX;
  int n0 = tx * 8, m0 = ty * TM;
  float acc[TM][8];
  #pragma unroll
  for (int i = 0; i < TM; ++i)
    #pragma unroll
    for (int j = 0; j < 8; ++j) acc[i][j] = 0.f;

  const float4* W4 = (const float4*)W;
  for (int k = 0; k < 128; ++k){
    float av[TM];
    #pragma unroll
    for (int i = 0; i < TM; ++i) av[i] = xs[k * STR + m0 + i];
    float4 b0 = W4[k * (BN / 4) + tx * 2];
    float4 b1 = W4[k * (BN / 4) + tx * 2 + 1];
    float bv[8] = {b0.x, b0.y, b0.z, b0.w, b1.x, b1.y, b1.z, b1.w};
    #pragma unroll
    for (int i = 0; i < TM; ++i)
      #pragma unroll
      for (int j = 0; j < 8; ++j) acc[i][j] = fmaf(av[i], bv[j], acc[i][j]);
  }

  float bb[8];
  #pragma unroll
  for (int j = 0; j < 8; ++j) bb[j] = bias ? bias[n0 + j] : 0.f;
  #pragma unroll
  for (int i = 0; i < TM; ++i){
    int row = bm0 + m0 + i;
    if (row < NNODE){
      float4 o0 = make_float4(acc[i][0] + bb[0], acc[i][1] + bb[1],
                              acc[i][2] + bb[2], acc[i][3] + bb[3]);
      float4 o1 = make_float4(acc[i][4] + bb[4], acc[i][5] + bb[5],
                              acc[i][6] + bb[6], acc[i][7] + bb[7]);
      ((float4*)out)[row * (BN / 4) + tx * 2]     = o0;
      ((float4*)out)[row * (BN / 4) + tx * 2 + 1] = o1;
    }
  }
}

// ---------------- small matvec: v[i] = dot(W[i,:], a) ----------------
__global__ void matvec_k(const float* __restrict__ W, const float* __restrict__ a,
                         float* __restrict__ v){
  int lane = threadIdx.x & 63;
  int r = blockIdx.x * 4 + (threadIdx.x >> 6);
  if (r >= DIM) return;
  const float2* W2 = (const float2*)(W + r * DIM);
  const float2* a2 = (const float2*)a;
  float2 w = W2[lane], aa = a2[lane];
  float s = wsum(w.x * aa.x + w.y * aa.y);
  if (lane == 0) v[r] = s;
}

// ---------------- attention logits per node ----------------
__global__ __launch_bounds__(256) void al_k(const float* __restrict__ A,
                                            const float* __restrict__ asrc,
                                            const float* __restrict__ P,
                                            const float* __restrict__ q,
                                            float* __restrict__ als,
                                            float* __restrict__ ald){
  int lane = threadIdx.x & 63;
  int n = blockIdx.x * 4 + (threadIdx.x >> 6);
  if (n >= NNODE) return;
  const float2* A2 = (const float2*)(A + n * DIM);
  const float2* P2 = (const float2*)(P + n * DIM);
  const float2* s2 = (const float2*)asrc;
  const float2* q2 = (const float2*)q;
  float2 a = A2[lane], sa = s2[lane];
  float2 p = P2[lane], qq = q2[lane];
  float vs = wsum(a.x * sa.x + a.y * sa.y);
  float vd = wsum(p.x * qq.x + p.y * qq.y);
  if (lane == 0){ als[n] = vs; ald[n] = vd; }
}

// ---------------- GAT softmax-aggregate, one wave per dst node ----------------
// Fast path (deg<=64): one edge per lane; logits computed ONCE; pass 3 pulls
// per-edge (s, e) from registers via shfl and keeps 4 row-loads in flight.
__global__ __launch_bounds__(256) void gat_k(const int* __restrict__ rp,
                                             const int* __restrict__ es,
                                             const float* __restrict__ als,
                                             const float* __restrict__ ald,
                                             const float* __restrict__ A,
                                             const float* __restrict__ L,
                                             const float* __restrict__ bc,
                                             float* __restrict__ H, int relu){
  int lane = threadIdx.x & 63;
  int n = blockIdx.x * 4 + (threadIdx.x >> 6);
  if (n >= NNODE) return;
  int start = rp[n], end = rp[n + 1];
  int deg = end - start;
  float ad = ald[n];
  const float2* A2 = (const float2*)A;
  float2 acc = make_float2(0.f, 0.f);
  float rinv = 0.f;

  if (deg <= 64){
    int s = 0; float z = -3.0e38f;
    if (lane < deg){
      s = es[start + lane];
      float t = als[s] + ad;
      z = t > 0.f ? t : NEG * t;
    }
    float m = wmax(z);
    float e = (lane < deg) ? __expf(z - m) : 0.f;  // 0 for pad lanes
    float denom = wsum(e);
    rinv = (deg > 0) ? 1.f / denom : 0.f;
    int dq = (deg + 3) & ~3;                       // pad loads hit row 0, w=0
    for (int j = 0; j < dq; j += 4){
      int   s0 = __shfl(s, j),     s1 = __shfl(s, j + 1);
      int   s2 = __shfl(s, j + 2), s3 = __shfl(s, j + 3);
      float w0 = __shfl(e, j),     w1 = __shfl(e, j + 1);
      float w2 = __shfl(e, j + 2), w3 = __shfl(e, j + 3);
      float2 v0 = A2[(size_t)s0 * 64 + lane];
      float2 v1 = A2[(size_t)s1 * 64 + lane];
      float2 v2 = A2[(size_t)s2 * 64 + lane];
      float2 v3 = A2[(size_t)s3 * 64 + lane];
      acc.x = fmaf(w0, v0.x, acc.x); acc.y = fmaf(w0, v0.y, acc.y);
      acc.x = fmaf(w1, v1.x, acc.x); acc.y = fmaf(w1, v1.y, acc.y);
      acc.x = fmaf(w2, v2.x, acc.x); acc.y = fmaf(w2, v2.y, acc.y);
      acc.x = fmaf(w3, v3.x, acc.x); acc.y = fmaf(w3, v3.y, acc.y);
    }
  } else {
    // slow path (deg > 64; ~never for Poisson(16) but required for correctness)
    float mloc = -3.0e38f;
    for (int i = start + lane; i < end; i += 64){
      int s = es[i];
      float zz = als[s] + ad;
      zz = zz > 0.f ? zz : NEG * zz;
      mloc = fmaxf(mloc, zz);
    }
    float m = wmax(mloc);
    float dloc = 0.f;
    for (int i = start + lane; i < end; i += 64){
      int s = es[i];
      float zz = als[s] + ad;
      zz = zz > 0.f ? zz : NEG * zz;
      dloc += __expf(zz - m);
    }
    rinv = 1.f / wsum(dloc);
    for (int i = start; i < end; ++i){
      int s = es[i];
      float zz = als[s] + ad;
      zz = zz > 0.f ? zz : NEG * zz;
      float w = __expf(zz - m);
      float2 v = A2[(size_t)s * 64 + lane];
      acc.x = fmaf(w, v.x, acc.x);
      acc.y = fmaf(w, v.y, acc.y);
    }
  }

  int c = lane * 2;
  float2 l2 = ((const float2*)(L + (size_t)n * DIM))[lane];
  float ox = fmaf(acc.x, rinv, l2.x + bc[c]);
  float oy = fmaf(acc.y, rinv, l2.y + bc[c + 1]);
  if (relu){ ox = fmaxf(ox, 0.f); oy = fmaxf(oy, 0.f); }
  ((float2*)(H + (size_t)n * DIM))[lane] = make_float2(ox, oy);
}

extern "C" void kernel_launch(void* const* d_in, const int* in_sizes, int n_in,
                              void* d_out, int out_size, void* d_ws, size_t ws_size,
                              hipStream_t stream){
  const float* x   = (const float*)d_in[0];
  const int*   ei  = (const int*)d_in[1];
  const float* w0s = (const float*)d_in[2];
  const float* w0d = (const float*)d_in[3];
  const float* a0s = (const float*)d_in[4];
  const float* a0d = (const float*)d_in[5];
  const float* bc0 = (const float*)d_in[6];
  const float* wl0 = (const float*)d_in[7];
  const float* bl0 = (const float*)d_in[8];
  const float* w1  = (const float*)d_in[9];
  const float* a1s = (const float*)d_in[10];
  const float* a1d = (const float*)d_in[11];
  const float* bc1 = (const float*)d_in[12];
  const float* wl1 = (const float*)d_in[13];
  const float* bl1 = (const float*)d_in[14];
  const float* w2  = (const float*)d_in[15];
  const float* a2s = (const float*)d_in[16];
  const float* a2d = (const float*)d_in[17];
  const float* bc2 = (const float*)d_in[18];
  const float* wl2 = (const float*)d_in[19];
  const float* bl2 = (const float*)d_in[20];
  const float* wh  = (const float*)d_in[21];
  const float* bh  = (const float*)d_in[22];
  float* out = (float*)d_out;

  float* H    = (float*)d_ws;
  float* A    = H + (size_t)NNODE * DIM;
  float* L    = A + (size_t)NNODE * DIM;
  float* als  = L + (size_t)NNODE * DIM;
  float* ald  = als + NNODE;
  float* vec0 = ald + NNODE;
  int*   rp   = (int*)(vec0 + DIM);
  int*   cur  = rp + (NNODE + 1);
  int*   cnt  = cur + NNODE;
  int*   bsum = cnt + NNODE;
  int*   boff = bsum + SCANB;
  int*   es   = boff + SCANB;

  // ---- CSR by dst (rebuilt every launch; ws is re-poisoned) ----
  hipMemsetAsync(cnt, 0, NNODE * sizeof(int), stream);
  hist_k<<<(NEDGE + 255) / 256, 256, 0, stream>>>(ei + NEDGE, cnt);
  partial_k<<<SCANB, 256, 0, stream>>>(cnt, bsum);
  scanb_k<<<1, 256, 0, stream>>>(bsum, boff, rp);
  emit_k<<<SCANB, 256, 0, stream>>>(cnt, boff, rp, cur);
  scatter_k<<<(NEDGE + 255) / 256, 256, 0, stream>>>(ei, cur, es);

  dim3 b(256);
  dim3 g64((NNODE + 63) / 64);
  dim3 gn((NNODE + 3) / 4);

  // ---- layer 0 ----
  gemm_k<128, 4><<<g64, b, 0, stream>>>(x, w0s, nullptr, A);     // h_src
  gemm_k<128, 4><<<g64, b, 0, stream>>>(x, wl0, bl0, L);         // lin
  matvec_k<<<32, 256, 0, stream>>>(w0d, a0d, vec0);              // w0_dst @ a0_dst
  al_k<<<gn, b, 0, stream>>>(A, a0s, x, vec0, als, ald);
  gat_k<<<gn, b, 0, stream>>>(rp, es, als, ald, A, L, bc0, H, 1);

  // ---- layer 1 ----
  gemm_k<128, 4><<<g64, b, 0, stream>>>(H, w1, nullptr, A);      // hs
  gemm_k<128, 4><<<g64, b, 0, stream>>>(H, wl1, bl1, L);
  al_k<<<gn, b, 0, stream>>>(A, a1s, A, a1d, als, ald);
  gat_k<<<gn, b, 0, stream>>>(rp, es, als, ald, A, L, bc1, H, 1);

  // ---- layer 2 (no relu) ----
  gemm_k<128, 4><<<g64, b, 0, stream>>>(H, w2, nullptr, A);
  gemm_k<128, 4><<<g64, b, 0, stream>>>(H, wl2, bl2, L);
  al_k<<<gn, b, 0, stream>>>(A, a2s, A, a2d, als, ald);
  gat_k<<<gn, b, 0, stream>>>(rp, es, als, ald, A, L, bc2, H, 0);

  // ---- head ----
  gemm_k<64, 2><<<g64, b, 0, stream>>>(H, wh, bh, out);
}

// Round 4
// 648.057 us; speedup vs baseline: 1.4390x; 1.0864x over previous
//
#include <hip/hip_runtime.h>

#define NNODE 50000
#define NEDGE 800000
#define DIM   128
#define HEADD 64
#define NEG   0.2f
#define SCANB 256   // blocks in grid-scan; 256*256 = 65536 >= NNODE

__device__ __forceinline__ float wmax(float v){
  #pragma unroll
  for (int m = 32; m > 0; m >>= 1) v = fmaxf(v, __shfl_xor(v, m));
  return v;
}
__device__ __forceinline__ float wsum(float v){
  #pragma unroll
  for (int m = 32; m > 0; m >>= 1) v += __shfl_xor(v, m);
  return v;
}
// fp32 -> bf16 bits, round-to-nearest-even (finite inputs)
__device__ __forceinline__ unsigned short f2bf(float f){
  unsigned int x = __float_as_uint(f);
  return (unsigned short)((x + 0x7fffu + ((x >> 16) & 1u)) >> 16);
}

// ---------------- CSR build ----------------
__global__ void hist_k(const int* __restrict__ dst, int* __restrict__ cnt){
  int e = blockIdx.x * 256 + threadIdx.x;
  if (e < NEDGE) atomicAdd(&cnt[dst[e]], 1);
}

__global__ __launch_bounds__(256) void partial_k(const int* __restrict__ cnt,
                                                 int* __restrict__ bsum){
  __shared__ int sd[256];
  int idx = blockIdx.x * 256 + threadIdx.x;
  int v = (idx < NNODE) ? cnt[idx] : 0;
  sd[threadIdx.x] = v; __syncthreads();
  #pragma unroll
  for (int off = 128; off > 0; off >>= 1){
    if (threadIdx.x < off) sd[threadIdx.x] += sd[threadIdx.x + off];
    __syncthreads();
  }
  if (threadIdx.x == 0) bsum[blockIdx.x] = sd[0];
}

__global__ __launch_bounds__(256) void scanb_k(const int* __restrict__ bsum,
                                               int* __restrict__ boff,
                                               int* __restrict__ rp){
  __shared__ int sd[256];
  int t = threadIdx.x;
  int v = bsum[t];
  sd[t] = v; __syncthreads();
  #pragma unroll
  for (int off = 1; off < 256; off <<= 1){
    int u = (t >= off) ? sd[t - off] : 0;
    __syncthreads();
    sd[t] += u;
    __syncthreads();
  }
  boff[t] = sd[t] - v;
  if (t == 255) rp[NNODE] = sd[255];
}

__global__ __launch_bounds__(256) void emit_k(const int* __restrict__ cnt,
                                              const int* __restrict__ boff,
                                              int* __restrict__ rp,
                                              int* __restrict__ cur){
  __shared__ int sd[256];
  int t = threadIdx.x;
  int idx = blockIdx.x * 256 + t;
  int v = (idx < NNODE) ? cnt[idx] : 0;
  sd[t] = v; __syncthreads();
  #pragma unroll
  for (int off = 1; off < 256; off <<= 1){
    int u = (t >= off) ? sd[t - off] : 0;
    __syncthreads();
    sd[t] += u;
    __syncthreads();
  }
  if (idx < NNODE){
    int pos = boff[blockIdx.x] + sd[t] - v;
    rp[idx] = pos; cur[idx] = pos;
  }
}

__global__ void scatter_k(const int* __restrict__ ei, int* __restrict__ cur,
                          int* __restrict__ es){
  int e = blockIdx.x * 256 + threadIdx.x;
  if (e < NEDGE){
    int s = ei[e], d = ei[NEDGE + e];
    int p = atomicAdd(&cur[d], 1);
    es[p] = s;
  }
}

// ------- GEMM: out[N,BN] = X[N,128] @ W[128,BN] (+bias); OUTBF -> bf16 out -------
template<int BN, int TM, int OUTBF>
__global__ __launch_bounds__(256) void gemm_k(const float* __restrict__ X,
                                              const float* __restrict__ W,
                                              const float* __restrict__ bias,
                                              void* __restrict__ outp){
  const int TX  = BN / 8;
  const int TY  = 256 / TX;
  const int BM  = TY * TM;
  const int STR = BM + 4;
  __shared__ float xs[128 * STR];
  int tid = threadIdx.x;
  int bm0 = blockIdx.x * BM;

  const int NF4 = BM * 32 / 256;
  #pragma unroll
  for (int i = 0; i < NF4; ++i){
    int gi = i * 256 + tid;
    int r  = gi >> 5;
    int c4 = gi & 31;
    int grow = bm0 + r;
    float4 v = make_float4(0.f, 0.f, 0.f, 0.f);
    if (grow < NNODE) v = ((const float4*)X)[grow * 32 + c4];
    int k = c4 * 4;
    xs[(k + 0) * STR + r] = v.x;
    xs[(k + 1) * STR + r] = v.y;
    xs[(k + 2) * STR + r] = v.z;
    xs[(k + 3) * STR + r] = v.w;
  }
  __syncthreads();

  int tx = tid % TX, ty = tid / TX;
  int n0 = tx * 8, m0 = ty * TM;
  float acc[TM][8];
  #pragma unroll
  for (int i = 0; i < TM; ++i)
    #pragma unroll
    for (int j = 0; j < 8; ++j) acc[i][j] = 0.f;

  const float4* W4 = (const float4*)W;
  for (int k = 0; k < 128; ++k){
    float av[TM];
    #pragma unroll
    for (int i = 0; i < TM; ++i) av[i] = xs[k * STR + m0 + i];
    float4 b0 = W4[k * (BN / 4) + tx * 2];
    float4 b1 = W4[k * (BN / 4) + tx * 2 + 1];
    float bv[8] = {b0.x, b0.y, b0.z, b0.w, b1.x, b1.y, b1.z, b1.w};
    #pragma unroll
    for (int i = 0; i < TM; ++i)
      #pragma unroll
      for (int j = 0; j < 8; ++j) acc[i][j] = fmaf(av[i], bv[j], acc[i][j]);
  }

  float bb[8];
  #pragma unroll
  for (int j = 0; j < 8; ++j) bb[j] = bias ? bias[n0 + j] : 0.f;
  #pragma unroll
  for (int i = 0; i < TM; ++i){
    int row = bm0 + m0 + i;
    if (row < NNODE){
      if (OUTBF){
        unsigned short us[8];
        #pragma unroll
        for (int j = 0; j < 8; ++j) us[j] = f2bf(acc[i][j] + bb[j]);
        uint4 pk;
        pk.x = (unsigned)us[0] | ((unsigned)us[1] << 16);
        pk.y = (unsigned)us[2] | ((unsigned)us[3] << 16);
        pk.z = (unsigned)us[4] | ((unsigned)us[5] << 16);
        pk.w = (unsigned)us[6] | ((unsigned)us[7] << 16);
        ((uint4*)outp)[row * (BN / 8) + tx] = pk;   // BN bf16 = BN/8 uint4
      } else {
        float4 o0 = make_float4(acc[i][0] + bb[0], acc[i][1] + bb[1],
                                acc[i][2] + bb[2], acc[i][3] + bb[3]);
        float4 o1 = make_float4(acc[i][4] + bb[4], acc[i][5] + bb[5],
                                acc[i][6] + bb[6], acc[i][7] + bb[7]);
        ((float4*)outp)[row * (BN / 4) + tx * 2]     = o0;
        ((float4*)outp)[row * (BN / 4) + tx * 2 + 1] = o1;
      }
    }
  }
}

// ------- batched matvec: u = Wa @ aa, v = Wb @ ab (u[r]=dot(Wa[r,:],aa)) -------
__global__ void mv2_k(const float* __restrict__ Wa, const float* __restrict__ aa,
                      const float* __restrict__ Wb, const float* __restrict__ ab,
                      float* __restrict__ u, float* __restrict__ v){
  int lane = threadIdx.x & 63;
  int r = blockIdx.x * 4 + (threadIdx.x >> 6);   // 0..255
  if (r >= 256) return;
  const float* W = (r < 128) ? Wa : Wb;
  const float* a = (r < 128) ? aa : ab;
  int rr = r & 127;
  float2 w = ((const float2*)(W + rr * DIM))[lane];
  float2 av = ((const float2*)a)[lane];
  float s = wsum(w.x * av.x + w.y * av.y);
  if (lane == 0){ if (r < 128) u[rr] = s; else v[rr] = s; }
}

// ------- dual matvec over rows: als[n]=dot(X[n],u), ald[n]=dot(X[n],v) -------
__global__ __launch_bounds__(256) void dualmv_k(const float* __restrict__ X,
                                                const float* __restrict__ u,
                                                const float* __restrict__ v,
                                                float* __restrict__ als,
                                                float* __restrict__ ald){
  int lane = threadIdx.x & 63;
  int n = blockIdx.x * 4 + (threadIdx.x >> 6);
  if (n >= NNODE) return;
  float2 xv = ((const float2*)(X + (size_t)n * DIM))[lane];
  float2 uu = ((const float2*)u)[lane];
  float2 vv = ((const float2*)v)[lane];
  float s1 = wsum(xv.x * uu.x + xv.y * uu.y);
  float s2 = wsum(xv.x * vv.x + xv.y * vv.y);
  if (lane == 0){ als[n] = s1; ald[n] = s2; }
}

// ---------------- GAT softmax-aggregate; A is bf16 [N,128] ----------------
__global__ __launch_bounds__(256) void gat_k(const int* __restrict__ rp,
                                             const int* __restrict__ es,
                                             const float* __restrict__ als,
                                             const float* __restrict__ ald,
                                             const unsigned int* __restrict__ A, // bf16x2 per uint
                                             const float* __restrict__ L,
                                             const float* __restrict__ bc,
                                             float* __restrict__ H, int relu){
  int lane = threadIdx.x & 63;
  int n = blockIdx.x * 4 + (threadIdx.x >> 6);
  if (n >= NNODE) return;
  int start = rp[n], end = rp[n + 1];
  int deg = end - start;
  float ad = ald[n];
  float2 acc = make_float2(0.f, 0.f);
  float rinv = 0.f;

  if (deg <= 64){
    int s = 0; float z = -3.0e38f;
    if (lane < deg){
      s = es[start + lane];
      float t = als[s] + ad;
      z = t > 0.f ? t : NEG * t;
    }
    float m = wmax(z);
    float e = (lane < deg) ? __expf(z - m) : 0.f;
    float denom = wsum(e);
    rinv = (deg > 0) ? 1.f / denom : 0.f;
    int dq = (deg + 3) & ~3;
    for (int j = 0; j < dq; j += 4){
      int   s0 = __shfl(s, j),     s1 = __shfl(s, j + 1);
      int   s2 = __shfl(s, j + 2), s3 = __shfl(s, j + 3);
      float w0 = __shfl(e, j),     w1 = __shfl(e, j + 1);
      float w2 = __shfl(e, j + 2), w3 = __shfl(e, j + 3);
      unsigned p0 = A[(size_t)s0 * 64 + lane];
      unsigned p1 = A[(size_t)s1 * 64 + lane];
      unsigned p2 = A[(size_t)s2 * 64 + lane];
      unsigned p3 = A[(size_t)s3 * 64 + lane];
      acc.x = fmaf(w0, __uint_as_float(p0 << 16), acc.x);
      acc.y = fmaf(w0, __uint_as_float(p0 & 0xffff0000u), acc.y);
      acc.x = fmaf(w1, __uint_as_float(p1 << 16), acc.x);
      acc.y = fmaf(w1, __uint_as_float(p1 & 0xffff0000u), acc.y);
      acc.x = fmaf(w2, __uint_as_float(p2 << 16), acc.x);
      acc.y = fmaf(w2, __uint_as_float(p2 & 0xffff0000u), acc.y);
      acc.x = fmaf(w3, __uint_as_float(p3 << 16), acc.x);
      acc.y = fmaf(w3, __uint_as_float(p3 & 0xffff0000u), acc.y);
    }
  } else {
    float mloc = -3.0e38f;
    for (int i = start + lane; i < end; i += 64){
      int s = es[i];
      float zz = als[s] + ad;
      zz = zz > 0.f ? zz : NEG * zz;
      mloc = fmaxf(mloc, zz);
    }
    float m = wmax(mloc);
    float dloc = 0.f;
    for (int i = start + lane; i < end; i += 64){
      int s = es[i];
      float zz = als[s] + ad;
      zz = zz > 0.f ? zz : NEG * zz;
      dloc += __expf(zz - m);
    }
    rinv = 1.f / wsum(dloc);
    for (int i = start; i < end; ++i){
      int s = es[i];
      float zz = als[s] + ad;
      zz = zz > 0.f ? zz : NEG * zz;
      float w = __expf(zz - m);
      unsigned p = A[(size_t)s * 64 + lane];
      acc.x = fmaf(w, __uint_as_float(p << 16), acc.x);
      acc.y = fmaf(w, __uint_as_float(p & 0xffff0000u), acc.y);
    }
  }

  int c = lane * 2;
  float2 l2 = ((const float2*)(L + (size_t)n * DIM))[lane];
  float ox = fmaf(acc.x, rinv, l2.x + bc[c]);
  float oy = fmaf(acc.y, rinv, l2.y + bc[c + 1]);
  if (relu){ ox = fmaxf(ox, 0.f); oy = fmaxf(oy, 0.f); }
  ((float2*)(H + (size_t)n * DIM))[lane] = make_float2(ox, oy);
}

extern "C" void kernel_launch(void* const* d_in, const int* in_sizes, int n_in,
                              void* d_out, int out_size, void* d_ws, size_t ws_size,
                              hipStream_t stream){
  const float* x   = (const float*)d_in[0];
  const int*   ei  = (const int*)d_in[1];
  const float* w0s = (const float*)d_in[2];
  const float* w0d = (const float*)d_in[3];
  const float* a0s = (const float*)d_in[4];
  const float* a0d = (const float*)d_in[5];
  const float* bc0 = (const float*)d_in[6];
  const float* wl0 = (const float*)d_in[7];
  const float* bl0 = (const float*)d_in[8];
  const float* w1  = (const float*)d_in[9];
  const float* a1s = (const float*)d_in[10];
  const float* a1d = (const float*)d_in[11];
  const float* bc1 = (const float*)d_in[12];
  const float* wl1 = (const float*)d_in[13];
  const float* bl1 = (const float*)d_in[14];
  const float* w2  = (const float*)d_in[15];
  const float* a2s = (const float*)d_in[16];
  const float* a2d = (const float*)d_in[17];
  const float* bc2 = (const float*)d_in[18];
  const float* wl2 = (const float*)d_in[19];
  const float* bl2 = (const float*)d_in[20];
  const float* wh  = (const float*)d_in[21];
  const float* bh  = (const float*)d_in[22];
  float* out = (float*)d_out;

  float* H    = (float*)d_ws;                       // [N,128] f32
  unsigned int* A = (unsigned int*)(H + (size_t)NNODE * DIM);  // [N,128] bf16 = N*64 uints
  float* L    = (float*)(A + (size_t)NNODE * 64);   // [N,128] f32
  float* als  = L + (size_t)NNODE * DIM;
  float* ald  = als + NNODE;
  float* u    = ald + NNODE;
  float* v    = u + DIM;
  int*   rp   = (int*)(v + DIM);
  int*   cur  = rp + (NNODE + 1);
  int*   cnt  = cur + NNODE;
  int*   bsum = cnt + NNODE;
  int*   boff = bsum + SCANB;
  int*   es   = boff + SCANB;

  // ---- CSR by dst (rebuilt every launch; ws is re-poisoned) ----
  hipMemsetAsync(cnt, 0, NNODE * sizeof(int), stream);
  hist_k<<<(NEDGE + 255) / 256, 256, 0, stream>>>(ei + NEDGE, cnt);
  partial_k<<<SCANB, 256, 0, stream>>>(cnt, bsum);
  scanb_k<<<1, 256, 0, stream>>>(bsum, boff, rp);
  emit_k<<<SCANB, 256, 0, stream>>>(cnt, boff, rp, cur);
  scatter_k<<<(NEDGE + 255) / 256, 256, 0, stream>>>(ei, cur, es);

  dim3 b(256);
  dim3 g64((NNODE + 63) / 64);
  dim3 gn((NNODE + 3) / 4);

  // ---- layer 0 ----
  gemm_k<128, 4, 1><<<g64, b, 0, stream>>>(x, w0s, nullptr, A);   // h_src (bf16)
  gemm_k<128, 4, 0><<<g64, b, 0, stream>>>(x, wl0, bl0, L);       // lin
  mv2_k<<<64, 256, 0, stream>>>(w0s, a0s, w0d, a0d, u, v);        // u=w0s@a0s, v=w0d@a0d
  dualmv_k<<<gn, b, 0, stream>>>(x, u, v, als, ald);              // logits (fp32-exact)
  gat_k<<<gn, b, 0, stream>>>(rp, es, als, ald, A, L, bc0, H, 1);

  // ---- layer 1 ----
  gemm_k<128, 4, 1><<<g64, b, 0, stream>>>(H, w1, nullptr, A);
  gemm_k<128, 4, 0><<<g64, b, 0, stream>>>(H, wl1, bl1, L);
  mv2_k<<<64, 256, 0, stream>>>(w1, a1s, w1, a1d, u, v);
  dualmv_k<<<gn, b, 0, stream>>>(H, u, v, als, ald);
  gat_k<<<gn, b, 0, stream>>>(rp, es, als, ald, A, L, bc1, H, 1);

  // ---- layer 2 (no relu) ----
  gemm_k<128, 4, 1><<<g64, b, 0, stream>>>(H, w2, nullptr, A);
  gemm_k<128, 4, 0><<<g64, b, 0, stream>>>(H, wl2, bl2, L);
  mv2_k<<<64, 256, 0, stream>>>(w2, a2s, w2, a2d, u, v);
  dualmv_k<<<gn, b, 0, stream>>>(H, u, v, als, ald);
  gat_k<<<gn, b, 0, stream>>>(rp, es, als, ald, A, L, bc2, H, 0);

  // ---- head ----
  gemm_k<64, 2, 0><<<g64, b, 0, stream>>>(H, wh, bh, out);
}

// Round 5
// 599.995 us; speedup vs baseline: 1.5542x; 1.0801x over previous
//
#include <hip/hip_runtime.h>

#define NNODE 50000
#define NEDGE 800000
#define DIM   128
#define HEADD 64
#define NEG   0.2f
#define NBUCK 196          // dst>>8 buckets (49999>>8 = 195)
#define EPB1  2048         // edges per block in pass-1 kernels
#define NB1   391          // ceil(NEDGE/EPB1)

__device__ __forceinline__ float wmax(float v){
  #pragma unroll
  for (int m = 32; m > 0; m >>= 1) v = fmaxf(v, __shfl_xor(v, m));
  return v;
}
__device__ __forceinline__ float wsum(float v){
  #pragma unroll
  for (int m = 32; m > 0; m >>= 1) v += __shfl_xor(v, m);
  return v;
}
// fp32 -> bf16 bits, round-to-nearest-even (finite inputs)
__device__ __forceinline__ unsigned short f2bf(float f){
  unsigned int x = __float_as_uint(f);
  return (unsigned short)((x + 0x7fffu + ((x >> 16) & 1u)) >> 16);
}

// ---------------- CSR build: 2-level bucket sort ----------------
// pass 1a: coarse histogram (196 buckets)
__global__ __launch_bounds__(256) void bhist_k(const int* __restrict__ dst,
                                               int* __restrict__ gcount){
  __shared__ int h[NBUCK];
  for (int i = threadIdx.x; i < NBUCK; i += 256) h[i] = 0;
  __syncthreads();
  int e0 = blockIdx.x * EPB1 + threadIdx.x;
  #pragma unroll
  for (int i = 0; i < 8; ++i){
    int e = e0 + i * 256;
    if (e < NEDGE) atomicAdd(&h[dst[e] >> 8], 1);
  }
  __syncthreads();
  for (int i = threadIdx.x; i < NBUCK; i += 256)
    if (h[i]) atomicAdd(&gcount[i], h[i]);
}

// pass 1b: scan 196 counts -> gbase (exclusive), gcur copy; rp[NNODE]=NEDGE
__global__ __launch_bounds__(256) void bscan_k(const int* __restrict__ gcount,
                                               int* __restrict__ gbase,
                                               int* __restrict__ gcur,
                                               int* __restrict__ rp){
  __shared__ int sd[256];
  int t = threadIdx.x;
  int v = (t < NBUCK) ? gcount[t] : 0;
  sd[t] = v; __syncthreads();
  #pragma unroll
  for (int off = 1; off < 256; off <<= 1){
    int u = (t >= off) ? sd[t - off] : 0;
    __syncthreads();
    sd[t] += u;
    __syncthreads();
  }
  int ex = sd[t] - v;
  if (t < NBUCK){ gbase[t] = ex; gcur[t] = ex; }
  if (t == NBUCK - 1) gbase[NBUCK] = sd[t];
  if (t == 0) rp[NNODE] = NEDGE;
}

// pass 1c: scatter packed (dst<<16|src) into bucket regions, block-claimed runs
__global__ __launch_bounds__(256) void bucket_k(const int* __restrict__ ei,
                                                int* __restrict__ gcur,
                                                unsigned int* __restrict__ packed){
  __shared__ int lh[NBUCK], lbase[NBUCK], lcur[NBUCK];
  for (int i = threadIdx.x; i < NBUCK; i += 256) lh[i] = 0;
  __syncthreads();
  unsigned int pk[8]; int bk[8];
  int e0 = blockIdx.x * EPB1 + threadIdx.x;
  #pragma unroll
  for (int i = 0; i < 8; ++i){
    int e = e0 + i * 256;
    bk[i] = -1;
    if (e < NEDGE){
      int s = ei[e], d = ei[NEDGE + e];
      pk[i] = ((unsigned)d << 16) | (unsigned)s;
      bk[i] = d >> 8;
      atomicAdd(&lh[bk[i]], 1);
    }
  }
  __syncthreads();
  for (int i = threadIdx.x; i < NBUCK; i += 256){
    lbase[i] = atomicAdd(&gcur[i], lh[i]);
    lcur[i] = 0;
  }
  __syncthreads();
  #pragma unroll
  for (int i = 0; i < 8; ++i){
    if (bk[i] >= 0){
      int p = lbase[bk[i]] + atomicAdd(&lcur[bk[i]], 1);
      packed[p] = pk[i];
    }
  }
}

// pass 2: one block per bucket -> rp + es (ushort), block-private es region
__global__ __launch_bounds__(256) void build_k(const int* __restrict__ gbase,
                                               const unsigned int* __restrict__ packed,
                                               int* __restrict__ rp,
                                               unsigned short* __restrict__ es){
  __shared__ int h[256], sd[256], cur[256];
  int b = blockIdx.x, t = threadIdx.x;
  int s0 = gbase[b], s1 = gbase[b + 1];
  h[t] = 0; __syncthreads();
  for (int i = s0 + t; i < s1; i += 256)
    atomicAdd(&h[(packed[i] >> 16) & 255], 1);
  __syncthreads();
  int v = h[t]; sd[t] = v; __syncthreads();
  #pragma unroll
  for (int off = 1; off < 256; off <<= 1){
    int u = (t >= off) ? sd[t - off] : 0;
    __syncthreads();
    sd[t] += u;
    __syncthreads();
  }
  int ex = sd[t] - v;
  cur[t] = ex;
  int d = b * 256 + t;
  if (d < NNODE) rp[d] = s0 + ex;
  __syncthreads();
  for (int i = s0 + t; i < s1; i += 256){
    unsigned int p = packed[i];
    int ld = (p >> 16) & 255;
    int pos = atomicAdd(&cur[ld], 1);
    es[s0 + pos] = (unsigned short)(p & 0xffffu);
  }
}

// ------- GEMM: out[N,BN] = X[N,128] @ W[128,BN] (+bias); OUTBF -> bf16 out -------
template<int BN, int TM, int OUTBF>
__global__ __launch_bounds__(256) void gemm_k(const float* __restrict__ X,
                                              const float* __restrict__ W,
                                              const float* __restrict__ bias,
                                              void* __restrict__ outp){
  const int TX  = BN / 8;
  const int TY  = 256 / TX;
  const int BM  = TY * TM;
  const int STR = BM + 4;
  __shared__ float xs[128 * STR];
  int tid = threadIdx.x;
  int bm0 = blockIdx.x * BM;

  const int NF4 = BM * 32 / 256;
  #pragma unroll
  for (int i = 0; i < NF4; ++i){
    int gi = i * 256 + tid;
    int r  = gi >> 5;
    int c4 = gi & 31;
    int grow = bm0 + r;
    float4 v = make_float4(0.f, 0.f, 0.f, 0.f);
    if (grow < NNODE) v = ((const float4*)X)[grow * 32 + c4];
    int k = c4 * 4;
    xs[(k + 0) * STR + r] = v.x;
    xs[(k + 1) * STR + r] = v.y;
    xs[(k + 2) * STR + r] = v.z;
    xs[(k + 3) * STR + r] = v.w;
  }
  __syncthreads();

  int tx = tid % TX, ty = tid / TX;
  int n0 = tx * 8, m0 = ty * TM;
  float acc[TM][8];
  #pragma unroll
  for (int i = 0; i < TM; ++i)
    #pragma unroll
    for (int j = 0; j < 8; ++j) acc[i][j] = 0.f;

  const float4* W4 = (const float4*)W;
  for (int k = 0; k < 128; ++k){
    float av[TM];
    #pragma unroll
    for (int i = 0; i < TM; ++i) av[i] = xs[k * STR + m0 + i];
    float4 b0 = W4[k * (BN / 4) + tx * 2];
    float4 b1 = W4[k * (BN / 4) + tx * 2 + 1];
    float bv[8] = {b0.x, b0.y, b0.z, b0.w, b1.x, b1.y, b1.z, b1.w};
    #pragma unroll
    for (int i = 0; i < TM; ++i)
      #pragma unroll
      for (int j = 0; j < 8; ++j) acc[i][j] = fmaf(av[i], bv[j], acc[i][j]);
  }

  float bb[8];
  #pragma unroll
  for (int j = 0; j < 8; ++j) bb[j] = bias ? bias[n0 + j] : 0.f;
  #pragma unroll
  for (int i = 0; i < TM; ++i){
    int row = bm0 + m0 + i;
    if (row < NNODE){
      if (OUTBF){
        unsigned short us[8];
        #pragma unroll
        for (int j = 0; j < 8; ++j) us[j] = f2bf(acc[i][j] + bb[j]);
        uint4 pk;
        pk.x = (unsigned)us[0] | ((unsigned)us[1] << 16);
        pk.y = (unsigned)us[2] | ((unsigned)us[3] << 16);
        pk.z = (unsigned)us[4] | ((unsigned)us[5] << 16);
        pk.w = (unsigned)us[6] | ((unsigned)us[7] << 16);
        ((uint4*)outp)[row * (BN / 8) + tx] = pk;
      } else {
        float4 o0 = make_float4(acc[i][0] + bb[0], acc[i][1] + bb[1],
                                acc[i][2] + bb[2], acc[i][3] + bb[3]);
        float4 o1 = make_float4(acc[i][4] + bb[4], acc[i][5] + bb[5],
                                acc[i][6] + bb[6], acc[i][7] + bb[7]);
        ((float4*)outp)[row * (BN / 4) + tx * 2]     = o0;
        ((float4*)outp)[row * (BN / 4) + tx * 2 + 1] = o1;
      }
    }
  }
}

// ------- batched matvec: u = Wa @ aa, v = Wb @ ab -------
__global__ void mv2_k(const float* __restrict__ Wa, const float* __restrict__ aa,
                      const float* __restrict__ Wb, const float* __restrict__ ab,
                      float* __restrict__ u, float* __restrict__ v){
  int lane = threadIdx.x & 63;
  int r = blockIdx.x * 4 + (threadIdx.x >> 6);
  if (r >= 256) return;
  const float* W = (r < 128) ? Wa : Wb;
  const float* a = (r < 128) ? aa : ab;
  int rr = r & 127;
  float2 w = ((const float2*)(W + rr * DIM))[lane];
  float2 av = ((const float2*)a)[lane];
  float s = wsum(w.x * av.x + w.y * av.y);
  if (lane == 0){ if (r < 128) u[rr] = s; else v[rr] = s; }
}

// ------- dual matvec: als[n]=dot(X[n],u), ald[n]=dot(X[n],v) -------
__global__ __launch_bounds__(256) void dualmv_k(const float* __restrict__ X,
                                                const float* __restrict__ u,
                                                const float* __restrict__ v,
                                                float* __restrict__ als,
                                                float* __restrict__ ald){
  int lane = threadIdx.x & 63;
  int n = blockIdx.x * 4 + (threadIdx.x >> 6);
  if (n >= NNODE) return;
  float2 xv = ((const float2*)(X + (size_t)n * DIM))[lane];
  float2 uu = ((const float2*)u)[lane];
  float2 vv = ((const float2*)v)[lane];
  float s1 = wsum(xv.x * uu.x + xv.y * uu.y);
  float s2 = wsum(xv.x * vv.x + xv.y * vv.y);
  if (lane == 0){ als[n] = s1; ald[n] = s2; }
}

// ---------------- GAT softmax-aggregate; A bf16 [N,128], es ushort ----------------
__global__ __launch_bounds__(256) void gat_k(const int* __restrict__ rp,
                                             const unsigned short* __restrict__ es,
                                             const float* __restrict__ als,
                                             const float* __restrict__ ald,
                                             const unsigned int* __restrict__ A,
                                             const float* __restrict__ L,
                                             const float* __restrict__ bc,
                                             float* __restrict__ H, int relu){
  int lane = threadIdx.x & 63;
  int n = blockIdx.x * 4 + (threadIdx.x >> 6);
  if (n >= NNODE) return;
  int start = rp[n], end = rp[n + 1];
  int deg = end - start;
  float ad = ald[n];
  float2 acc = make_float2(0.f, 0.f);
  float rinv = 0.f;

  if (deg <= 64){
    int s = 0; float z = -3.0e38f;
    if (lane < deg){
      s = es[start + lane];
      float t = als[s] + ad;
      z = t > 0.f ? t : NEG * t;
    }
    float m = wmax(z);
    float e = (lane < deg) ? __expf(z - m) : 0.f;
    float denom = wsum(e);
    rinv = (deg > 0) ? 1.f / denom : 0.f;
    int dq = (deg + 3) & ~3;
    for (int j = 0; j < dq; j += 4){
      int   s0 = __shfl(s, j),     s1 = __shfl(s, j + 1);
      int   s2 = __shfl(s, j + 2), s3 = __shfl(s, j + 3);
      float w0 = __shfl(e, j),     w1 = __shfl(e, j + 1);
      float w2 = __shfl(e, j + 2), w3 = __shfl(e, j + 3);
      unsigned p0 = A[(size_t)s0 * 64 + lane];
      unsigned p1 = A[(size_t)s1 * 64 + lane];
      unsigned p2 = A[(size_t)s2 * 64 + lane];
      unsigned p3 = A[(size_t)s3 * 64 + lane];
      acc.x = fmaf(w0, __uint_as_float(p0 << 16), acc.x);
      acc.y = fmaf(w0, __uint_as_float(p0 & 0xffff0000u), acc.y);
      acc.x = fmaf(w1, __uint_as_float(p1 << 16), acc.x);
      acc.y = fmaf(w1, __uint_as_float(p1 & 0xffff0000u), acc.y);
      acc.x = fmaf(w2, __uint_as_float(p2 << 16), acc.x);
      acc.y = fmaf(w2, __uint_as_float(p2 & 0xffff0000u), acc.y);
      acc.x = fmaf(w3, __uint_as_float(p3 << 16), acc.x);
      acc.y = fmaf(w3, __uint_as_float(p3 & 0xffff0000u), acc.y);
    }
  } else {
    float mloc = -3.0e38f;
    for (int i = start + lane; i < end; i += 64){
      int s = es[i];
      float zz = als[s] + ad;
      zz = zz > 0.f ? zz : NEG * zz;
      mloc = fmaxf(mloc, zz);
    }
    float m = wmax(mloc);
    float dloc = 0.f;
    for (int i = start + lane; i < end; i += 64){
      int s = es[i];
      float zz = als[s] + ad;
      zz = zz > 0.f ? zz : NEG * zz;
      dloc += __expf(zz - m);
    }
    rinv = 1.f / wsum(dloc);
    for (int i = start; i < end; ++i){
      int s = es[i];
      float zz = als[s] + ad;
      zz = zz > 0.f ? zz : NEG * zz;
      float w = __expf(zz - m);
      unsigned p = A[(size_t)s * 64 + lane];
      acc.x = fmaf(w, __uint_as_float(p << 16), acc.x);
      acc.y = fmaf(w, __uint_as_float(p & 0xffff0000u), acc.y);
    }
  }

  int c = lane * 2;
  float2 l2 = ((const float2*)(L + (size_t)n * DIM))[lane];
  float ox = fmaf(acc.x, rinv, l2.x + bc[c]);
  float oy = fmaf(acc.y, rinv, l2.y + bc[c + 1]);
  if (relu){ ox = fmaxf(ox, 0.f); oy = fmaxf(oy, 0.f); }
  ((float2*)(H + (size_t)n * DIM))[lane] = make_float2(ox, oy);
}

extern "C" void kernel_launch(void* const* d_in, const int* in_sizes, int n_in,
                              void* d_out, int out_size, void* d_ws, size_t ws_size,
                              hipStream_t stream){
  const float* x   = (const float*)d_in[0];
  const int*   ei  = (const int*)d_in[1];
  const float* w0s = (const float*)d_in[2];
  const float* w0d = (const float*)d_in[3];
  const float* a0s = (const float*)d_in[4];
  const float* a0d = (const float*)d_in[5];
  const float* bc0 = (const float*)d_in[6];
  const float* wl0 = (const float*)d_in[7];
  const float* bl0 = (const float*)d_in[8];
  const float* w1  = (const float*)d_in[9];
  const float* a1s = (const float*)d_in[10];
  const float* a1d = (const float*)d_in[11];
  const float* bc1 = (const float*)d_in[12];
  const float* wl1 = (const float*)d_in[13];
  const float* bl1 = (const float*)d_in[14];
  const float* w2  = (const float*)d_in[15];
  const float* a2s = (const float*)d_in[16];
  const float* a2d = (const float*)d_in[17];
  const float* bc2 = (const float*)d_in[18];
  const float* wl2 = (const float*)d_in[19];
  const float* bl2 = (const float*)d_in[20];
  const float* wh  = (const float*)d_in[21];
  const float* bh  = (const float*)d_in[22];
  float* out = (float*)d_out;

  float* H    = (float*)d_ws;                                   // [N,128] f32
  unsigned int* A = (unsigned int*)(H + (size_t)NNODE * DIM);   // [N,128] bf16
  float* L    = (float*)(A + (size_t)NNODE * 64);               // [N,128] f32
  float* als  = L + (size_t)NNODE * DIM;
  float* ald  = als + NNODE;
  float* u    = ald + NNODE;
  float* v    = u + DIM;
  int*   rp   = (int*)(v + DIM);            // NNODE+1
  int*   gcount = rp + (NNODE + 1);         // NBUCK
  int*   gbase  = gcount + NBUCK;           // NBUCK+1
  int*   gcur   = gbase + (NBUCK + 1);      // NBUCK
  unsigned int* packed = (unsigned int*)(gcur + NBUCK);         // NEDGE
  unsigned short* es   = (unsigned short*)(packed + NEDGE);     // NEDGE

  // ---- CSR by dst: 2-level bucket sort (rebuilt every launch) ----
  hipMemsetAsync(gcount, 0, NBUCK * sizeof(int), stream);
  bhist_k<<<NB1, 256, 0, stream>>>(ei + NEDGE, gcount);
  bscan_k<<<1, 256, 0, stream>>>(gcount, gbase, gcur, rp);
  bucket_k<<<NB1, 256, 0, stream>>>(ei, gcur, packed);
  build_k<<<NBUCK, 256, 0, stream>>>(gbase, packed, rp, es);

  dim3 b(256);
  dim3 g64((NNODE + 63) / 64);
  dim3 gn((NNODE + 3) / 4);

  // ---- layer 0 ----
  gemm_k<128, 4, 1><<<g64, b, 0, stream>>>(x, w0s, nullptr, A);   // h_src (bf16)
  gemm_k<128, 4, 0><<<g64, b, 0, stream>>>(x, wl0, bl0, L);       // lin
  mv2_k<<<64, 256, 0, stream>>>(w0s, a0s, w0d, a0d, u, v);
  dualmv_k<<<gn, b, 0, stream>>>(x, u, v, als, ald);
  gat_k<<<gn, b, 0, stream>>>(rp, es, als, ald, A, L, bc0, H, 1);

  // ---- layer 1 ----
  gemm_k<128, 4, 1><<<g64, b, 0, stream>>>(H, w1, nullptr, A);
  gemm_k<128, 4, 0><<<g64, b, 0, stream>>>(H, wl1, bl1, L);
  mv2_k<<<64, 256, 0, stream>>>(w1, a1s, w1, a1d, u, v);
  dualmv_k<<<gn, b, 0, stream>>>(H, u, v, als, ald);
  gat_k<<<gn, b, 0, stream>>>(rp, es, als, ald, A, L, bc1, H, 1);

  // ---- layer 2 (no relu) ----
  gemm_k<128, 4, 1><<<g64, b, 0, stream>>>(H, w2, nullptr, A);
  gemm_k<128, 4, 0><<<g64, b, 0, stream>>>(H, wl2, bl2, L);
  mv2_k<<<64, 256, 0, stream>>>(w2, a2s, w2, a2d, u, v);
  dualmv_k<<<gn, b, 0, stream>>>(H, u, v, als, ald);
  gat_k<<<gn, b, 0, stream>>>(rp, es, als, ald, A, L, bc2, H, 0);

  // ---- head ----
  gemm_k<64, 2, 0><<<g64, b, 0, stream>>>(H, wh, bh, out);
}

// Round 6
// 526.270 us; speedup vs baseline: 1.7720x; 1.1401x over previous
//
#include <hip/hip_runtime.h>

#define NNODE 50000
#define NEDGE 800000
#define DIM   128
#define HEADD 64
#define NEG   0.2f
#define NBUCK 196          // dst>>8 buckets (49999>>8 = 195)
#define EPB1  2048         // edges per block in pass-1 kernels
#define NB1   391          // ceil(NEDGE/EPB1)

__device__ __forceinline__ float wmax(float v){
  #pragma unroll
  for (int m = 32; m > 0; m >>= 1) v = fmaxf(v, __shfl_xor(v, m));
  return v;
}
__device__ __forceinline__ float wsum(float v){
  #pragma unroll
  for (int m = 32; m > 0; m >>= 1) v += __shfl_xor(v, m);
  return v;
}
// fp32 -> bf16 bits, round-to-nearest-even (finite inputs)
__device__ __forceinline__ unsigned short f2bf(float f){
  unsigned int x = __float_as_uint(f);
  return (unsigned short)((x + 0x7fffu + ((x >> 16) & 1u)) >> 16);
}

// ---------------- CSR build: 2-level bucket sort ----------------
__global__ __launch_bounds__(256) void bhist_k(const int* __restrict__ dst,
                                               int* __restrict__ gcount){
  __shared__ int h[NBUCK];
  for (int i = threadIdx.x; i < NBUCK; i += 256) h[i] = 0;
  __syncthreads();
  int e0 = blockIdx.x * EPB1 + threadIdx.x;
  #pragma unroll
  for (int i = 0; i < 8; ++i){
    int e = e0 + i * 256;
    if (e < NEDGE) atomicAdd(&h[dst[e] >> 8], 1);
  }
  __syncthreads();
  for (int i = threadIdx.x; i < NBUCK; i += 256)
    if (h[i]) atomicAdd(&gcount[i], h[i]);
}

__global__ __launch_bounds__(256) void bscan_k(const int* __restrict__ gcount,
                                               int* __restrict__ gbase,
                                               int* __restrict__ gcur,
                                               int* __restrict__ rp){
  __shared__ int sd[256];
  int t = threadIdx.x;
  int v = (t < NBUCK) ? gcount[t] : 0;
  sd[t] = v; __syncthreads();
  #pragma unroll
  for (int off = 1; off < 256; off <<= 1){
    int u = (t >= off) ? sd[t - off] : 0;
    __syncthreads();
    sd[t] += u;
    __syncthreads();
  }
  int ex = sd[t] - v;
  if (t < NBUCK){ gbase[t] = ex; gcur[t] = ex; }
  if (t == NBUCK - 1) gbase[NBUCK] = sd[t];
  if (t == 0) rp[NNODE] = NEDGE;
}

__global__ __launch_bounds__(256) void bucket_k(const int* __restrict__ ei,
                                                int* __restrict__ gcur,
                                                unsigned int* __restrict__ packed){
  __shared__ int lh[NBUCK], lbase[NBUCK], lcur[NBUCK];
  for (int i = threadIdx.x; i < NBUCK; i += 256) lh[i] = 0;
  __syncthreads();
  unsigned int pk[8]; int bk[8];
  int e0 = blockIdx.x * EPB1 + threadIdx.x;
  #pragma unroll
  for (int i = 0; i < 8; ++i){
    int e = e0 + i * 256;
    bk[i] = -1;
    if (e < NEDGE){
      int s = ei[e], d = ei[NEDGE + e];
      pk[i] = ((unsigned)d << 16) | (unsigned)s;
      bk[i] = d >> 8;
      atomicAdd(&lh[bk[i]], 1);
    }
  }
  __syncthreads();
  for (int i = threadIdx.x; i < NBUCK; i += 256){
    lbase[i] = atomicAdd(&gcur[i], lh[i]);
    lcur[i] = 0;
  }
  __syncthreads();
  #pragma unroll
  for (int i = 0; i < 8; ++i){
    if (bk[i] >= 0){
      int p = lbase[bk[i]] + atomicAdd(&lcur[bk[i]], 1);
      packed[p] = pk[i];
    }
  }
}

__global__ __launch_bounds__(256) void build_k(const int* __restrict__ gbase,
                                               const unsigned int* __restrict__ packed,
                                               int* __restrict__ rp,
                                               unsigned short* __restrict__ es){
  __shared__ int h[256], sd[256], cur[256];
  int b = blockIdx.x, t = threadIdx.x;
  int s0 = gbase[b], s1 = gbase[b + 1];
  h[t] = 0; __syncthreads();
  for (int i = s0 + t; i < s1; i += 256)
    atomicAdd(&h[(packed[i] >> 16) & 255], 1);
  __syncthreads();
  int v = h[t]; sd[t] = v; __syncthreads();
  #pragma unroll
  for (int off = 1; off < 256; off <<= 1){
    int u = (t >= off) ? sd[t - off] : 0;
    __syncthreads();
    sd[t] += u;
    __syncthreads();
  }
  int ex = sd[t] - v;
  cur[t] = ex;
  int d = b * 256 + t;
  if (d < NNODE) rp[d] = s0 + ex;
  __syncthreads();
  for (int i = s0 + t; i < s1; i += 256){
    unsigned int p = packed[i];
    int ld = (p >> 16) & 255;
    int pos = atomicAdd(&cur[ld], 1);
    es[s0 + pos] = (unsigned short)(p & 0xffffu);
  }
}

// ------- GEMM: out[N,BN] = X[N,128] @ W[128,BN] (+bias); OUTBF -> bf16 out -------
// W staged in LDS ([k][n], fp32, <=64KB); X rows stream from global into
// registers (no transpose, no LDS writes in hot loop, no bank conflicts).
template<int BN, int TM, int OUTBF>
__global__ __launch_bounds__(256) void gemm_k(const float* __restrict__ X,
                                              const float* __restrict__ W,
                                              const float* __restrict__ bias,
                                              void* __restrict__ outp){
  const int TX = BN / 8;           // threads across cols (each owns 8 cols)
  const int TY = 256 / TX;
  const int BM = TY * TM;          // rows per block
  __shared__ float ws[128 * BN];   // 64 KB for BN=128

  int tid = threadIdx.x;
  // stage W -> LDS, coalesced float4
  {
    const float4* W4 = (const float4*)W;
    float4* ws4 = (float4*)ws;
    #pragma unroll
    for (int i = 0; i < (128 * BN / 4) / 256; ++i)
      ws4[i * 256 + tid] = W4[i * 256 + tid];
  }
  __syncthreads();

  int tx = tid % TX, ty = tid / TX;
  int n0 = tx * 8;
  int bm0 = blockIdx.x * BM;

  int rc[TM];                      // clamped row indices (writes are guarded)
  #pragma unroll
  for (int i = 0; i < TM; ++i){
    int r = bm0 + ty * TM + i;
    rc[i] = r < NNODE ? r : NNODE - 1;
  }

  float acc[TM][8];
  #pragma unroll
  for (int i = 0; i < TM; ++i)
    #pragma unroll
    for (int j = 0; j < 8; ++j) acc[i][j] = 0.f;

  const float4* X4 = (const float4*)X;
  #pragma unroll 2
  for (int kq = 0; kq < 32; ++kq){          // k-quad: 4 consecutive k
    float4 xa[TM];
    #pragma unroll
    for (int i = 0; i < TM; ++i) xa[i] = X4[(size_t)rc[i] * 32 + kq];
    #pragma unroll
    for (int kk = 0; kk < 4; ++kk){
      const float* bp = &ws[(kq * 4 + kk) * BN + n0];
      float4 b0 = *(const float4*)bp;
      float4 b1 = *(const float4*)(bp + 4);
      float bv[8] = {b0.x, b0.y, b0.z, b0.w, b1.x, b1.y, b1.z, b1.w};
      #pragma unroll
      for (int i = 0; i < TM; ++i){
        float a = ((const float*)&xa[i])[kk];
        #pragma unroll
        for (int j = 0; j < 8; ++j) acc[i][j] = fmaf(a, bv[j], acc[i][j]);
      }
    }
  }

  float bb[8];
  #pragma unroll
  for (int j = 0; j < 8; ++j) bb[j] = bias ? bias[n0 + j] : 0.f;
  #pragma unroll
  for (int i = 0; i < TM; ++i){
    int row = bm0 + ty * TM + i;
    if (row < NNODE){
      if (OUTBF){
        unsigned short us[8];
        #pragma unroll
        for (int j = 0; j < 8; ++j) us[j] = f2bf(acc[i][j] + bb[j]);
        uint4 pk;
        pk.x = (unsigned)us[0] | ((unsigned)us[1] << 16);
        pk.y = (unsigned)us[2] | ((unsigned)us[3] << 16);
        pk.z = (unsigned)us[4] | ((unsigned)us[5] << 16);
        pk.w = (unsigned)us[6] | ((unsigned)us[7] << 16);
        ((uint4*)outp)[(size_t)row * (BN / 8) + tx] = pk;
      } else {
        float4 o0 = make_float4(acc[i][0] + bb[0], acc[i][1] + bb[1],
                                acc[i][2] + bb[2], acc[i][3] + bb[3]);
        float4 o1 = make_float4(acc[i][4] + bb[4], acc[i][5] + bb[5],
                                acc[i][6] + bb[6], acc[i][7] + bb[7]);
        ((float4*)outp)[(size_t)row * (BN / 4) + tx * 2]     = o0;
        ((float4*)outp)[(size_t)row * (BN / 4) + tx * 2 + 1] = o1;
      }
    }
  }
}

// ------- batched matvec: u = Wa @ aa, v = Wb @ ab -------
__global__ void mv2_k(const float* __restrict__ Wa, const float* __restrict__ aa,
                      const float* __restrict__ Wb, const float* __restrict__ ab,
                      float* __restrict__ u, float* __restrict__ v){
  int lane = threadIdx.x & 63;
  int r = blockIdx.x * 4 + (threadIdx.x >> 6);
  if (r >= 256) return;
  const float* W = (r < 128) ? Wa : Wb;
  const float* a = (r < 128) ? aa : ab;
  int rr = r & 127;
  float2 w = ((const float2*)(W + rr * DIM))[lane];
  float2 av = ((const float2*)a)[lane];
  float s = wsum(w.x * av.x + w.y * av.y);
  if (lane == 0){ if (r < 128) u[rr] = s; else v[rr] = s; }
}

// ------- dual matvec: als[n]=dot(X[n],u), ald[n]=dot(X[n],v) -------
__global__ __launch_bounds__(256) void dualmv_k(const float* __restrict__ X,
                                                const float* __restrict__ u,
                                                const float* __restrict__ v,
                                                float* __restrict__ als,
                                                float* __restrict__ ald){
  int lane = threadIdx.x & 63;
  int n = blockIdx.x * 4 + (threadIdx.x >> 6);
  if (n >= NNODE) return;
  float2 xv = ((const float2*)(X + (size_t)n * DIM))[lane];
  float2 uu = ((const float2*)u)[lane];
  float2 vv = ((const float2*)v)[lane];
  float s1 = wsum(xv.x * uu.x + xv.y * uu.y);
  float s2 = wsum(xv.x * vv.x + xv.y * vv.y);
  if (lane == 0){ als[n] = s1; ald[n] = s2; }
}

// ---------------- GAT softmax-aggregate; A bf16 [N,128], es ushort ----------------
__global__ __launch_bounds__(256) void gat_k(const int* __restrict__ rp,
                                             const unsigned short* __restrict__ es,
                                             const float* __restrict__ als,
                                             const float* __restrict__ ald,
                                             const unsigned int* __restrict__ A,
                                             const float* __restrict__ L,
                                             const float* __restrict__ bc,
                                             float* __restrict__ H, int relu){
  int lane = threadIdx.x & 63;
  int n = blockIdx.x * 4 + (threadIdx.x >> 6);
  if (n >= NNODE) return;
  int start = rp[n], end = rp[n + 1];
  int deg = end - start;
  float ad = ald[n];
  float2 acc = make_float2(0.f, 0.f);
  float rinv = 0.f;

  if (deg <= 64){
    int s = 0; float z = -3.0e38f;
    if (lane < deg){
      s = es[start + lane];
      float t = als[s] + ad;
      z = t > 0.f ? t : NEG * t;
    }
    float m = wmax(z);
    float e = (lane < deg) ? __expf(z - m) : 0.f;
    float denom = wsum(e);
    rinv = (deg > 0) ? 1.f / denom : 0.f;
    int dq = (deg + 3) & ~3;
    for (int j = 0; j < dq; j += 4){
      int   s0 = __shfl(s, j),     s1 = __shfl(s, j + 1);
      int   s2 = __shfl(s, j + 2), s3 = __shfl(s, j + 3);
      float w0 = __shfl(e, j),     w1 = __shfl(e, j + 1);
      float w2 = __shfl(e, j + 2), w3 = __shfl(e, j + 3);
      unsigned p0 = A[(size_t)s0 * 64 + lane];
      unsigned p1 = A[(size_t)s1 * 64 + lane];
      unsigned p2 = A[(size_t)s2 * 64 + lane];
      unsigned p3 = A[(size_t)s3 * 64 + lane];
      acc.x = fmaf(w0, __uint_as_float(p0 << 16), acc.x);
      acc.y = fmaf(w0, __uint_as_float(p0 & 0xffff0000u), acc.y);
      acc.x = fmaf(w1, __uint_as_float(p1 << 16), acc.x);
      acc.y = fmaf(w1, __uint_as_float(p1 & 0xffff0000u), acc.y);
      acc.x = fmaf(w2, __uint_as_float(p2 << 16), acc.x);
      acc.y = fmaf(w2, __uint_as_float(p2 & 0xffff0000u), acc.y);
      acc.x = fmaf(w3, __uint_as_float(p3 << 16), acc.x);
      acc.y = fmaf(w3, __uint_as_float(p3 & 0xffff0000u), acc.y);
    }
  } else {
    float mloc = -3.0e38f;
    for (int i = start + lane; i < end; i += 64){
      int s = es[i];
      float zz = als[s] + ad;
      zz = zz > 0.f ? zz : NEG * zz;
      mloc = fmaxf(mloc, zz);
    }
    float m = wmax(mloc);
    float dloc = 0.f;
    for (int i = start + lane; i < end; i += 64){
      int s = es[i];
      float zz = als[s] + ad;
      zz = zz > 0.f ? zz : NEG * zz;
      dloc += __expf(zz - m);
    }
    rinv = 1.f / wsum(dloc);
    for (int i = start; i < end; ++i){
      int s = es[i];
      float zz = als[s] + ad;
      zz = zz > 0.f ? zz : NEG * zz;
      float w = __expf(zz - m);
      unsigned p = A[(size_t)s * 64 + lane];
      acc.x = fmaf(w, __uint_as_float(p << 16), acc.x);
      acc.y = fmaf(w, __uint_as_float(p & 0xffff0000u), acc.y);
    }
  }

  int c = lane * 2;
  float2 l2 = ((const float2*)(L + (size_t)n * DIM))[lane];
  float ox = fmaf(acc.x, rinv, l2.x + bc[c]);
  float oy = fmaf(acc.y, rinv, l2.y + bc[c + 1]);
  if (relu){ ox = fmaxf(ox, 0.f); oy = fmaxf(oy, 0.f); }
  ((float2*)(H + (size_t)n * DIM))[lane] = make_float2(ox, oy);
}

extern "C" void kernel_launch(void* const* d_in, const int* in_sizes, int n_in,
                              void* d_out, int out_size, void* d_ws, size_t ws_size,
                              hipStream_t stream){
  const float* x   = (const float*)d_in[0];
  const int*   ei  = (const int*)d_in[1];
  const float* w0s = (const float*)d_in[2];
  const float* w0d = (const float*)d_in[3];
  const float* a0s = (const float*)d_in[4];
  const float* a0d = (const float*)d_in[5];
  const float* bc0 = (const float*)d_in[6];
  const float* wl0 = (const float*)d_in[7];
  const float* bl0 = (const float*)d_in[8];
  const float* w1  = (const float*)d_in[9];
  const float* a1s = (const float*)d_in[10];
  const float* a1d = (const float*)d_in[11];
  const float* bc1 = (const float*)d_in[12];
  const float* wl1 = (const float*)d_in[13];
  const float* bl1 = (const float*)d_in[14];
  const float* w2  = (const float*)d_in[15];
  const float* a2s = (const float*)d_in[16];
  const float* a2d = (const float*)d_in[17];
  const float* bc2 = (const float*)d_in[18];
  const float* wl2 = (const float*)d_in[19];
  const float* bl2 = (const float*)d_in[20];
  const float* wh  = (const float*)d_in[21];
  const float* bh  = (const float*)d_in[22];
  float* out = (float*)d_out;

  float* H    = (float*)d_ws;                                   // [N,128] f32
  unsigned int* A = (unsigned int*)(H + (size_t)NNODE * DIM);   // [N,128] bf16
  float* L    = (float*)(A + (size_t)NNODE * 64);               // [N,128] f32
  float* als  = L + (size_t)NNODE * DIM;
  float* ald  = als + NNODE;
  float* u    = ald + NNODE;
  float* v    = u + DIM;
  int*   rp   = (int*)(v + DIM);            // NNODE+1
  int*   gcount = rp + (NNODE + 1);         // NBUCK
  int*   gbase  = gcount + NBUCK;           // NBUCK+1
  int*   gcur   = gbase + (NBUCK + 1);      // NBUCK
  unsigned int* packed = (unsigned int*)(gcur + NBUCK);         // NEDGE
  unsigned short* es   = (unsigned short*)(packed + NEDGE);     // NEDGE

  // ---- CSR by dst: 2-level bucket sort (rebuilt every launch) ----
  hipMemsetAsync(gcount, 0, NBUCK * sizeof(int), stream);
  bhist_k<<<NB1, 256, 0, stream>>>(ei + NEDGE, gcount);
  bscan_k<<<1, 256, 0, stream>>>(gcount, gbase, gcur, rp);
  bucket_k<<<NB1, 256, 0, stream>>>(ei, gcur, packed);
  build_k<<<NBUCK, 256, 0, stream>>>(gbase, packed, rp, es);

  dim3 b(256);
  dim3 g64((NNODE + 63) / 64);   // 64 rows/block in gemm_k (TM=4 / TM=2 head)
  dim3 gn((NNODE + 3) / 4);

  // ---- layer 0 ----
  gemm_k<128, 4, 1><<<g64, b, 0, stream>>>(x, w0s, nullptr, A);   // h_src (bf16)
  gemm_k<128, 4, 0><<<g64, b, 0, stream>>>(x, wl0, bl0, L);       // lin
  mv2_k<<<64, 256, 0, stream>>>(w0s, a0s, w0d, a0d, u, v);
  dualmv_k<<<gn, b, 0, stream>>>(x, u, v, als, ald);
  gat_k<<<gn, b, 0, stream>>>(rp, es, als, ald, A, L, bc0, H, 1);

  // ---- layer 1 ----
  gemm_k<128, 4, 1><<<g64, b, 0, stream>>>(H, w1, nullptr, A);
  gemm_k<128, 4, 0><<<g64, b, 0, stream>>>(H, wl1, bl1, L);
  mv2_k<<<64, 256, 0, stream>>>(w1, a1s, w1, a1d, u, v);
  dualmv_k<<<gn, b, 0, stream>>>(H, u, v, als, ald);
  gat_k<<<gn, b, 0, stream>>>(rp, es, als, ald, A, L, bc1, H, 1);

  // ---- layer 2 (no relu) ----
  gemm_k<128, 4, 1><<<g64, b, 0, stream>>>(H, w2, nullptr, A);
  gemm_k<128, 4, 0><<<g64, b, 0, stream>>>(H, wl2, bl2, L);
  mv2_k<<<64, 256, 0, stream>>>(w2, a2s, w2, a2d, u, v);
  dualmv_k<<<gn, b, 0, stream>>>(H, u, v, als, ald);
  gat_k<<<gn, b, 0, stream>>>(rp, es, als, ald, A, L, bc2, H, 0);

  // ---- head ----
  gemm_k<64, 2, 0><<<g64, b, 0, stream>>>(H, wh, bh, out);
}

// Round 7
// 400.300 us; speedup vs baseline: 2.3296x; 1.3147x over previous
//
#include <hip/hip_runtime.h>

#define NNODE 50000
#define NEDGE 800000
#define DIM   128
#define HEADD 64
#define NEG   0.2f
#define NBUCK 196          // dst>>8 buckets (49999>>8 = 195)
#define EPB1  2048         // edges per block in pass-1 kernels
#define NB1   391          // ceil(NEDGE/EPB1)
#define GBLK  782          // ceil(NNODE/64) row-blocks for mfma GEMM

typedef __attribute__((ext_vector_type(8))) short bf16x8;
typedef __attribute__((ext_vector_type(4))) float f32x4;

__device__ __forceinline__ float wmax(float v){
  #pragma unroll
  for (int m = 32; m > 0; m >>= 1) v = fmaxf(v, __shfl_xor(v, m));
  return v;
}
__device__ __forceinline__ float wsum(float v){
  #pragma unroll
  for (int m = 32; m > 0; m >>= 1) v += __shfl_xor(v, m);
  return v;
}
// fp32 -> bf16 bits, round-to-nearest-even (finite inputs)
__device__ __forceinline__ unsigned short f2bf(float f){
  unsigned int x = __float_as_uint(f);
  return (unsigned short)((x + 0x7fffu + ((x >> 16) & 1u)) >> 16);
}

// ---------------- CSR build: 2-level bucket sort ----------------
__global__ __launch_bounds__(256) void bhist_k(const int* __restrict__ dst,
                                               int* __restrict__ gcount){
  __shared__ int h[NBUCK];
  for (int i = threadIdx.x; i < NBUCK; i += 256) h[i] = 0;
  __syncthreads();
  int e0 = blockIdx.x * EPB1 + threadIdx.x;
  #pragma unroll
  for (int i = 0; i < 8; ++i){
    int e = e0 + i * 256;
    if (e < NEDGE) atomicAdd(&h[dst[e] >> 8], 1);
  }
  __syncthreads();
  for (int i = threadIdx.x; i < NBUCK; i += 256)
    if (h[i]) atomicAdd(&gcount[i], h[i]);
}

__global__ __launch_bounds__(256) void bscan_k(const int* __restrict__ gcount,
                                               int* __restrict__ gbase,
                                               int* __restrict__ gcur,
                                               int* __restrict__ rp){
  __shared__ int sd[256];
  int t = threadIdx.x;
  int v = (t < NBUCK) ? gcount[t] : 0;
  sd[t] = v; __syncthreads();
  #pragma unroll
  for (int off = 1; off < 256; off <<= 1){
    int u = (t >= off) ? sd[t - off] : 0;
    __syncthreads();
    sd[t] += u;
    __syncthreads();
  }
  int ex = sd[t] - v;
  if (t < NBUCK){ gbase[t] = ex; gcur[t] = ex; }
  if (t == NBUCK - 1) gbase[NBUCK] = sd[t];
  if (t == 0) rp[NNODE] = NEDGE;
}

__global__ __launch_bounds__(256) void bucket_k(const int* __restrict__ ei,
                                                int* __restrict__ gcur,
                                                unsigned int* __restrict__ packed){
  __shared__ int lh[NBUCK], lbase[NBUCK], lcur[NBUCK];
  for (int i = threadIdx.x; i < NBUCK; i += 256) lh[i] = 0;
  __syncthreads();
  unsigned int pk[8]; int bk[8];
  int e0 = blockIdx.x * EPB1 + threadIdx.x;
  #pragma unroll
  for (int i = 0; i < 8; ++i){
    int e = e0 + i * 256;
    bk[i] = -1;
    if (e < NEDGE){
      int s = ei[e], d = ei[NEDGE + e];
      pk[i] = ((unsigned)d << 16) | (unsigned)s;
      bk[i] = d >> 8;
      atomicAdd(&lh[bk[i]], 1);
    }
  }
  __syncthreads();
  for (int i = threadIdx.x; i < NBUCK; i += 256){
    lbase[i] = atomicAdd(&gcur[i], lh[i]);
    lcur[i] = 0;
  }
  __syncthreads();
  #pragma unroll
  for (int i = 0; i < 8; ++i){
    if (bk[i] >= 0){
      int p = lbase[bk[i]] + atomicAdd(&lcur[bk[i]], 1);
      packed[p] = pk[i];
    }
  }
}

__global__ __launch_bounds__(256) void build_k(const int* __restrict__ gbase,
                                               const unsigned int* __restrict__ packed,
                                               int* __restrict__ rp,
                                               unsigned short* __restrict__ es){
  __shared__ int h[256], sd[256], cur[256];
  int b = blockIdx.x, t = threadIdx.x;
  int s0 = gbase[b], s1 = gbase[b + 1];
  h[t] = 0; __syncthreads();
  for (int i = s0 + t; i < s1; i += 256)
    atomicAdd(&h[(packed[i] >> 16) & 255], 1);
  __syncthreads();
  int v = h[t]; sd[t] = v; __syncthreads();
  #pragma unroll
  for (int off = 1; off < 256; off <<= 1){
    int u = (t >= off) ? sd[t - off] : 0;
    __syncthreads();
    sd[t] += u;
    __syncthreads();
  }
  int ex = sd[t] - v;
  cur[t] = ex;
  int d = b * 256 + t;
  if (d < NNODE) rp[d] = s0 + ex;
  __syncthreads();
  for (int i = s0 + t; i < s1; i += 256){
    unsigned int p = packed[i];
    int ld = (p >> 16) & 255;
    int pos = atomicAdd(&cur[ld], 1);
    es[s0 + pos] = (unsigned short)(p & 0xffffu);
  }
}

// ------- cvt: f32 [N,128] -> packed bf16 (uint = 2 elems) -------
__global__ __launch_bounds__(256) void cvt_k(const float* __restrict__ X,
                                             unsigned int* __restrict__ Xb){
  int i = blockIdx.x * 256 + threadIdx.x;
  if (i < NNODE * 64){
    float2 v = ((const float2*)X)[i];
    Xb[i] = (unsigned)f2bf(v.x) | ((unsigned)f2bf(v.y) << 16);
  }
}

// ------- weight swizzle: (Wa[128,128] | Wl[128,128]) f32 -> B-frag-linear bf16 -------
// layout: [(ct*4+q)*64 + lane] * 8 elems; lane holds B[k=q*32+quad*8+j][n=ct*16+(lane&15)]
__global__ __launch_bounds__(256) void prep_k(const float* __restrict__ Wa,
                                              const float* __restrict__ Wl,
                                              unsigned short* __restrict__ Wz){
  int g = blockIdx.x * 256 + threadIdx.x;   // 0..4095
  int ct = g >> 8, q = (g >> 6) & 3, lane = g & 63;
  int n = lane & 15, quad = lane >> 4;
  const float* W = (ct < 8) ? Wa : Wl;
  int c = (ct & 7) * 16 + n;
  unsigned short* dst = Wz + ((size_t)(ct * 4 + q) * 64 + lane) * 8;
  #pragma unroll
  for (int j = 0; j < 8; ++j){
    int k = q * 32 + quad * 8 + j;
    dst[j] = f2bf(W[k * 128 + c]);
  }
}

// ------- fused MFMA GEMM: [A | L](N,256) = Xb(N,128) @ [Wa|Wl]; A->bf16, L->f32+bias -------
__global__ __launch_bounds__(256) void mfma_k(const unsigned short* __restrict__ Xb,
                                              const unsigned short* __restrict__ Wz,
                                              const float* __restrict__ bl,
                                              unsigned short* __restrict__ Aout,
                                              float* __restrict__ Lout){
  int lane = threadIdx.x & 63;
  int wid  = threadIdx.x >> 6;
  int r0   = blockIdx.x * 64 + wid * 16;
  int quad = lane >> 4;
  int col  = lane & 15;

  int rA = r0 + col; if (rA > NNODE - 1) rA = NNODE - 1;
  const bf16x8* xrow = (const bf16x8*)(Xb + (size_t)rA * 128);
  bf16x8 a[4];
  #pragma unroll
  for (int q = 0; q < 4; ++q) a[q] = xrow[q * 4 + quad];   // k = q*32 + quad*8 ..

  const bf16x8* wz = (const bf16x8*)Wz;
  int rowq = r0 + quad * 4;
  #pragma unroll
  for (int ct = 0; ct < 16; ++ct){
    f32x4 acc = {0.f, 0.f, 0.f, 0.f};
    #pragma unroll
    for (int q = 0; q < 4; ++q){
      bf16x8 b = wz[(ct * 4 + q) * 64 + lane];
      acc = __builtin_amdgcn_mfma_f32_16x16x32_bf16(a[q], b, acc, 0, 0, 0);
    }
    if (ct < 8){
      int c = ct * 16 + col;
      #pragma unroll
      for (int r = 0; r < 4; ++r){
        int row = rowq + r;
        if (row < NNODE) Aout[(size_t)row * 128 + c] = f2bf(acc[r]);
      }
    } else {
      int c = (ct - 8) * 16 + col;
      float bb = bl[c];
      #pragma unroll
      for (int r = 0; r < 4; ++r){
        int row = rowq + r;
        if (row < NNODE) Lout[(size_t)row * 128 + c] = acc[r] + bb;
      }
    }
  }
}

// ------- fp32 vector GEMM (head only): out[N,BN] = X[N,128]@W + bias -------
template<int BN, int TM>
__global__ __launch_bounds__(256) void gemm_k(const float* __restrict__ X,
                                              const float* __restrict__ W,
                                              const float* __restrict__ bias,
                                              float* __restrict__ outp){
  const int TX = BN / 8;
  const int TY = 256 / TX;
  const int BM = TY * TM;
  __shared__ float ws[128 * BN];
  int tid = threadIdx.x;
  {
    const float4* W4 = (const float4*)W;
    float4* ws4 = (float4*)ws;
    #pragma unroll
    for (int i = 0; i < (128 * BN / 4) / 256; ++i)
      ws4[i * 256 + tid] = W4[i * 256 + tid];
  }
  __syncthreads();

  int tx = tid % TX, ty = tid / TX;
  int n0 = tx * 8;
  int bm0 = blockIdx.x * BM;
  int rc[TM];
  #pragma unroll
  for (int i = 0; i < TM; ++i){
    int r = bm0 + ty * TM + i;
    rc[i] = r < NNODE ? r : NNODE - 1;
  }
  float acc[TM][8];
  #pragma unroll
  for (int i = 0; i < TM; ++i)
    #pragma unroll
    for (int j = 0; j < 8; ++j) acc[i][j] = 0.f;

  const float4* X4 = (const float4*)X;
  #pragma unroll 2
  for (int kq = 0; kq < 32; ++kq){
    float4 xa[TM];
    #pragma unroll
    for (int i = 0; i < TM; ++i) xa[i] = X4[(size_t)rc[i] * 32 + kq];
    #pragma unroll
    for (int kk = 0; kk < 4; ++kk){
      const float* bp = &ws[(kq * 4 + kk) * BN + n0];
      float4 b0 = *(const float4*)bp;
      float4 b1 = *(const float4*)(bp + 4);
      float bv[8] = {b0.x, b0.y, b0.z, b0.w, b1.x, b1.y, b1.z, b1.w};
      #pragma unroll
      for (int i = 0; i < TM; ++i){
        float av = ((const float*)&xa[i])[kk];
        #pragma unroll
        for (int j = 0; j < 8; ++j) acc[i][j] = fmaf(av, bv[j], acc[i][j]);
      }
    }
  }
  float bb[8];
  #pragma unroll
  for (int j = 0; j < 8; ++j) bb[j] = bias ? bias[n0 + j] : 0.f;
  #pragma unroll
  for (int i = 0; i < TM; ++i){
    int row = bm0 + ty * TM + i;
    if (row < NNODE){
      float4 o0 = make_float4(acc[i][0] + bb[0], acc[i][1] + bb[1],
                              acc[i][2] + bb[2], acc[i][3] + bb[3]);
      float4 o1 = make_float4(acc[i][4] + bb[4], acc[i][5] + bb[5],
                              acc[i][6] + bb[6], acc[i][7] + bb[7]);
      ((float4*)outp)[(size_t)row * (BN / 4) + tx * 2]     = o0;
      ((float4*)outp)[(size_t)row * (BN / 4) + tx * 2 + 1] = o1;
    }
  }
}

// ------- batched matvec: u = Wa @ aa, v = Wb @ ab -------
__global__ void mv2_k(const float* __restrict__ Wa, const float* __restrict__ aa,
                      const float* __restrict__ Wb, const float* __restrict__ ab,
                      float* __restrict__ u, float* __restrict__ v){
  int lane = threadIdx.x & 63;
  int r = blockIdx.x * 4 + (threadIdx.x >> 6);
  if (r >= 256) return;
  const float* W = (r < 128) ? Wa : Wb;
  const float* a = (r < 128) ? aa : ab;
  int rr = r & 127;
  float2 w = ((const float2*)(W + rr * DIM))[lane];
  float2 av = ((const float2*)a)[lane];
  float s = wsum(w.x * av.x + w.y * av.y);
  if (lane == 0){ if (r < 128) u[rr] = s; else v[rr] = s; }
}

// ------- dual matvec: als[n]=dot(X[n],u), ald[n]=dot(X[n],v) (fp32 path) -------
__global__ __launch_bounds__(256) void dualmv_k(const float* __restrict__ X,
                                                const float* __restrict__ u,
                                                const float* __restrict__ v,
                                                float* __restrict__ als,
                                                float* __restrict__ ald){
  int lane = threadIdx.x & 63;
  int n = blockIdx.x * 4 + (threadIdx.x >> 6);
  if (n >= NNODE) return;
  float2 xv = ((const float2*)(X + (size_t)n * DIM))[lane];
  float2 uu = ((const float2*)u)[lane];
  float2 vv = ((const float2*)v)[lane];
  float s1 = wsum(xv.x * uu.x + xv.y * uu.y);
  float s2 = wsum(xv.x * vv.x + xv.y * vv.y);
  if (lane == 0){ als[n] = s1; ald[n] = s2; }
}

// ---------------- GAT softmax-aggregate; A bf16, es ushort; emits H f32 + Hb bf16 ----------------
__global__ __launch_bounds__(256) void gat_k(const int* __restrict__ rp,
                                             const unsigned short* __restrict__ es,
                                             const float* __restrict__ als,
                                             const float* __restrict__ ald,
                                             const unsigned int* __restrict__ A,
                                             const float* __restrict__ L,
                                             const float* __restrict__ bc,
                                             float* __restrict__ H,
                                             unsigned int* __restrict__ Hb, int relu){
  int lane = threadIdx.x & 63;
  int n = blockIdx.x * 4 + (threadIdx.x >> 6);
  if (n >= NNODE) return;
  int start = rp[n], end = rp[n + 1];
  int deg = end - start;
  float ad = ald[n];
  float2 acc = make_float2(0.f, 0.f);
  float rinv = 0.f;

  if (deg <= 64){
    int s = 0; float z = -3.0e38f;
    if (lane < deg){
      s = es[start + lane];
      float t = als[s] + ad;
      z = t > 0.f ? t : NEG * t;
    }
    float m = wmax(z);
    float e = (lane < deg) ? __expf(z - m) : 0.f;
    float denom = wsum(e);
    rinv = (deg > 0) ? 1.f / denom : 0.f;
    int dq = (deg + 3) & ~3;
    for (int j = 0; j < dq; j += 4){
      int   s0 = __shfl(s, j),     s1 = __shfl(s, j + 1);
      int   s2 = __shfl(s, j + 2), s3 = __shfl(s, j + 3);
      float w0 = __shfl(e, j),     w1 = __shfl(e, j + 1);
      float w2 = __shfl(e, j + 2), w3 = __shfl(e, j + 3);
      unsigned p0 = A[(size_t)s0 * 64 + lane];
      unsigned p1 = A[(size_t)s1 * 64 + lane];
      unsigned p2 = A[(size_t)s2 * 64 + lane];
      unsigned p3 = A[(size_t)s3 * 64 + lane];
      acc.x = fmaf(w0, __uint_as_float(p0 << 16), acc.x);
      acc.y = fmaf(w0, __uint_as_float(p0 & 0xffff0000u), acc.y);
      acc.x = fmaf(w1, __uint_as_float(p1 << 16), acc.x);
      acc.y = fmaf(w1, __uint_as_float(p1 & 0xffff0000u), acc.y);
      acc.x = fmaf(w2, __uint_as_float(p2 << 16), acc.x);
      acc.y = fmaf(w2, __uint_as_float(p2 & 0xffff0000u), acc.y);
      acc.x = fmaf(w3, __uint_as_float(p3 << 16), acc.x);
      acc.y = fmaf(w3, __uint_as_float(p3 & 0xffff0000u), acc.y);
    }
  } else {
    float mloc = -3.0e38f;
    for (int i = start + lane; i < end; i += 64){
      int s = es[i];
      float zz = als[s] + ad;
      zz = zz > 0.f ? zz : NEG * zz;
      mloc = fmaxf(mloc, zz);
    }
    float m = wmax(mloc);
    float dloc = 0.f;
    for (int i = start + lane; i < end; i += 64){
      int s = es[i];
      float zz = als[s] + ad;
      zz = zz > 0.f ? zz : NEG * zz;
      dloc += __expf(zz - m);
    }
    rinv = 1.f / wsum(dloc);
    for (int i = start; i < end; ++i){
      int s = es[i];
      float zz = als[s] + ad;
      zz = zz > 0.f ? zz : NEG * zz;
      float w = __expf(zz - m);
      unsigned p = A[(size_t)s * 64 + lane];
      acc.x = fmaf(w, __uint_as_float(p << 16), acc.x);
      acc.y = fmaf(w, __uint_as_float(p & 0xffff0000u), acc.y);
    }
  }

  int c = lane * 2;
  float2 l2 = ((const float2*)(L + (size_t)n * DIM))[lane];
  float ox = fmaf(acc.x, rinv, l2.x + bc[c]);
  float oy = fmaf(acc.y, rinv, l2.y + bc[c + 1]);
  if (relu){ ox = fmaxf(ox, 0.f); oy = fmaxf(oy, 0.f); }
  ((float2*)(H + (size_t)n * DIM))[lane] = make_float2(ox, oy);
  Hb[(size_t)n * 64 + lane] = (unsigned)f2bf(ox) | ((unsigned)f2bf(oy) << 16);
}

extern "C" void kernel_launch(void* const* d_in, const int* in_sizes, int n_in,
                              void* d_out, int out_size, void* d_ws, size_t ws_size,
                              hipStream_t stream){
  const float* x   = (const float*)d_in[0];
  const int*   ei  = (const int*)d_in[1];
  const float* w0s = (const float*)d_in[2];
  const float* w0d = (const float*)d_in[3];
  const float* a0s = (const float*)d_in[4];
  const float* a0d = (const float*)d_in[5];
  const float* bc0 = (const float*)d_in[6];
  const float* wl0 = (const float*)d_in[7];
  const float* bl0 = (const float*)d_in[8];
  const float* w1  = (const float*)d_in[9];
  const float* a1s = (const float*)d_in[10];
  const float* a1d = (const float*)d_in[11];
  const float* bc1 = (const float*)d_in[12];
  const float* wl1 = (const float*)d_in[13];
  const float* bl1 = (const float*)d_in[14];
  const float* w2  = (const float*)d_in[15];
  const float* a2s = (const float*)d_in[16];
  const float* a2d = (const float*)d_in[17];
  const float* bc2 = (const float*)d_in[18];
  const float* wl2 = (const float*)d_in[19];
  const float* bl2 = (const float*)d_in[20];
  const float* wh  = (const float*)d_in[21];
  const float* bh  = (const float*)d_in[22];
  float* out = (float*)d_out;

  float* H    = (float*)d_ws;                                   // [N,128] f32
  unsigned int* A  = (unsigned int*)(H + (size_t)NNODE * DIM);  // [N,128] bf16
  float* L    = (float*)(A + (size_t)NNODE * 64);               // [N,128] f32
  unsigned int* Xb = (unsigned int*)(L + (size_t)NNODE * DIM);  // [N,128] bf16
  unsigned int* Hb = Xb + (size_t)NNODE * 64;                   // [N,128] bf16
  float* als  = (float*)(Hb + (size_t)NNODE * 64);
  float* ald  = als + NNODE;
  float* u    = ald + NNODE;
  float* v    = u + DIM;
  unsigned short* Wz0 = (unsigned short*)(v + DIM);             // 128*256 bf16
  unsigned short* Wz1 = Wz0 + 128 * 256;
  unsigned short* Wz2 = Wz1 + 128 * 256;
  int*   rp   = (int*)(Wz2 + 128 * 256);    // NNODE+1
  int*   gcount = rp + (NNODE + 1);         // NBUCK
  int*   gbase  = gcount + NBUCK;           // NBUCK+1
  int*   gcur   = gbase + (NBUCK + 1);      // NBUCK
  unsigned int* packed = (unsigned int*)(gcur + NBUCK);         // NEDGE
  unsigned short* es   = (unsigned short*)(packed + NEDGE);     // NEDGE

  // ---- CSR by dst: 2-level bucket sort (rebuilt every launch) ----
  hipMemsetAsync(gcount, 0, NBUCK * sizeof(int), stream);
  bhist_k<<<NB1, 256, 0, stream>>>(ei + NEDGE, gcount);
  bscan_k<<<1, 256, 0, stream>>>(gcount, gbase, gcur, rp);
  bucket_k<<<NB1, 256, 0, stream>>>(ei, gcur, packed);
  build_k<<<NBUCK, 256, 0, stream>>>(gbase, packed, rp, es);

  dim3 b(256);
  dim3 gn((NNODE + 3) / 4);

  // ---- prep: x->bf16, weight swizzles ----
  cvt_k<<<(NNODE * 64 + 255) / 256, b, 0, stream>>>(x, Xb);
  prep_k<<<16, b, 0, stream>>>(w0s, wl0, Wz0);
  prep_k<<<16, b, 0, stream>>>(w1, wl1, Wz1);
  prep_k<<<16, b, 0, stream>>>(w2, wl2, Wz2);

  // ---- layer 0 ----
  mfma_k<<<GBLK, b, 0, stream>>>((const unsigned short*)Xb, Wz0, bl0,
                                 (unsigned short*)A, L);
  mv2_k<<<64, 256, 0, stream>>>(w0s, a0s, w0d, a0d, u, v);
  dualmv_k<<<gn, b, 0, stream>>>(x, u, v, als, ald);
  gat_k<<<gn, b, 0, stream>>>(rp, es, als, ald, A, L, bc0, H, Hb, 1);

  // ---- layer 1 ----
  mfma_k<<<GBLK, b, 0, stream>>>((const unsigned short*)Hb, Wz1, bl1,
                                 (unsigned short*)A, L);
  mv2_k<<<64, 256, 0, stream>>>(w1, a1s, w1, a1d, u, v);
  dualmv_k<<<gn, b, 0, stream>>>(H, u, v, als, ald);
  gat_k<<<gn, b, 0, stream>>>(rp, es, als, ald, A, L, bc1, H, Hb, 1);

  // ---- layer 2 (no relu) ----
  mfma_k<<<GBLK, b, 0, stream>>>((const unsigned short*)Hb, Wz2, bl2,
                                 (unsigned short*)A, L);
  mv2_k<<<64, 256, 0, stream>>>(w2, a2s, w2, a2d, u, v);
  dualmv_k<<<gn, b, 0, stream>>>(H, u, v, als, ald);
  gat_k<<<gn, b, 0, stream>>>(rp, es, als, ald, A, L, bc2, H, Hb, 0);

  // ---- head (fp32 for precision) ----
  gemm_k<64, 2><<<dim3((NNODE + 63) / 64), b, 0, stream>>>(H, wh, bh, out);
}

// Round 8
// 372.171 us; speedup vs baseline: 2.5056x; 1.0756x over previous
//
#include <hip/hip_runtime.h>

#define NNODE 50000
#define NEDGE 800000
#define DIM   128
#define HEADD 64
#define NEG   0.2f
#define NBUCK 196          // dst>>8 buckets (49999>>8 = 195)
#define EPB1  2048         // edges per block in pass-1 kernels
#define NB1   391          // ceil(NEDGE/EPB1)
#define GBLK  782          // ceil(NNODE/64) row-blocks for mfma GEMM

typedef __attribute__((ext_vector_type(8))) short bf16x8;
typedef __attribute__((ext_vector_type(4))) float f32x4;

__device__ __forceinline__ float wmax(float v){
  #pragma unroll
  for (int m = 32; m > 0; m >>= 1) v = fmaxf(v, __shfl_xor(v, m));
  return v;
}
__device__ __forceinline__ float wsum(float v){
  #pragma unroll
  for (int m = 32; m > 0; m >>= 1) v += __shfl_xor(v, m);
  return v;
}
// fp32 -> bf16 bits, round-to-nearest-even (finite inputs)
__device__ __forceinline__ unsigned short f2bf(float f){
  unsigned int x = __float_as_uint(f);
  return (unsigned short)((x + 0x7fffu + ((x >> 16) & 1u)) >> 16);
}
__device__ __forceinline__ float bflo(unsigned u){ return __uint_as_float(u << 16); }
__device__ __forceinline__ float bfhi(unsigned u){ return __uint_as_float(u & 0xffff0000u); }

// ---------------- CSR build: 2-level bucket sort ----------------
__global__ __launch_bounds__(256) void bhist_k(const int* __restrict__ dst,
                                               int* __restrict__ gcount){
  __shared__ int h[NBUCK];
  for (int i = threadIdx.x; i < NBUCK; i += 256) h[i] = 0;
  __syncthreads();
  int e0 = blockIdx.x * EPB1 + threadIdx.x;
  #pragma unroll
  for (int i = 0; i < 8; ++i){
    int e = e0 + i * 256;
    if (e < NEDGE) atomicAdd(&h[dst[e] >> 8], 1);
  }
  __syncthreads();
  for (int i = threadIdx.x; i < NBUCK; i += 256)
    if (h[i]) atomicAdd(&gcount[i], h[i]);
}

__global__ __launch_bounds__(256) void bscan_k(const int* __restrict__ gcount,
                                               int* __restrict__ gbase,
                                               int* __restrict__ gcur,
                                               int* __restrict__ rp){
  __shared__ int sd[256];
  int t = threadIdx.x;
  int v = (t < NBUCK) ? gcount[t] : 0;
  sd[t] = v; __syncthreads();
  #pragma unroll
  for (int off = 1; off < 256; off <<= 1){
    int u = (t >= off) ? sd[t - off] : 0;
    __syncthreads();
    sd[t] += u;
    __syncthreads();
  }
  int ex = sd[t] - v;
  if (t < NBUCK){ gbase[t] = ex; gcur[t] = ex; }
  if (t == NBUCK - 1) gbase[NBUCK] = sd[t];
  if (t == 0) rp[NNODE] = NEDGE;
}

__global__ __launch_bounds__(256) void bucket_k(const int* __restrict__ ei,
                                                int* __restrict__ gcur,
                                                unsigned int* __restrict__ packed){
  __shared__ int lh[NBUCK], lbase[NBUCK], lcur[NBUCK];
  for (int i = threadIdx.x; i < NBUCK; i += 256) lh[i] = 0;
  __syncthreads();
  unsigned int pk[8]; int bk[8];
  int e0 = blockIdx.x * EPB1 + threadIdx.x;
  #pragma unroll
  for (int i = 0; i < 8; ++i){
    int e = e0 + i * 256;
    bk[i] = -1;
    if (e < NEDGE){
      int s = ei[e], d = ei[NEDGE + e];
      pk[i] = ((unsigned)d << 16) | (unsigned)s;
      bk[i] = d >> 8;
      atomicAdd(&lh[bk[i]], 1);
    }
  }
  __syncthreads();
  for (int i = threadIdx.x; i < NBUCK; i += 256){
    lbase[i] = atomicAdd(&gcur[i], lh[i]);
    lcur[i] = 0;
  }
  __syncthreads();
  #pragma unroll
  for (int i = 0; i < 8; ++i){
    if (bk[i] >= 0){
      int p = lbase[bk[i]] + atomicAdd(&lcur[bk[i]], 1);
      packed[p] = pk[i];
    }
  }
}

__global__ __launch_bounds__(256) void build_k(const int* __restrict__ gbase,
                                               const unsigned int* __restrict__ packed,
                                               int* __restrict__ rp,
                                               unsigned short* __restrict__ es){
  __shared__ int h[256], sd[256], cur[256];
  int b = blockIdx.x, t = threadIdx.x;
  int s0 = gbase[b], s1 = gbase[b + 1];
  h[t] = 0; __syncthreads();
  for (int i = s0 + t; i < s1; i += 256)
    atomicAdd(&h[(packed[i] >> 16) & 255], 1);
  __syncthreads();
  int v = h[t]; sd[t] = v; __syncthreads();
  #pragma unroll
  for (int off = 1; off < 256; off <<= 1){
    int u = (t >= off) ? sd[t - off] : 0;
    __syncthreads();
    sd[t] += u;
    __syncthreads();
  }
  int ex = sd[t] - v;
  cur[t] = ex;
  int d = b * 256 + t;
  if (d < NNODE) rp[d] = s0 + ex;
  __syncthreads();
  for (int i = s0 + t; i < s1; i += 256){
    unsigned int p = packed[i];
    int ld = (p >> 16) & 255;
    int pos = atomicAdd(&cur[ld], 1);
    es[s0 + pos] = (unsigned short)(p & 0xffffu);
  }
}

// ------- cvt: f32 [N,128] -> packed bf16 -------
__global__ __launch_bounds__(256) void cvt_k(const float* __restrict__ X,
                                             unsigned int* __restrict__ Xb){
  int i = blockIdx.x * 256 + threadIdx.x;
  if (i < NNODE * 64){
    float2 v = ((const float2*)X)[i];
    Xb[i] = (unsigned)f2bf(v.x) | ((unsigned)f2bf(v.y) << 16);
  }
}

// ------- weight swizzle: (Wa | Wl) f32 -> B-frag-linear bf16 -------
__global__ __launch_bounds__(256) void prep_k(const float* __restrict__ Wa,
                                              const float* __restrict__ Wl,
                                              unsigned short* __restrict__ Wz){
  int g = blockIdx.x * 256 + threadIdx.x;   // 0..4095
  int ct = g >> 8, q = (g >> 6) & 3, lane = g & 63;
  int n = lane & 15, quad = lane >> 4;
  const float* W = (ct < 8) ? Wa : Wl;
  int c = (ct & 7) * 16 + n;
  unsigned short* dst = Wz + ((size_t)(ct * 4 + q) * 64 + lane) * 8;
  #pragma unroll
  for (int j = 0; j < 8; ++j){
    int k = q * 32 + quad * 8 + j;
    dst[j] = f2bf(W[k * 128 + c]);
  }
}

// ------- fused MFMA GEMM ------------------------------------------------
// FUSE=0: A-input = Xb (bf16 rows). FUSE=1: A-input row = relu(Cb + Lin).
// Outputs: Aout bf16 [N,128] = h@Wa, Lout f32 [N,128] = h@Wl + bl.
// LOGITS=1: als[n]=dot((h@Wa)[n,:],as_), ald=dot(...,ad_) via fp32 accs.
template<int FUSE, int LOGITS>
__global__ __launch_bounds__(256) void mfma_k(const unsigned short* __restrict__ Xb,
                                              const unsigned int* __restrict__ Cb,
                                              const float* __restrict__ Lin,
                                              const unsigned short* __restrict__ Wz,
                                              const float* __restrict__ bl,
                                              const float* __restrict__ as_,
                                              const float* __restrict__ ad_,
                                              unsigned short* __restrict__ Aout,
                                              float* __restrict__ Lout,
                                              float* __restrict__ als,
                                              float* __restrict__ ald){
  int lane = threadIdx.x & 63;
  int wid  = threadIdx.x >> 6;
  int r0   = blockIdx.x * 64 + wid * 16;
  int quad = lane >> 4;
  int col  = lane & 15;

  int rA = r0 + col; if (rA > NNODE - 1) rA = NNODE - 1;
  bf16x8 a[4];
  if (FUSE){
    const uint4*   c4 = (const uint4*)(Cb + (size_t)rA * 64);
    const float4*  l4 = (const float4*)(Lin + (size_t)rA * 128);
    #pragma unroll
    for (int q = 0; q < 4; ++q){
      int kb = q * 32 + quad * 8;          // element base, multiple of 8
      uint4  cc = c4[kb >> 3];
      float4 la = l4[kb >> 2];
      float4 lb = l4[(kb >> 2) + 1];
      float h0 = fmaxf(bflo(cc.x) + la.x, 0.f);
      float h1 = fmaxf(bfhi(cc.x) + la.y, 0.f);
      float h2 = fmaxf(bflo(cc.y) + la.z, 0.f);
      float h3 = fmaxf(bfhi(cc.y) + la.w, 0.f);
      float h4 = fmaxf(bflo(cc.z) + lb.x, 0.f);
      float h5 = fmaxf(bfhi(cc.z) + lb.y, 0.f);
      float h6 = fmaxf(bflo(cc.w) + lb.z, 0.f);
      float h7 = fmaxf(bfhi(cc.w) + lb.w, 0.f);
      bf16x8 av;
      av[0] = (short)f2bf(h0); av[1] = (short)f2bf(h1);
      av[2] = (short)f2bf(h2); av[3] = (short)f2bf(h3);
      av[4] = (short)f2bf(h4); av[5] = (short)f2bf(h5);
      av[6] = (short)f2bf(h6); av[7] = (short)f2bf(h7);
      a[q] = av;
    }
  } else {
    const bf16x8* xrow = (const bf16x8*)(Xb + (size_t)rA * 128);
    #pragma unroll
    for (int q = 0; q < 4; ++q) a[q] = xrow[q * 4 + quad];
  }

  const bf16x8* wz = (const bf16x8*)Wz;
  int rowq = r0 + quad * 4;
  float alsp[4] = {0.f, 0.f, 0.f, 0.f};
  float aldp[4] = {0.f, 0.f, 0.f, 0.f};

  #pragma unroll
  for (int ct = 0; ct < 16; ++ct){
    f32x4 acc = {0.f, 0.f, 0.f, 0.f};
    #pragma unroll
    for (int q = 0; q < 4; ++q){
      bf16x8 bfr = wz[(ct * 4 + q) * 64 + lane];
      acc = __builtin_amdgcn_mfma_f32_16x16x32_bf16(a[q], bfr, acc, 0, 0, 0);
    }
    if (ct < 8){
      int c = ct * 16 + col;
      if (LOGITS){
        float asv = as_[c], adv = ad_[c];
        #pragma unroll
        for (int r = 0; r < 4; ++r){
          alsp[r] = fmaf(acc[r], asv, alsp[r]);
          aldp[r] = fmaf(acc[r], adv, aldp[r]);
        }
      }
      #pragma unroll
      for (int r = 0; r < 4; ++r){
        int row = rowq + r;
        if (row < NNODE) Aout[(size_t)row * 128 + c] = f2bf(acc[r]);
      }
    } else {
      int c = (ct - 8) * 16 + col;
      float bb = bl[c];
      #pragma unroll
      for (int r = 0; r < 4; ++r){
        int row = rowq + r;
        if (row < NNODE) Lout[(size_t)row * 128 + c] = acc[r] + bb;
      }
    }
  }

  if (LOGITS){
    #pragma unroll
    for (int m = 1; m < 16; m <<= 1){
      #pragma unroll
      for (int r = 0; r < 4; ++r){
        alsp[r] += __shfl_xor(alsp[r], m);
        aldp[r] += __shfl_xor(aldp[r], m);
      }
    }
    if (col == 0){
      #pragma unroll
      for (int r = 0; r < 4; ++r){
        int row = rowq + r;
        if (row < NNODE){ als[row] = alsp[r]; ald[row] = aldp[r]; }
      }
    }
  }
}

// ------- head: out[N,64] = (Cb + L2) @ Wh + bh (fp32 vector, no relu) -------
__global__ __launch_bounds__(256) void head_k(const unsigned int* __restrict__ Cb,
                                              const float* __restrict__ L,
                                              const float* __restrict__ W,
                                              const float* __restrict__ bias,
                                              float* __restrict__ outp){
  const int BN = 64, TM = 2;
  const int TX = BN / 8;           // 8
  const int TY = 256 / TX;         // 32
  const int BM = TY * TM;          // 64
  __shared__ float ws[128 * BN];
  int tid = threadIdx.x;
  {
    const float4* W4 = (const float4*)W;
    float4* ws4 = (float4*)ws;
    #pragma unroll
    for (int i = 0; i < (128 * BN / 4) / 256; ++i)
      ws4[i * 256 + tid] = W4[i * 256 + tid];
  }
  __syncthreads();

  int tx = tid % TX, ty = tid / TX;
  int n0 = tx * 8;
  int bm0 = blockIdx.x * BM;
  int rc[TM];
  #pragma unroll
  for (int i = 0; i < TM; ++i){
    int r = bm0 + ty * TM + i;
    rc[i] = r < NNODE ? r : NNODE - 1;
  }
  float acc[TM][8];
  #pragma unroll
  for (int i = 0; i < TM; ++i)
    #pragma unroll
    for (int j = 0; j < 8; ++j) acc[i][j] = 0.f;

  const float4* L4 = (const float4*)L;
  const uint2*  C2 = (const uint2*)Cb;
  #pragma unroll 2
  for (int kq = 0; kq < 32; ++kq){
    float4 xa[TM];
    #pragma unroll
    for (int i = 0; i < TM; ++i){
      float4 la = L4[(size_t)rc[i] * 32 + kq];
      uint2  cu = C2[(size_t)rc[i] * 32 + kq];
      xa[i] = make_float4(la.x + bflo(cu.x), la.y + bfhi(cu.x),
                          la.z + bflo(cu.y), la.w + bfhi(cu.y));
    }
    #pragma unroll
    for (int kk = 0; kk < 4; ++kk){
      const float* bp = &ws[(kq * 4 + kk) * BN + n0];
      float4 b0 = *(const float4*)bp;
      float4 b1 = *(const float4*)(bp + 4);
      float bv[8] = {b0.x, b0.y, b0.z, b0.w, b1.x, b1.y, b1.z, b1.w};
      #pragma unroll
      for (int i = 0; i < TM; ++i){
        float av = ((const float*)&xa[i])[kk];
        #pragma unroll
        for (int j = 0; j < 8; ++j) acc[i][j] = fmaf(av, bv[j], acc[i][j]);
      }
    }
  }
  float bb[8];
  #pragma unroll
  for (int j = 0; j < 8; ++j) bb[j] = bias[n0 + j];
  #pragma unroll
  for (int i = 0; i < TM; ++i){
    int row = bm0 + ty * TM + i;
    if (row < NNODE){
      float4 o0 = make_float4(acc[i][0] + bb[0], acc[i][1] + bb[1],
                              acc[i][2] + bb[2], acc[i][3] + bb[3]);
      float4 o1 = make_float4(acc[i][4] + bb[4], acc[i][5] + bb[5],
                              acc[i][6] + bb[6], acc[i][7] + bb[7]);
      ((float4*)outp)[(size_t)row * (BN / 4) + tx * 2]     = o0;
      ((float4*)outp)[(size_t)row * (BN / 4) + tx * 2 + 1] = o1;
    }
  }
}

// ------- batched matvec: u = Wa @ aa, v = Wb @ ab (layer 0 only) -------
__global__ void mv2_k(const float* __restrict__ Wa, const float* __restrict__ aa,
                      const float* __restrict__ Wb, const float* __restrict__ ab,
                      float* __restrict__ u, float* __restrict__ v){
  int lane = threadIdx.x & 63;
  int r = blockIdx.x * 4 + (threadIdx.x >> 6);
  if (r >= 256) return;
  const float* W = (r < 128) ? Wa : Wb;
  const float* a = (r < 128) ? aa : ab;
  int rr = r & 127;
  float2 w = ((const float2*)(W + rr * DIM))[lane];
  float2 av = ((const float2*)a)[lane];
  float s = wsum(w.x * av.x + w.y * av.y);
  if (lane == 0){ if (r < 128) u[rr] = s; else v[rr] = s; }
}

// ------- dual matvec over x (layer 0 only) -------
__global__ __launch_bounds__(256) void dualmv_k(const float* __restrict__ X,
                                                const float* __restrict__ u,
                                                const float* __restrict__ v,
                                                float* __restrict__ als,
                                                float* __restrict__ ald){
  int lane = threadIdx.x & 63;
  int n = blockIdx.x * 4 + (threadIdx.x >> 6);
  if (n >= NNODE) return;
  float2 xv = ((const float2*)(X + (size_t)n * DIM))[lane];
  float2 uu = ((const float2*)u)[lane];
  float2 vv = ((const float2*)v)[lane];
  float s1 = wsum(xv.x * uu.x + xv.y * uu.y);
  float s2 = wsum(xv.x * vv.x + xv.y * vv.y);
  if (lane == 0){ als[n] = s1; ald[n] = s2; }
}

// ---------------- GAT softmax-aggregate -> Cb = conv + bc (bf16) ----------------
__global__ __launch_bounds__(256) void gat_k(const int* __restrict__ rp,
                                             const unsigned short* __restrict__ es,
                                             const float* __restrict__ als,
                                             const float* __restrict__ ald,
                                             const unsigned int* __restrict__ A,
                                             const float* __restrict__ bc,
                                             unsigned int* __restrict__ Cb){
  int lane = threadIdx.x & 63;
  int n = blockIdx.x * 4 + (threadIdx.x >> 6);
  if (n >= NNODE) return;
  int start = rp[n], end = rp[n + 1];
  int deg = end - start;
  float ad = ald[n];
  float2 acc = make_float2(0.f, 0.f);
  float rinv = 0.f;

  if (deg <= 64){
    int s = 0; float z = -3.0e38f;
    if (lane < deg){
      s = es[start + lane];
      float t = als[s] + ad;
      z = t > 0.f ? t : NEG * t;
    }
    float m = wmax(z);
    float e = (lane < deg) ? __expf(z - m) : 0.f;
    float denom = wsum(e);
    rinv = (deg > 0) ? 1.f / denom : 0.f;
    int dq = (deg + 3) & ~3;
    for (int j = 0; j < dq; j += 4){
      int   s0 = __shfl(s, j),     s1 = __shfl(s, j + 1);
      int   s2 = __shfl(s, j + 2), s3 = __shfl(s, j + 3);
      float w0 = __shfl(e, j),     w1 = __shfl(e, j + 1);
      float w2 = __shfl(e, j + 2), w3 = __shfl(e, j + 3);
      unsigned p0 = A[(size_t)s0 * 64 + lane];
      unsigned p1 = A[(size_t)s1 * 64 + lane];
      unsigned p2 = A[(size_t)s2 * 64 + lane];
      unsigned p3 = A[(size_t)s3 * 64 + lane];
      acc.x = fmaf(w0, bflo(p0), acc.x); acc.y = fmaf(w0, bfhi(p0), acc.y);
      acc.x = fmaf(w1, bflo(p1), acc.x); acc.y = fmaf(w1, bfhi(p1), acc.y);
      acc.x = fmaf(w2, bflo(p2), acc.x); acc.y = fmaf(w2, bfhi(p2), acc.y);
      acc.x = fmaf(w3, bflo(p3), acc.x); acc.y = fmaf(w3, bfhi(p3), acc.y);
    }
  } else {
    float mloc = -3.0e38f;
    for (int i = start + lane; i < end; i += 64){
      int s = es[i];
      float zz = als[s] + ad;
      zz = zz > 0.f ? zz : NEG * zz;
      mloc = fmaxf(mloc, zz);
    }
    float m = wmax(mloc);
    float dloc = 0.f;
    for (int i = start + lane; i < end; i += 64){
      int s = es[i];
      float zz = als[s] + ad;
      zz = zz > 0.f ? zz : NEG * zz;
      dloc += __expf(zz - m);
    }
    rinv = 1.f / wsum(dloc);
    for (int i = start; i < end; ++i){
      int s = es[i];
      float zz = als[s] + ad;
      zz = zz > 0.f ? zz : NEG * zz;
      float w = __expf(zz - m);
      unsigned p = A[(size_t)s * 64 + lane];
      acc.x = fmaf(w, bflo(p), acc.x);
      acc.y = fmaf(w, bfhi(p), acc.y);
    }
  }

  int c = lane * 2;
  float cx = fmaf(acc.x, rinv, bc[c]);
  float cy = fmaf(acc.y, rinv, bc[c + 1]);
  Cb[(size_t)n * 64 + lane] = (unsigned)f2bf(cx) | ((unsigned)f2bf(cy) << 16);
}

extern "C" void kernel_launch(void* const* d_in, const int* in_sizes, int n_in,
                              void* d_out, int out_size, void* d_ws, size_t ws_size,
                              hipStream_t stream){
  const float* x   = (const float*)d_in[0];
  const int*   ei  = (const int*)d_in[1];
  const float* w0s = (const float*)d_in[2];
  const float* w0d = (const float*)d_in[3];
  const float* a0s = (const float*)d_in[4];
  const float* a0d = (const float*)d_in[5];
  const float* bc0 = (const float*)d_in[6];
  const float* wl0 = (const float*)d_in[7];
  const float* bl0 = (const float*)d_in[8];
  const float* w1  = (const float*)d_in[9];
  const float* a1s = (const float*)d_in[10];
  const float* a1d = (const float*)d_in[11];
  const float* bc1 = (const float*)d_in[12];
  const float* wl1 = (const float*)d_in[13];
  const float* bl1 = (const float*)d_in[14];
  const float* w2  = (const float*)d_in[15];
  const float* a2s = (const float*)d_in[16];
  const float* a2d = (const float*)d_in[17];
  const float* bc2 = (const float*)d_in[18];
  const float* wl2 = (const float*)d_in[19];
  const float* bl2 = (const float*)d_in[20];
  const float* wh  = (const float*)d_in[21];
  const float* bh  = (const float*)d_in[22];
  float* out = (float*)d_out;

  unsigned int* Ab = (unsigned int*)d_ws;                        // [N,128] bf16
  float* LA   = (float*)(Ab + (size_t)NNODE * 64);               // [N,128] f32
  float* LB   = LA + (size_t)NNODE * DIM;                        // [N,128] f32
  unsigned int* Cb = (unsigned int*)(LB + (size_t)NNODE * DIM);  // [N,128] bf16
  unsigned int* Xb = Cb + (size_t)NNODE * 64;                    // [N,128] bf16
  float* als  = (float*)(Xb + (size_t)NNODE * 64);
  float* ald  = als + NNODE;
  float* u    = ald + NNODE;
  float* v    = u + DIM;
  unsigned short* Wz0 = (unsigned short*)(v + DIM);              // 128*256 bf16
  unsigned short* Wz1 = Wz0 + 128 * 256;
  unsigned short* Wz2 = Wz1 + 128 * 256;
  int*   rp   = (int*)(Wz2 + 128 * 256);    // NNODE+1
  int*   gcount = rp + (NNODE + 1);         // NBUCK
  int*   gbase  = gcount + NBUCK;           // NBUCK+1
  int*   gcur   = gbase + (NBUCK + 1);      // NBUCK
  unsigned int* packed = (unsigned int*)(gcur + NBUCK);          // NEDGE
  unsigned short* es   = (unsigned short*)(packed + NEDGE);      // NEDGE

  // ---- CSR by dst: 2-level bucket sort (rebuilt every launch) ----
  hipMemsetAsync(gcount, 0, NBUCK * sizeof(int), stream);
  bhist_k<<<NB1, 256, 0, stream>>>(ei + NEDGE, gcount);
  bscan_k<<<1, 256, 0, stream>>>(gcount, gbase, gcur, rp);
  bucket_k<<<NB1, 256, 0, stream>>>(ei, gcur, packed);
  build_k<<<NBUCK, 256, 0, stream>>>(gbase, packed, rp, es);

  dim3 b(256);
  dim3 gn((NNODE + 3) / 4);

  // ---- prep ----
  cvt_k<<<(NNODE * 64 + 255) / 256, b, 0, stream>>>(x, Xb);
  prep_k<<<16, b, 0, stream>>>(w0s, wl0, Wz0);
  prep_k<<<16, b, 0, stream>>>(w1, wl1, Wz1);
  prep_k<<<16, b, 0, stream>>>(w2, wl2, Wz2);
  mv2_k<<<64, 256, 0, stream>>>(w0s, a0s, w0d, a0d, u, v);

  // ---- layer 0 ----
  dualmv_k<<<gn, b, 0, stream>>>(x, u, v, als, ald);             // logits (exact)
  mfma_k<0,0><<<GBLK, b, 0, stream>>>((const unsigned short*)Xb, nullptr, nullptr,
                                      Wz0, bl0, nullptr, nullptr,
                                      (unsigned short*)Ab, LA, nullptr, nullptr);
  gat_k<<<gn, b, 0, stream>>>(rp, es, als, ald, Ab, bc0, Cb);

  // ---- layer 1: h1 = relu(Cb + LA) fused; logits in epilogue ----
  mfma_k<1,1><<<GBLK, b, 0, stream>>>(nullptr, Cb, LA,
                                      Wz1, bl1, a1s, a1d,
                                      (unsigned short*)Ab, LB, als, ald);
  gat_k<<<gn, b, 0, stream>>>(rp, es, als, ald, Ab, bc1, Cb);

  // ---- layer 2: h2 = relu(Cb + LB) fused ----
  mfma_k<1,1><<<GBLK, b, 0, stream>>>(nullptr, Cb, LB,
                                      Wz2, bl2, a2s, a2d,
                                      (unsigned short*)Ab, LA, als, ald);
  gat_k<<<gn, b, 0, stream>>>(rp, es, als, ald, Ab, bc2, Cb);

  // ---- head: h3 = Cb + LA (no relu) ----
  head_k<<<dim3((NNODE + 63) / 64), b, 0, stream>>>(Cb, LA, wh, bh, out);
}

// Round 9
// 371.860 us; speedup vs baseline: 2.5077x; 1.0008x over previous
//
#include <hip/hip_runtime.h>

#define NNODE 50000
#define NEDGE 800000
#define DIM   128
#define HEADD 64
#define NEG   0.2f
#define NBUCK 196          // dst>>8 buckets (49999>>8 = 195)
#define EPB1  2048         // edges per block in pass-1 kernels
#define NB1   391          // ceil(NEDGE/EPB1)
#define GBLK  782          // ceil(NNODE/64) row-blocks for mfma GEMM

typedef __attribute__((ext_vector_type(8))) short bf16x8;
typedef __attribute__((ext_vector_type(4))) float f32x4;

__device__ __forceinline__ float wmax(float v){
  #pragma unroll
  for (int m = 32; m > 0; m >>= 1) v = fmaxf(v, __shfl_xor(v, m));
  return v;
}
__device__ __forceinline__ float wsum(float v){
  #pragma unroll
  for (int m = 32; m > 0; m >>= 1) v += __shfl_xor(v, m);
  return v;
}
// fp32 -> bf16 bits, round-to-nearest-even (finite inputs)
__device__ __forceinline__ unsigned short f2bf(float f){
  unsigned int x = __float_as_uint(f);
  return (unsigned short)((x + 0x7fffu + ((x >> 16) & 1u)) >> 16);
}
__device__ __forceinline__ float bflo(unsigned u){ return __uint_as_float(u << 16); }
__device__ __forceinline__ float bfhi(unsigned u){ return __uint_as_float(u & 0xffff0000u); }

// ---------------- CSR build: 2-level bucket sort ----------------
__global__ __launch_bounds__(256) void bhist_k(const int* __restrict__ dst,
                                               int* __restrict__ gcount){
  __shared__ int h[NBUCK];
  for (int i = threadIdx.x; i < NBUCK; i += 256) h[i] = 0;
  __syncthreads();
  int e0 = blockIdx.x * EPB1 + threadIdx.x;
  #pragma unroll
  for (int i = 0; i < 8; ++i){
    int e = e0 + i * 256;
    if (e < NEDGE) atomicAdd(&h[dst[e] >> 8], 1);
  }
  __syncthreads();
  for (int i = threadIdx.x; i < NBUCK; i += 256)
    if (h[i]) atomicAdd(&gcount[i], h[i]);
}

__global__ __launch_bounds__(256) void bscan_k(const int* __restrict__ gcount,
                                               int* __restrict__ gbase,
                                               int* __restrict__ gcur,
                                               int* __restrict__ rp){
  __shared__ int sd[256];
  int t = threadIdx.x;
  int v = (t < NBUCK) ? gcount[t] : 0;
  sd[t] = v; __syncthreads();
  #pragma unroll
  for (int off = 1; off < 256; off <<= 1){
    int u = (t >= off) ? sd[t - off] : 0;
    __syncthreads();
    sd[t] += u;
    __syncthreads();
  }
  int ex = sd[t] - v;
  if (t < NBUCK){ gbase[t] = ex; gcur[t] = ex; }
  if (t == NBUCK - 1) gbase[NBUCK] = sd[t];
  if (t == 0) rp[NNODE] = NEDGE;
}

__global__ __launch_bounds__(256) void bucket_k(const int* __restrict__ ei,
                                                int* __restrict__ gcur,
                                                unsigned int* __restrict__ packed){
  __shared__ int lh[NBUCK], lbase[NBUCK], lcur[NBUCK];
  for (int i = threadIdx.x; i < NBUCK; i += 256) lh[i] = 0;
  __syncthreads();
  unsigned int pk[8]; int bk[8];
  int e0 = blockIdx.x * EPB1 + threadIdx.x;
  #pragma unroll
  for (int i = 0; i < 8; ++i){
    int e = e0 + i * 256;
    bk[i] = -1;
    if (e < NEDGE){
      int s = ei[e], d = ei[NEDGE + e];
      pk[i] = ((unsigned)d << 16) | (unsigned)s;
      bk[i] = d >> 8;
      atomicAdd(&lh[bk[i]], 1);
    }
  }
  __syncthreads();
  for (int i = threadIdx.x; i < NBUCK; i += 256){
    lbase[i] = atomicAdd(&gcur[i], lh[i]);
    lcur[i] = 0;
  }
  __syncthreads();
  #pragma unroll
  for (int i = 0; i < 8; ++i){
    if (bk[i] >= 0){
      int p = lbase[bk[i]] + atomicAdd(&lcur[bk[i]], 1);
      packed[p] = pk[i];
    }
  }
}

__global__ __launch_bounds__(256) void build_k(const int* __restrict__ gbase,
                                               const unsigned int* __restrict__ packed,
                                               int* __restrict__ rp,
                                               unsigned short* __restrict__ es){
  __shared__ int h[256], sd[256], cur[256];
  int b = blockIdx.x, t = threadIdx.x;
  int s0 = gbase[b], s1 = gbase[b + 1];
  h[t] = 0; __syncthreads();
  for (int i = s0 + t; i < s1; i += 256)
    atomicAdd(&h[(packed[i] >> 16) & 255], 1);
  __syncthreads();
  int v = h[t]; sd[t] = v; __syncthreads();
  #pragma unroll
  for (int off = 1; off < 256; off <<= 1){
    int u = (t >= off) ? sd[t - off] : 0;
    __syncthreads();
    sd[t] += u;
    __syncthreads();
  }
  int ex = sd[t] - v;
  cur[t] = ex;
  int d = b * 256 + t;
  if (d < NNODE) rp[d] = s0 + ex;
  __syncthreads();
  for (int i = s0 + t; i < s1; i += 256){
    unsigned int p = packed[i];
    int ld = (p >> 16) & 255;
    int pos = atomicAdd(&cur[ld], 1);
    es[s0 + pos] = (unsigned short)(p & 0xffffu);
  }
}

// ------- prep3: swizzle 3 layers' (Wa|Wl) f32 -> B-frag-linear bf16 -------
__global__ __launch_bounds__(256) void prep3_k(const float* __restrict__ w0a,
                                               const float* __restrict__ w0l,
                                               const float* __restrict__ w1a,
                                               const float* __restrict__ w1l,
                                               const float* __restrict__ w2a,
                                               const float* __restrict__ w2l,
                                               unsigned short* __restrict__ Wz){
  int layer = blockIdx.x >> 4;
  int g = (blockIdx.x & 15) * 256 + threadIdx.x;   // 0..4095
  int ct = g >> 8, q = (g >> 6) & 3, lane = g & 63;
  int n = lane & 15, quad = lane >> 4;
  const float* W;
  if (layer == 0)      W = (ct < 8) ? w0a : w0l;
  else if (layer == 1) W = (ct < 8) ? w1a : w1l;
  else                 W = (ct < 8) ? w2a : w2l;
  int c = (ct & 7) * 16 + n;
  unsigned short* dst = Wz + (size_t)layer * 32768 +
                        ((size_t)(ct * 4 + q) * 64 + lane) * 8;
  #pragma unroll
  for (int j = 0; j < 8; ++j){
    int k = q * 32 + quad * 8 + j;
    dst[j] = f2bf(W[k * 128 + c]);
  }
}

// ------- cvt + layer-0 logits fused: Xb = bf16(x); als/ald = x@u, x@v -------
__global__ __launch_bounds__(256) void cvtdual_k(const float* __restrict__ X,
                                                 const float* __restrict__ u,
                                                 const float* __restrict__ v,
                                                 unsigned int* __restrict__ Xb,
                                                 float* __restrict__ als,
                                                 float* __restrict__ ald){
  int lane = threadIdx.x & 63;
  int n = blockIdx.x * 4 + (threadIdx.x >> 6);
  if (n >= NNODE) return;
  float2 xv = ((const float2*)(X + (size_t)n * DIM))[lane];
  Xb[(size_t)n * 64 + lane] = (unsigned)f2bf(xv.x) | ((unsigned)f2bf(xv.y) << 16);
  float2 uu = ((const float2*)u)[lane];
  float2 vv = ((const float2*)v)[lane];
  float s1 = wsum(xv.x * uu.x + xv.y * uu.y);
  float s2 = wsum(xv.x * vv.x + xv.y * vv.y);
  if (lane == 0){ als[n] = s1; ald[n] = s2; }
}

// ------- fused MFMA GEMM; weights staged in LDS ------------------------
// FUSE=0: A-input = Xb (bf16 rows). FUSE=1: A-input row = relu(Cb + Lin).
// Outputs: Aout bf16 = h@Wa, Lout f32 = h@Wl + bl.
// LOGITS=1: als/ald = (h@Wa)@as_/ad_ via fp32 epilogue reduction.
template<int FUSE, int LOGITS>
__global__ __launch_bounds__(256) void mfma_k(const unsigned short* __restrict__ Xb,
                                              const unsigned int* __restrict__ Cb,
                                              const float* __restrict__ Lin,
                                              const unsigned short* __restrict__ Wz,
                                              const float* __restrict__ bl,
                                              const float* __restrict__ as_,
                                              const float* __restrict__ ad_,
                                              unsigned short* __restrict__ Aout,
                                              float* __restrict__ Lout,
                                              float* __restrict__ als,
                                              float* __restrict__ ald){
  __shared__ unsigned short wls[32768];   // 64 KB: full swizzled (Wa|Wl)
  {
    const uint4* src = (const uint4*)Wz;
    uint4* dst = (uint4*)wls;
    #pragma unroll
    for (int i = 0; i < 16; ++i)
      dst[i * 256 + threadIdx.x] = src[i * 256 + threadIdx.x];
  }

  int lane = threadIdx.x & 63;
  int wid  = threadIdx.x >> 6;
  int r0   = blockIdx.x * 64 + wid * 16;
  int quad = lane >> 4;
  int col  = lane & 15;

  int rA = r0 + col; if (rA > NNODE - 1) rA = NNODE - 1;
  bf16x8 a[4];
  if (FUSE){
    const uint4*   c4 = (const uint4*)(Cb + (size_t)rA * 64);
    const float4*  l4 = (const float4*)(Lin + (size_t)rA * 128);
    #pragma unroll
    for (int q = 0; q < 4; ++q){
      int kb = q * 32 + quad * 8;          // element base, multiple of 8
      uint4  cc = c4[kb >> 3];
      float4 la = l4[kb >> 2];
      float4 lb = l4[(kb >> 2) + 1];
      float h0 = fmaxf(bflo(cc.x) + la.x, 0.f);
      float h1 = fmaxf(bfhi(cc.x) + la.y, 0.f);
      float h2 = fmaxf(bflo(cc.y) + la.z, 0.f);
      float h3 = fmaxf(bfhi(cc.y) + la.w, 0.f);
      float h4 = fmaxf(bflo(cc.z) + lb.x, 0.f);
      float h5 = fmaxf(bfhi(cc.z) + lb.y, 0.f);
      float h6 = fmaxf(bflo(cc.w) + lb.z, 0.f);
      float h7 = fmaxf(bfhi(cc.w) + lb.w, 0.f);
      bf16x8 av;
      av[0] = (short)f2bf(h0); av[1] = (short)f2bf(h1);
      av[2] = (short)f2bf(h2); av[3] = (short)f2bf(h3);
      av[4] = (short)f2bf(h4); av[5] = (short)f2bf(h5);
      av[6] = (short)f2bf(h6); av[7] = (short)f2bf(h7);
      a[q] = av;
    }
  } else {
    const bf16x8* xrow = (const bf16x8*)(Xb + (size_t)rA * 128);
    #pragma unroll
    for (int q = 0; q < 4; ++q) a[q] = xrow[q * 4 + quad];
  }

  __syncthreads();                        // weights staged
  const bf16x8* wz = (const bf16x8*)wls;  // LDS reads (ds_read_b128)
  int rowq = r0 + quad * 4;
  float alsp[4] = {0.f, 0.f, 0.f, 0.f};
  float aldp[4] = {0.f, 0.f, 0.f, 0.f};

  #pragma unroll
  for (int ct = 0; ct < 16; ++ct){
    f32x4 acc = {0.f, 0.f, 0.f, 0.f};
    #pragma unroll
    for (int q = 0; q < 4; ++q){
      bf16x8 bfr = wz[(ct * 4 + q) * 64 + lane];
      acc = __builtin_amdgcn_mfma_f32_16x16x32_bf16(a[q], bfr, acc, 0, 0, 0);
    }
    if (ct < 8){
      int c = ct * 16 + col;
      if (LOGITS){
        float asv = as_[c], adv = ad_[c];
        #pragma unroll
        for (int r = 0; r < 4; ++r){
          alsp[r] = fmaf(acc[r], asv, alsp[r]);
          aldp[r] = fmaf(acc[r], adv, aldp[r]);
        }
      }
      #pragma unroll
      for (int r = 0; r < 4; ++r){
        int row = rowq + r;
        if (row < NNODE) Aout[(size_t)row * 128 + c] = f2bf(acc[r]);
      }
    } else {
      int c = (ct - 8) * 16 + col;
      float bb = bl[c];
      #pragma unroll
      for (int r = 0; r < 4; ++r){
        int row = rowq + r;
        if (row < NNODE) Lout[(size_t)row * 128 + c] = acc[r] + bb;
      }
    }
  }

  if (LOGITS){
    #pragma unroll
    for (int m = 1; m < 16; m <<= 1){
      #pragma unroll
      for (int r = 0; r < 4; ++r){
        alsp[r] += __shfl_xor(alsp[r], m);
        aldp[r] += __shfl_xor(aldp[r], m);
      }
    }
    if (col == 0){
      #pragma unroll
      for (int r = 0; r < 4; ++r){
        int row = rowq + r;
        if (row < NNODE){ als[row] = alsp[r]; ald[row] = aldp[r]; }
      }
    }
  }
}

// ------- head: out[N,64] = (Cb + L2) @ Wh + bh (fp32 vector, no relu) -------
__global__ __launch_bounds__(256) void head_k(const unsigned int* __restrict__ Cb,
                                              const float* __restrict__ L,
                                              const float* __restrict__ W,
                                              const float* __restrict__ bias,
                                              float* __restrict__ outp){
  const int BN = 64, TM = 2;
  const int TX = BN / 8;           // 8
  const int TY = 256 / TX;         // 32
  const int BM = TY * TM;          // 64
  __shared__ float ws[128 * BN];
  int tid = threadIdx.x;
  {
    const float4* W4 = (const float4*)W;
    float4* ws4 = (float4*)ws;
    #pragma unroll
    for (int i = 0; i < (128 * BN / 4) / 256; ++i)
      ws4[i * 256 + tid] = W4[i * 256 + tid];
  }
  __syncthreads();

  int tx = tid % TX, ty = tid / TX;
  int n0 = tx * 8;
  int bm0 = blockIdx.x * BM;
  int rc[TM];
  #pragma unroll
  for (int i = 0; i < TM; ++i){
    int r = bm0 + ty * TM + i;
    rc[i] = r < NNODE ? r : NNODE - 1;
  }
  float acc[TM][8];
  #pragma unroll
  for (int i = 0; i < TM; ++i)
    #pragma unroll
    for (int j = 0; j < 8; ++j) acc[i][j] = 0.f;

  const float4* L4 = (const float4*)L;
  const uint2*  C2 = (const uint2*)Cb;
  #pragma unroll 2
  for (int kq = 0; kq < 32; ++kq){
    float4 xa[TM];
    #pragma unroll
    for (int i = 0; i < TM; ++i){
      float4 la = L4[(size_t)rc[i] * 32 + kq];
      uint2  cu = C2[(size_t)rc[i] * 32 + kq];
      xa[i] = make_float4(la.x + bflo(cu.x), la.y + bfhi(cu.x),
                          la.z + bflo(cu.y), la.w + bfhi(cu.y));
    }
    #pragma unroll
    for (int kk = 0; kk < 4; ++kk){
      const float* bp = &ws[(kq * 4 + kk) * BN + n0];
      float4 b0 = *(const float4*)bp;
      float4 b1 = *(const float4*)(bp + 4);
      float bv[8] = {b0.x, b0.y, b0.z, b0.w, b1.x, b1.y, b1.z, b1.w};
      #pragma unroll
      for (int i = 0; i < TM; ++i){
        float av = ((const float*)&xa[i])[kk];
        #pragma unroll
        for (int j = 0; j < 8; ++j) acc[i][j] = fmaf(av, bv[j], acc[i][j]);
      }
    }
  }
  float bb[8];
  #pragma unroll
  for (int j = 0; j < 8; ++j) bb[j] = bias[n0 + j];
  #pragma unroll
  for (int i = 0; i < TM; ++i){
    int row = bm0 + ty * TM + i;
    if (row < NNODE){
      float4 o0 = make_float4(acc[i][0] + bb[0], acc[i][1] + bb[1],
                              acc[i][2] + bb[2], acc[i][3] + bb[3]);
      float4 o1 = make_float4(acc[i][4] + bb[4], acc[i][5] + bb[5],
                              acc[i][6] + bb[6], acc[i][7] + bb[7]);
      ((float4*)outp)[(size_t)row * (BN / 4) + tx * 2]     = o0;
      ((float4*)outp)[(size_t)row * (BN / 4) + tx * 2 + 1] = o1;
    }
  }
}

// ------- batched matvec: u = Wa @ aa, v = Wb @ ab (layer 0 only) -------
__global__ void mv2_k(const float* __restrict__ Wa, const float* __restrict__ aa,
                      const float* __restrict__ Wb, const float* __restrict__ ab,
                      float* __restrict__ u, float* __restrict__ v){
  int lane = threadIdx.x & 63;
  int r = blockIdx.x * 4 + (threadIdx.x >> 6);
  if (r >= 256) return;
  const float* W = (r < 128) ? Wa : Wb;
  const float* a = (r < 128) ? aa : ab;
  int rr = r & 127;
  float2 w = ((const float2*)(W + rr * DIM))[lane];
  float2 av = ((const float2*)a)[lane];
  float s = wsum(w.x * av.x + w.y * av.y);
  if (lane == 0){ if (r < 128) u[rr] = s; else v[rr] = s; }
}

// ---------------- GAT softmax-aggregate -> Cb = conv + bc (bf16) ----------------
__global__ __launch_bounds__(256) void gat_k(const int* __restrict__ rp,
                                             const unsigned short* __restrict__ es,
                                             const float* __restrict__ als,
                                             const float* __restrict__ ald,
                                             const unsigned int* __restrict__ A,
                                             const float* __restrict__ bc,
                                             unsigned int* __restrict__ Cb){
  int lane = threadIdx.x & 63;
  int n = blockIdx.x * 4 + (threadIdx.x >> 6);
  if (n >= NNODE) return;
  int start = rp[n], end = rp[n + 1];
  int deg = end - start;
  float ad = ald[n];
  float2 acc = make_float2(0.f, 0.f);
  float rinv = 0.f;

  if (deg <= 64){
    int s = 0; float z = -3.0e38f;
    if (lane < deg){
      s = es[start + lane];
      float t = als[s] + ad;
      z = t > 0.f ? t : NEG * t;
    }
    float m = wmax(z);
    float e = (lane < deg) ? __expf(z - m) : 0.f;
    float denom = wsum(e);
    rinv = (deg > 0) ? 1.f / denom : 0.f;
    int dq = (deg + 7) & ~7;                  // pad loads hit row 0, weight 0
    for (int j = 0; j < dq; j += 8){
      int   s0 = __shfl(s, j),     s1 = __shfl(s, j + 1);
      int   s2 = __shfl(s, j + 2), s3 = __shfl(s, j + 3);
      int   s4 = __shfl(s, j + 4), s5 = __shfl(s, j + 5);
      int   s6 = __shfl(s, j + 6), s7 = __shfl(s, j + 7);
      float w0 = __shfl(e, j),     w1 = __shfl(e, j + 1);
      float w2 = __shfl(e, j + 2), w3 = __shfl(e, j + 3);
      float w4 = __shfl(e, j + 4), w5 = __shfl(e, j + 5);
      float w6 = __shfl(e, j + 6), w7 = __shfl(e, j + 7);
      unsigned p0 = A[(size_t)s0 * 64 + lane];
      unsigned p1 = A[(size_t)s1 * 64 + lane];
      unsigned p2 = A[(size_t)s2 * 64 + lane];
      unsigned p3 = A[(size_t)s3 * 64 + lane];
      unsigned p4 = A[(size_t)s4 * 64 + lane];
      unsigned p5 = A[(size_t)s5 * 64 + lane];
      unsigned p6 = A[(size_t)s6 * 64 + lane];
      unsigned p7 = A[(size_t)s7 * 64 + lane];
      acc.x = fmaf(w0, bflo(p0), acc.x); acc.y = fmaf(w0, bfhi(p0), acc.y);
      acc.x = fmaf(w1, bflo(p1), acc.x); acc.y = fmaf(w1, bfhi(p1), acc.y);
      acc.x = fmaf(w2, bflo(p2), acc.x); acc.y = fmaf(w2, bfhi(p2), acc.y);
      acc.x = fmaf(w3, bflo(p3), acc.x); acc.y = fmaf(w3, bfhi(p3), acc.y);
      acc.x = fmaf(w4, bflo(p4), acc.x); acc.y = fmaf(w4, bfhi(p4), acc.y);
      acc.x = fmaf(w5, bflo(p5), acc.x); acc.y = fmaf(w5, bfhi(p5), acc.y);
      acc.x = fmaf(w6, bflo(p6), acc.x); acc.y = fmaf(w6, bfhi(p6), acc.y);
      acc.x = fmaf(w7, bflo(p7), acc.x); acc.y = fmaf(w7, bfhi(p7), acc.y);
    }
  } else {
    float mloc = -3.0e38f;
    for (int i = start + lane; i < end; i += 64){
      int s = es[i];
      float zz = als[s] + ad;
      zz = zz > 0.f ? zz : NEG * zz;
      mloc = fmaxf(mloc, zz);
    }
    float m = wmax(mloc);
    float dloc = 0.f;
    for (int i = start + lane; i < end; i += 64){
      int s = es[i];
      float zz = als[s] + ad;
      zz = zz > 0.f ? zz : NEG * zz;
      dloc += __expf(zz - m);
    }
    rinv = 1.f / wsum(dloc);
    for (int i = start; i < end; ++i){
      int s = es[i];
      float zz = als[s] + ad;
      zz = zz > 0.f ? zz : NEG * zz;
      float w = __expf(zz - m);
      unsigned p = A[(size_t)s * 64 + lane];
      acc.x = fmaf(w, bflo(p), acc.x);
      acc.y = fmaf(w, bfhi(p), acc.y);
    }
  }

  int c = lane * 2;
  float cx = fmaf(acc.x, rinv, bc[c]);
  float cy = fmaf(acc.y, rinv, bc[c + 1]);
  Cb[(size_t)n * 64 + lane] = (unsigned)f2bf(cx) | ((unsigned)f2bf(cy) << 16);
}

extern "C" void kernel_launch(void* const* d_in, const int* in_sizes, int n_in,
                              void* d_out, int out_size, void* d_ws, size_t ws_size,
                              hipStream_t stream){
  const float* x   = (const float*)d_in[0];
  const int*   ei  = (const int*)d_in[1];
  const float* w0s = (const float*)d_in[2];
  const float* w0d = (const float*)d_in[3];
  const float* a0s = (const float*)d_in[4];
  const float* a0d = (const float*)d_in[5];
  const float* bc0 = (const float*)d_in[6];
  const float* wl0 = (const float*)d_in[7];
  const float* bl0 = (const float*)d_in[8];
  const float* w1  = (const float*)d_in[9];
  const float* a1s = (const float*)d_in[10];
  const float* a1d = (const float*)d_in[11];
  const float* bc1 = (const float*)d_in[12];
  const float* wl1 = (const float*)d_in[13];
  const float* bl1 = (const float*)d_in[14];
  const float* w2  = (const float*)d_in[15];
  const float* a2s = (const float*)d_in[16];
  const float* a2d = (const float*)d_in[17];
  const float* bc2 = (const float*)d_in[18];
  const float* wl2 = (const float*)d_in[19];
  const float* bl2 = (const float*)d_in[20];
  const float* wh  = (const float*)d_in[21];
  const float* bh  = (const float*)d_in[22];
  float* out = (float*)d_out;

  unsigned int* Ab = (unsigned int*)d_ws;                        // [N,128] bf16
  float* LA   = (float*)(Ab + (size_t)NNODE * 64);               // [N,128] f32
  float* LB   = LA + (size_t)NNODE * DIM;                        // [N,128] f32
  unsigned int* Cb = (unsigned int*)(LB + (size_t)NNODE * DIM);  // [N,128] bf16
  unsigned int* Xb = Cb + (size_t)NNODE * 64;                    // [N,128] bf16
  float* als  = (float*)(Xb + (size_t)NNODE * 64);
  float* ald  = als + NNODE;
  float* u    = ald + NNODE;
  float* v    = u + DIM;
  unsigned short* Wz = (unsigned short*)(v + DIM);               // 3 * 32768 bf16
  int*   rp   = (int*)(Wz + 3 * 32768);     // NNODE+1
  int*   gcount = rp + (NNODE + 1);         // NBUCK
  int*   gbase  = gcount + NBUCK;           // NBUCK+1
  int*   gcur   = gbase + (NBUCK + 1);      // NBUCK
  unsigned int* packed = (unsigned int*)(gcur + NBUCK);          // NEDGE
  unsigned short* es   = (unsigned short*)(packed + NEDGE);      // NEDGE

  // ---- CSR by dst: 2-level bucket sort (rebuilt every launch) ----
  hipMemsetAsync(gcount, 0, NBUCK * sizeof(int), stream);
  bhist_k<<<NB1, 256, 0, stream>>>(ei + NEDGE, gcount);
  bscan_k<<<1, 256, 0, stream>>>(gcount, gbase, gcur, rp);
  bucket_k<<<NB1, 256, 0, stream>>>(ei, gcur, packed);
  build_k<<<NBUCK, 256, 0, stream>>>(gbase, packed, rp, es);

  dim3 b(256);
  dim3 gn((NNODE + 3) / 4);

  // ---- prep ----
  prep3_k<<<48, b, 0, stream>>>(w0s, wl0, w1, wl1, w2, wl2, Wz);
  mv2_k<<<64, 256, 0, stream>>>(w0s, a0s, w0d, a0d, u, v);
  cvtdual_k<<<gn, b, 0, stream>>>(x, u, v, Xb, als, ald);        // Xb + layer-0 logits

  // ---- layer 0 ----
  mfma_k<0,0><<<GBLK, b, 0, stream>>>((const unsigned short*)Xb, nullptr, nullptr,
                                      Wz, bl0, nullptr, nullptr,
                                      (unsigned short*)Ab, LA, nullptr, nullptr);
  gat_k<<<gn, b, 0, stream>>>(rp, es, als, ald, Ab, bc0, Cb);

  // ---- layer 1: h1 = relu(Cb + LA) fused; logits in epilogue ----
  mfma_k<1,1><<<GBLK, b, 0, stream>>>(nullptr, Cb, LA,
                                      Wz + 32768, bl1, a1s, a1d,
                                      (unsigned short*)Ab, LB, als, ald);
  gat_k<<<gn, b, 0, stream>>>(rp, es, als, ald, Ab, bc1, Cb);

  // ---- layer 2: h2 = relu(Cb + LB) fused ----
  mfma_k<1,1><<<GBLK, b, 0, stream>>>(nullptr, Cb, LB,
                                      Wz + 2 * 32768, bl2, a2s, a2d,
                                      (unsigned short*)Ab, LA, als, ald);
  gat_k<<<gn, b, 0, stream>>>(rp, es, als, ald, Ab, bc2, Cb);

  // ---- head: h3 = Cb + LA (no relu) ----
  head_k<<<dim3((NNODE + 63) / 64), b, 0, stream>>>(Cb, LA, wh, bh, out);
}

// Round 10
// 346.719 us; speedup vs baseline: 2.6896x; 1.0725x over previous
//
#include <hip/hip_runtime.h>

#define NNODE 50000
#define NEDGE 800000
#define DIM   128
#define HEADD 64
#define NEG   0.2f
#define NBUCK 196          // dst>>8 buckets (49999>>8 = 195)
#define EPB1  2048         // edges per block in pass-1 kernels
#define NB1   391          // ceil(NEDGE/EPB1)
#define GBLK  782          // ceil(NNODE/64) row-blocks for mfma GEMM

typedef __attribute__((ext_vector_type(8))) short bf16x8;
typedef __attribute__((ext_vector_type(4))) float f32x4;

__device__ __forceinline__ float wmax(float v){
  #pragma unroll
  for (int m = 32; m > 0; m >>= 1) v = fmaxf(v, __shfl_xor(v, m));
  return v;
}
__device__ __forceinline__ float wsum(float v){
  #pragma unroll
  for (int m = 32; m > 0; m >>= 1) v += __shfl_xor(v, m);
  return v;
}
// fp32 -> bf16 bits, round-to-nearest-even (finite inputs)
__device__ __forceinline__ unsigned short f2bf(float f){
  unsigned int x = __float_as_uint(f);
  return (unsigned short)((x + 0x7fffu + ((x >> 16) & 1u)) >> 16);
}
__device__ __forceinline__ float bflo(unsigned u){ return __uint_as_float(u << 16); }
__device__ __forceinline__ float bfhi(unsigned u){ return __uint_as_float(u & 0xffff0000u); }

// ---------------- CSR build: radix-style, NO global atomics ----------------
// 1) per-(bucket,block) counts
__global__ __launch_bounds__(256) void bhist2_k(const int* __restrict__ dst,
                                                int* __restrict__ cnt){
  __shared__ int h[NBUCK];
  for (int i = threadIdx.x; i < NBUCK; i += 256) h[i] = 0;
  __syncthreads();
  int e0 = blockIdx.x * EPB1 + threadIdx.x;
  #pragma unroll
  for (int i = 0; i < 8; ++i){
    int e = e0 + i * 256;
    if (e < NEDGE) atomicAdd(&h[dst[e] >> 8], 1);
  }
  __syncthreads();
  for (int i = threadIdx.x; i < NBUCK; i += 256)
    cnt[i * NB1 + blockIdx.x] = h[i];
}

// 2) exclusive scan each bucket's 391 counts -> cbase; row total -> btot
__global__ __launch_bounds__(256) void scan196_k(const int* __restrict__ cnt,
                                                 int* __restrict__ cbase,
                                                 int* __restrict__ btot){
  __shared__ int sd[256];
  int b = blockIdx.x, t = threadIdx.x;
  const int* row = cnt + (size_t)b * NB1;
  int i0 = t * 2, i1 = t * 2 + 1;
  int v0 = (i0 < NB1) ? row[i0] : 0;
  int v1 = (i1 < NB1) ? row[i1] : 0;
  int s = v0 + v1;
  sd[t] = s; __syncthreads();
  #pragma unroll
  for (int off = 1; off < 256; off <<= 1){
    int u = (t >= off) ? sd[t - off] : 0;
    __syncthreads();
    sd[t] += u;
    __syncthreads();
  }
  int ex = sd[t] - s;
  if (i0 < NB1) cbase[(size_t)b * NB1 + i0] = ex;
  if (i1 < NB1) cbase[(size_t)b * NB1 + i1] = ex + v0;
  if (t == 255) btot[b] = sd[255];
}

// 3) scan bucket totals -> gbase (exclusive); also rp[NNODE]=NEDGE
__global__ __launch_bounds__(256) void bscan2_k(const int* __restrict__ btot,
                                                int* __restrict__ gbase,
                                                int* __restrict__ rp){
  __shared__ int sd[256];
  int t = threadIdx.x;
  int v = (t < NBUCK) ? btot[t] : 0;
  sd[t] = v; __syncthreads();
  #pragma unroll
  for (int off = 1; off < 256; off <<= 1){
    int u = (t >= off) ? sd[t - off] : 0;
    __syncthreads();
    sd[t] += u;
    __syncthreads();
  }
  if (t < NBUCK) gbase[t] = sd[t] - v;
  if (t == NBUCK - 1) gbase[NBUCK] = sd[t];
  if (t == 0) rp[NNODE] = NEDGE;
}

// 4) scatter packed (dst<<16|src) at deterministic positions (LDS atomics only)
__global__ __launch_bounds__(256) void scat2_k(const int* __restrict__ ei,
                                               const int* __restrict__ gbase,
                                               const int* __restrict__ cbase,
                                               unsigned int* __restrict__ packed){
  __shared__ int lcur[NBUCK];
  for (int i = threadIdx.x; i < NBUCK; i += 256) lcur[i] = 0;
  __syncthreads();
  int e0 = blockIdx.x * EPB1 + threadIdx.x;
  #pragma unroll
  for (int i = 0; i < 8; ++i){
    int e = e0 + i * 256;
    if (e < NEDGE){
      int s = ei[e], d = ei[NEDGE + e];
      int b = d >> 8;
      int r = atomicAdd(&lcur[b], 1);
      int pos = gbase[b] + cbase[(size_t)b * NB1 + blockIdx.x] + r;
      packed[pos] = ((unsigned)d << 16) | (unsigned)s;
    }
  }
}

// 5) one block per bucket -> rp + es (ushort), block-private es region
__global__ __launch_bounds__(256) void build_k(const int* __restrict__ gbase,
                                               const unsigned int* __restrict__ packed,
                                               int* __restrict__ rp,
                                               unsigned short* __restrict__ es){
  __shared__ int h[256], sd[256], cur[256];
  int b = blockIdx.x, t = threadIdx.x;
  int s0 = gbase[b], s1 = gbase[b + 1];
  h[t] = 0; __syncthreads();
  for (int i = s0 + t; i < s1; i += 256)
    atomicAdd(&h[(packed[i] >> 16) & 255], 1);
  __syncthreads();
  int v = h[t]; sd[t] = v; __syncthreads();
  #pragma unroll
  for (int off = 1; off < 256; off <<= 1){
    int u = (t >= off) ? sd[t - off] : 0;
    __syncthreads();
    sd[t] += u;
    __syncthreads();
  }
  int ex = sd[t] - v;
  cur[t] = ex;
  int d = b * 256 + t;
  if (d < NNODE) rp[d] = s0 + ex;
  __syncthreads();
  for (int i = s0 + t; i < s1; i += 256){
    unsigned int p = packed[i];
    int ld = (p >> 16) & 255;
    int pos = atomicAdd(&cur[ld], 1);
    es[s0 + pos] = (unsigned short)(p & 0xffffu);
  }
}

// ------- prep3: swizzle 3 layers' (Wa|Wl) f32 -> B-frag-linear bf16 -------
__global__ __launch_bounds__(256) void prep3_k(const float* __restrict__ w0a,
                                               const float* __restrict__ w0l,
                                               const float* __restrict__ w1a,
                                               const float* __restrict__ w1l,
                                               const float* __restrict__ w2a,
                                               const float* __restrict__ w2l,
                                               unsigned short* __restrict__ Wz){
  int layer = blockIdx.x >> 4;
  int g = (blockIdx.x & 15) * 256 + threadIdx.x;   // 0..4095
  int ct = g >> 8, q = (g >> 6) & 3, lane = g & 63;
  int n = lane & 15, quad = lane >> 4;
  const float* W;
  if (layer == 0)      W = (ct < 8) ? w0a : w0l;
  else if (layer == 1) W = (ct < 8) ? w1a : w1l;
  else                 W = (ct < 8) ? w2a : w2l;
  int c = (ct & 7) * 16 + n;
  unsigned short* dst = Wz + (size_t)layer * 32768 +
                        ((size_t)(ct * 4 + q) * 64 + lane) * 8;
  #pragma unroll
  for (int j = 0; j < 8; ++j){
    int k = q * 32 + quad * 8 + j;
    dst[j] = f2bf(W[k * 128 + c]);
  }
}

// ------- cvt + layer-0 logits fused: Xb = bf16(x); als/ald = x@u, x@v -------
__global__ __launch_bounds__(256) void cvtdual_k(const float* __restrict__ X,
                                                 const float* __restrict__ u,
                                                 const float* __restrict__ v,
                                                 unsigned int* __restrict__ Xb,
                                                 float* __restrict__ als,
                                                 float* __restrict__ ald){
  int lane = threadIdx.x & 63;
  int n = blockIdx.x * 4 + (threadIdx.x >> 6);
  if (n >= NNODE) return;
  float2 xv = ((const float2*)(X + (size_t)n * DIM))[lane];
  Xb[(size_t)n * 64 + lane] = (unsigned)f2bf(xv.x) | ((unsigned)f2bf(xv.y) << 16);
  float2 uu = ((const float2*)u)[lane];
  float2 vv = ((const float2*)v)[lane];
  float s1 = wsum(xv.x * uu.x + xv.y * uu.y);
  float s2 = wsum(xv.x * vv.x + xv.y * vv.y);
  if (lane == 0){ als[n] = s1; ald[n] = s2; }
}

// ------- fused MFMA GEMM; weights staged in LDS ------------------------
template<int FUSE, int LOGITS>
__global__ __launch_bounds__(256) void mfma_k(const unsigned short* __restrict__ Xb,
                                              const unsigned int* __restrict__ Cb,
                                              const float* __restrict__ Lin,
                                              const unsigned short* __restrict__ Wz,
                                              const float* __restrict__ bl,
                                              const float* __restrict__ as_,
                                              const float* __restrict__ ad_,
                                              unsigned short* __restrict__ Aout,
                                              float* __restrict__ Lout,
                                              float* __restrict__ als,
                                              float* __restrict__ ald){
  __shared__ unsigned short wls[32768];   // 64 KB: full swizzled (Wa|Wl)
  {
    const uint4* src = (const uint4*)Wz;
    uint4* dst = (uint4*)wls;
    #pragma unroll
    for (int i = 0; i < 16; ++i)
      dst[i * 256 + threadIdx.x] = src[i * 256 + threadIdx.x];
  }

  int lane = threadIdx.x & 63;
  int wid  = threadIdx.x >> 6;
  int r0   = blockIdx.x * 64 + wid * 16;
  int quad = lane >> 4;
  int col  = lane & 15;

  int rA = r0 + col; if (rA > NNODE - 1) rA = NNODE - 1;
  bf16x8 a[4];
  if (FUSE){
    const uint4*   c4 = (const uint4*)(Cb + (size_t)rA * 64);
    const float4*  l4 = (const float4*)(Lin + (size_t)rA * 128);
    #pragma unroll
    for (int q = 0; q < 4; ++q){
      int kb = q * 32 + quad * 8;          // element base, multiple of 8
      uint4  cc = c4[kb >> 3];
      float4 la = l4[kb >> 2];
      float4 lb = l4[(kb >> 2) + 1];
      float h0 = fmaxf(bflo(cc.x) + la.x, 0.f);
      float h1 = fmaxf(bfhi(cc.x) + la.y, 0.f);
      float h2 = fmaxf(bflo(cc.y) + la.z, 0.f);
      float h3 = fmaxf(bfhi(cc.y) + la.w, 0.f);
      float h4 = fmaxf(bflo(cc.z) + lb.x, 0.f);
      float h5 = fmaxf(bfhi(cc.z) + lb.y, 0.f);
      float h6 = fmaxf(bflo(cc.w) + lb.z, 0.f);
      float h7 = fmaxf(bfhi(cc.w) + lb.w, 0.f);
      bf16x8 av;
      av[0] = (short)f2bf(h0); av[1] = (short)f2bf(h1);
      av[2] = (short)f2bf(h2); av[3] = (short)f2bf(h3);
      av[4] = (short)f2bf(h4); av[5] = (short)f2bf(h5);
      av[6] = (short)f2bf(h6); av[7] = (short)f2bf(h7);
      a[q] = av;
    }
  } else {
    const bf16x8* xrow = (const bf16x8*)(Xb + (size_t)rA * 128);
    #pragma unroll
    for (int q = 0; q < 4; ++q) a[q] = xrow[q * 4 + quad];
  }

  __syncthreads();                        // weights staged
  const bf16x8* wz = (const bf16x8*)wls;  // LDS reads (ds_read_b128)
  int rowq = r0 + quad * 4;
  float alsp[4] = {0.f, 0.f, 0.f, 0.f};
  float aldp[4] = {0.f, 0.f, 0.f, 0.f};

  #pragma unroll
  for (int ct = 0; ct < 16; ++ct){
    f32x4 acc = {0.f, 0.f, 0.f, 0.f};
    #pragma unroll
    for (int q = 0; q < 4; ++q){
      bf16x8 bfr = wz[(ct * 4 + q) * 64 + lane];
      acc = __builtin_amdgcn_mfma_f32_16x16x32_bf16(a[q], bfr, acc, 0, 0, 0);
    }
    if (ct < 8){
      int c = ct * 16 + col;
      if (LOGITS){
        float asv = as_[c], adv = ad_[c];
        #pragma unroll
        for (int r = 0; r < 4; ++r){
          alsp[r] = fmaf(acc[r], asv, alsp[r]);
          aldp[r] = fmaf(acc[r], adv, aldp[r]);
        }
      }
      #pragma unroll
      for (int r = 0; r < 4; ++r){
        int row = rowq + r;
        if (row < NNODE) Aout[(size_t)row * 128 + c] = f2bf(acc[r]);
      }
    } else {
      int c = (ct - 8) * 16 + col;
      float bb = bl[c];
      #pragma unroll
      for (int r = 0; r < 4; ++r){
        int row = rowq + r;
        if (row < NNODE) Lout[(size_t)row * 128 + c] = acc[r] + bb;
      }
    }
  }

  if (LOGITS){
    #pragma unroll
    for (int m = 1; m < 16; m <<= 1){
      #pragma unroll
      for (int r = 0; r < 4; ++r){
        alsp[r] += __shfl_xor(alsp[r], m);
        aldp[r] += __shfl_xor(aldp[r], m);
      }
    }
    if (col == 0){
      #pragma unroll
      for (int r = 0; r < 4; ++r){
        int row = rowq + r;
        if (row < NNODE){ als[row] = alsp[r]; ald[row] = aldp[r]; }
      }
    }
  }
}

// ------- head: out[N,64] = (Cb + L2) @ Wh + bh (fp32 vector, no relu) -------
__global__ __launch_bounds__(256) void head_k(const unsigned int* __restrict__ Cb,
                                              const float* __restrict__ L,
                                              const float* __restrict__ W,
                                              const float* __restrict__ bias,
                                              float* __restrict__ outp){
  const int BN = 64, TM = 2;
  const int TX = BN / 8;           // 8
  const int TY = 256 / TX;         // 32
  const int BM = TY * TM;          // 64
  __shared__ float ws[128 * BN];
  int tid = threadIdx.x;
  {
    const float4* W4 = (const float4*)W;
    float4* ws4 = (float4*)ws;
    #pragma unroll
    for (int i = 0; i < (128 * BN / 4) / 256; ++i)
      ws4[i * 256 + tid] = W4[i * 256 + tid];
  }
  __syncthreads();

  int tx = tid % TX, ty = tid / TX;
  int n0 = tx * 8;
  int bm0 = blockIdx.x * BM;
  int rc[TM];
  #pragma unroll
  for (int i = 0; i < TM; ++i){
    int r = bm0 + ty * TM + i;
    rc[i] = r < NNODE ? r : NNODE - 1;
  }
  float acc[TM][8];
  #pragma unroll
  for (int i = 0; i < TM; ++i)
    #pragma unroll
    for (int j = 0; j < 8; ++j) acc[i][j] = 0.f;

  const float4* L4 = (const float4*)L;
  const uint2*  C2 = (const uint2*)Cb;
  #pragma unroll 2
  for (int kq = 0; kq < 32; ++kq){
    float4 xa[TM];
    #pragma unroll
    for (int i = 0; i < TM; ++i){
      float4 la = L4[(size_t)rc[i] * 32 + kq];
      uint2  cu = C2[(size_t)rc[i] * 32 + kq];
      xa[i] = make_float4(la.x + bflo(cu.x), la.y + bfhi(cu.x),
                          la.z + bflo(cu.y), la.w + bfhi(cu.y));
    }
    #pragma unroll
    for (int kk = 0; kk < 4; ++kk){
      const float* bp = &ws[(kq * 4 + kk) * BN + n0];
      float4 b0 = *(const float4*)bp;
      float4 b1 = *(const float4*)(bp + 4);
      float bv[8] = {b0.x, b0.y, b0.z, b0.w, b1.x, b1.y, b1.z, b1.w};
      #pragma unroll
      for (int i = 0; i < TM; ++i){
        float av = ((const float*)&xa[i])[kk];
        #pragma unroll
        for (int j = 0; j < 8; ++j) acc[i][j] = fmaf(av, bv[j], acc[i][j]);
      }
    }
  }
  float bb[8];
  #pragma unroll
  for (int j = 0; j < 8; ++j) bb[j] = bias[n0 + j];
  #pragma unroll
  for (int i = 0; i < TM; ++i){
    int row = bm0 + ty * TM + i;
    if (row < NNODE){
      float4 o0 = make_float4(acc[i][0] + bb[0], acc[i][1] + bb[1],
                              acc[i][2] + bb[2], acc[i][3] + bb[3]);
      float4 o1 = make_float4(acc[i][4] + bb[4], acc[i][5] + bb[5],
                              acc[i][6] + bb[6], acc[i][7] + bb[7]);
      ((float4*)outp)[(size_t)row * (BN / 4) + tx * 2]     = o0;
      ((float4*)outp)[(size_t)row * (BN / 4) + tx * 2 + 1] = o1;
    }
  }
}

// ------- batched matvec: u = Wa @ aa, v = Wb @ ab (layer 0 only) -------
__global__ void mv2_k(const float* __restrict__ Wa, const float* __restrict__ aa,
                      const float* __restrict__ Wb, const float* __restrict__ ab,
                      float* __restrict__ u, float* __restrict__ v){
  int lane = threadIdx.x & 63;
  int r = blockIdx.x * 4 + (threadIdx.x >> 6);
  if (r >= 256) return;
  const float* W = (r < 128) ? Wa : Wb;
  const float* a = (r < 128) ? aa : ab;
  int rr = r & 127;
  float2 w = ((const float2*)(W + rr * DIM))[lane];
  float2 av = ((const float2*)a)[lane];
  float s = wsum(w.x * av.x + w.y * av.y);
  if (lane == 0){ if (r < 128) u[rr] = s; else v[rr] = s; }
}

// ---------------- GAT softmax-aggregate -> Cb = conv + bc (bf16) ----------------
__global__ __launch_bounds__(256) void gat_k(const int* __restrict__ rp,
                                             const unsigned short* __restrict__ es,
                                             const float* __restrict__ als,
                                             const float* __restrict__ ald,
                                             const unsigned int* __restrict__ A,
                                             const float* __restrict__ bc,
                                             unsigned int* __restrict__ Cb){
  int lane = threadIdx.x & 63;
  int n = blockIdx.x * 4 + (threadIdx.x >> 6);
  if (n >= NNODE) return;
  int start = rp[n], end = rp[n + 1];
  int deg = end - start;
  float ad = ald[n];
  float2 acc = make_float2(0.f, 0.f);
  float rinv = 0.f;

  if (deg <= 64){
    int s = 0; float z = -3.0e38f;
    if (lane < deg){
      s = es[start + lane];
      float t = als[s] + ad;
      z = t > 0.f ? t : NEG * t;
    }
    float m = wmax(z);
    float e = (lane < deg) ? __expf(z - m) : 0.f;
    float denom = wsum(e);
    rinv = (deg > 0) ? 1.f / denom : 0.f;
    int dq = (deg + 7) & ~7;                  // pad loads hit row 0, weight 0
    for (int j = 0; j < dq; j += 8){
      int   s0 = __shfl(s, j),     s1 = __shfl(s, j + 1);
      int   s2 = __shfl(s, j + 2), s3 = __shfl(s, j + 3);
      int   s4 = __shfl(s, j + 4), s5 = __shfl(s, j + 5);
      int   s6 = __shfl(s, j + 6), s7 = __shfl(s, j + 7);
      float w0 = __shfl(e, j),     w1 = __shfl(e, j + 1);
      float w2 = __shfl(e, j + 2), w3 = __shfl(e, j + 3);
      float w4 = __shfl(e, j + 4), w5 = __shfl(e, j + 5);
      float w6 = __shfl(e, j + 6), w7 = __shfl(e, j + 7);
      unsigned p0 = A[(size_t)s0 * 64 + lane];
      unsigned p1 = A[(size_t)s1 * 64 + lane];
      unsigned p2 = A[(size_t)s2 * 64 + lane];
      unsigned p3 = A[(size_t)s3 * 64 + lane];
      unsigned p4 = A[(size_t)s4 * 64 + lane];
      unsigned p5 = A[(size_t)s5 * 64 + lane];
      unsigned p6 = A[(size_t)s6 * 64 + lane];
      unsigned p7 = A[(size_t)s7 * 64 + lane];
      acc.x = fmaf(w0, bflo(p0), acc.x); acc.y = fmaf(w0, bfhi(p0), acc.y);
      acc.x = fmaf(w1, bflo(p1), acc.x); acc.y = fmaf(w1, bfhi(p1), acc.y);
      acc.x = fmaf(w2, bflo(p2), acc.x); acc.y = fmaf(w2, bfhi(p2), acc.y);
      acc.x = fmaf(w3, bflo(p3), acc.x); acc.y = fmaf(w3, bfhi(p3), acc.y);
      acc.x = fmaf(w4, bflo(p4), acc.x); acc.y = fmaf(w4, bfhi(p4), acc.y);
      acc.x = fmaf(w5, bflo(p5), acc.x); acc.y = fmaf(w5, bfhi(p5), acc.y);
      acc.x = fmaf(w6, bflo(p6), acc.x); acc.y = fmaf(w6, bfhi(p6), acc.y);
      acc.x = fmaf(w7, bflo(p7), acc.x); acc.y = fmaf(w7, bfhi(p7), acc.y);
    }
  } else {
    float mloc = -3.0e38f;
    for (int i = start + lane; i < end; i += 64){
      int s = es[i];
      float zz = als[s] + ad;
      zz = zz > 0.f ? zz : NEG * zz;
      mloc = fmaxf(mloc, zz);
    }
    float m = wmax(mloc);
    float dloc = 0.f;
    for (int i = start + lane; i < end; i += 64){
      int s = es[i];
      float zz = als[s] + ad;
      zz = zz > 0.f ? zz : NEG * zz;
      dloc += __expf(zz - m);
    }
    rinv = 1.f / wsum(dloc);
    for (int i = start; i < end; ++i){
      int s = es[i];
      float zz = als[s] + ad;
      zz = zz > 0.f ? zz : NEG * zz;
      float w = __expf(zz - m);
      unsigned p = A[(size_t)s * 64 + lane];
      acc.x = fmaf(w, bflo(p), acc.x);
      acc.y = fmaf(w, bfhi(p), acc.y);
    }
  }

  int c = lane * 2;
  float cx = fmaf(acc.x, rinv, bc[c]);
  float cy = fmaf(acc.y, rinv, bc[c + 1]);
  Cb[(size_t)n * 64 + lane] = (unsigned)f2bf(cx) | ((unsigned)f2bf(cy) << 16);
}

extern "C" void kernel_launch(void* const* d_in, const int* in_sizes, int n_in,
                              void* d_out, int out_size, void* d_ws, size_t ws_size,
                              hipStream_t stream){
  const float* x   = (const float*)d_in[0];
  const int*   ei  = (const int*)d_in[1];
  const float* w0s = (const float*)d_in[2];
  const float* w0d = (const float*)d_in[3];
  const float* a0s = (const float*)d_in[4];
  const float* a0d = (const float*)d_in[5];
  const float* bc0 = (const float*)d_in[6];
  const float* wl0 = (const float*)d_in[7];
  const float* bl0 = (const float*)d_in[8];
  const float* w1  = (const float*)d_in[9];
  const float* a1s = (const float*)d_in[10];
  const float* a1d = (const float*)d_in[11];
  const float* bc1 = (const float*)d_in[12];
  const float* wl1 = (const float*)d_in[13];
  const float* bl1 = (const float*)d_in[14];
  const float* w2  = (const float*)d_in[15];
  const float* a2s = (const float*)d_in[16];
  const float* a2d = (const float*)d_in[17];
  const float* bc2 = (const float*)d_in[18];
  const float* wl2 = (const float*)d_in[19];
  const float* bl2 = (const float*)d_in[20];
  const float* wh  = (const float*)d_in[21];
  const float* bh  = (const float*)d_in[22];
  float* out = (float*)d_out;

  unsigned int* Ab = (unsigned int*)d_ws;                        // [N,128] bf16
  float* LA   = (float*)(Ab + (size_t)NNODE * 64);               // [N,128] f32
  float* LB   = LA + (size_t)NNODE * DIM;                        // [N,128] f32
  unsigned int* Cb = (unsigned int*)(LB + (size_t)NNODE * DIM);  // [N,128] bf16
  unsigned int* Xb = Cb + (size_t)NNODE * 64;                    // [N,128] bf16
  float* als  = (float*)(Xb + (size_t)NNODE * 64);
  float* ald  = als + NNODE;
  float* u    = ald + NNODE;
  float* v    = u + DIM;
  unsigned short* Wz = (unsigned short*)(v + DIM);               // 3 * 32768 bf16
  int*   rp   = (int*)(Wz + 3 * 32768);     // NNODE+1
  int*   cnt   = rp + (NNODE + 1);          // NBUCK*NB1
  int*   cbase = cnt + NBUCK * NB1;         // NBUCK*NB1
  int*   btot  = cbase + NBUCK * NB1;       // NBUCK
  int*   gbase = btot + NBUCK;              // NBUCK+1
  unsigned int* packed = (unsigned int*)(gbase + (NBUCK + 1));   // NEDGE
  unsigned short* es   = (unsigned short*)(packed + NEDGE);      // NEDGE

  // ---- CSR by dst: radix-style, zero global atomics ----
  bhist2_k<<<NB1, 256, 0, stream>>>(ei + NEDGE, cnt);
  scan196_k<<<NBUCK, 256, 0, stream>>>(cnt, cbase, btot);
  bscan2_k<<<1, 256, 0, stream>>>(btot, gbase, rp);
  scat2_k<<<NB1, 256, 0, stream>>>(ei, gbase, cbase, packed);
  build_k<<<NBUCK, 256, 0, stream>>>(gbase, packed, rp, es);

  dim3 b(256);
  dim3 gn((NNODE + 3) / 4);

  // ---- prep ----
  prep3_k<<<48, b, 0, stream>>>(w0s, wl0, w1, wl1, w2, wl2, Wz);
  mv2_k<<<64, 256, 0, stream>>>(w0s, a0s, w0d, a0d, u, v);
  cvtdual_k<<<gn, b, 0, stream>>>(x, u, v, Xb, als, ald);        // Xb + layer-0 logits

  // ---- layer 0 ----
  mfma_k<0,0><<<GBLK, b, 0, stream>>>((const unsigned short*)Xb, nullptr, nullptr,
                                      Wz, bl0, nullptr, nullptr,
                                      (unsigned short*)Ab, LA, nullptr, nullptr);
  gat_k<<<gn, b, 0, stream>>>(rp, es, als, ald, Ab, bc0, Cb);

  // ---- layer 1: h1 = relu(Cb + LA) fused; logits in epilogue ----
  mfma_k<1,1><<<GBLK, b, 0, stream>>>(nullptr, Cb, LA,
                                      Wz + 32768, bl1, a1s, a1d,
                                      (unsigned short*)Ab, LB, als, ald);
  gat_k<<<gn, b, 0, stream>>>(rp, es, als, ald, Ab, bc1, Cb);

  // ---- layer 2: h2 = relu(Cb + LB) fused ----
  mfma_k<1,1><<<GBLK, b, 0, stream>>>(nullptr, Cb, LB,
                                      Wz + 2 * 32768, bl2, a2s, a2d,
                                      (unsigned short*)Ab, LA, als, ald);
  gat_k<<<gn, b, 0, stream>>>(rp, es, als, ald, Ab, bc2, Cb);

  // ---- head: h3 = Cb + LA (no relu) ----
  head_k<<<dim3((NNODE + 63) / 64), b, 0, stream>>>(Cb, LA, wh, bh, out);
}

// Round 11
// 330.499 us; speedup vs baseline: 2.8216x; 1.0491x over previous
//
#include <hip/hip_runtime.h>

#define NNODE 50000
#define NEDGE 800000
#define DIM   128
#define NEG   0.2f
#define NBUCK 196
#define EPB1  2048
#define NB1   391
#define GBLK  782          // ceil(NNODE/64)

typedef __attribute__((ext_vector_type(8))) short bf16x8;
typedef __attribute__((ext_vector_type(4))) float f32x4;

__device__ __forceinline__ float wmax(float v){
  #pragma unroll
  for (int m = 32; m > 0; m >>= 1) v = fmaxf(v, __shfl_xor(v, m));
  return v;
}
__device__ __forceinline__ float wsum(float v){
  #pragma unroll
  for (int m = 32; m > 0; m >>= 1) v += __shfl_xor(v, m);
  return v;
}
__device__ __forceinline__ unsigned short f2bf(float f){
  unsigned int x = __float_as_uint(f);
  return (unsigned short)((x + 0x7fffu + ((x >> 16) & 1u)) >> 16);
}
__device__ __forceinline__ float bflo(unsigned u){ return __uint_as_float(u << 16); }
__device__ __forceinline__ float bfhi(unsigned u){ return __uint_as_float(u & 0xffff0000u); }

// ---------------- CSR build: radix-style, NO global atomics ----------------
__global__ __launch_bounds__(256) void bhist2_k(const int* __restrict__ dst,
                                                int* __restrict__ cnt){
  __shared__ int h[NBUCK];
  for (int i = threadIdx.x; i < NBUCK; i += 256) h[i] = 0;
  __syncthreads();
  int e0 = blockIdx.x * EPB1 + threadIdx.x;
  #pragma unroll
  for (int i = 0; i < 8; ++i){
    int e = e0 + i * 256;
    if (e < NEDGE) atomicAdd(&h[dst[e] >> 8], 1);
  }
  __syncthreads();
  for (int i = threadIdx.x; i < NBUCK; i += 256)
    cnt[i * NB1 + blockIdx.x] = h[i];
}

__global__ __launch_bounds__(256) void scan196_k(const int* __restrict__ cnt,
                                                 int* __restrict__ cbase,
                                                 int* __restrict__ btot){
  __shared__ int sd[256];
  int b = blockIdx.x, t = threadIdx.x;
  const int* row = cnt + (size_t)b * NB1;
  int i0 = t * 2, i1 = t * 2 + 1;
  int v0 = (i0 < NB1) ? row[i0] : 0;
  int v1 = (i1 < NB1) ? row[i1] : 0;
  int s = v0 + v1;
  sd[t] = s; __syncthreads();
  #pragma unroll
  for (int off = 1; off < 256; off <<= 1){
    int u = (t >= off) ? sd[t - off] : 0;
    __syncthreads();
    sd[t] += u;
    __syncthreads();
  }
  int ex = sd[t] - s;
  if (i0 < NB1) cbase[(size_t)b * NB1 + i0] = ex;
  if (i1 < NB1) cbase[(size_t)b * NB1 + i1] = ex + v0;
  if (t == 255) btot[b] = sd[255];
}

__global__ __launch_bounds__(256) void bscan2_k(const int* __restrict__ btot,
                                                int* __restrict__ gbase,
                                                int* __restrict__ rp){
  __shared__ int sd[256];
  int t = threadIdx.x;
  int v = (t < NBUCK) ? btot[t] : 0;
  sd[t] = v; __syncthreads();
  #pragma unroll
  for (int off = 1; off < 256; off <<= 1){
    int u = (t >= off) ? sd[t - off] : 0;
    __syncthreads();
    sd[t] += u;
    __syncthreads();
  }
  if (t < NBUCK) gbase[t] = sd[t] - v;
  if (t == NBUCK - 1) gbase[NBUCK] = sd[t];
  if (t == 0) rp[NNODE] = NEDGE;
}

__global__ __launch_bounds__(256) void scat2_k(const int* __restrict__ ei,
                                               const int* __restrict__ gbase,
                                               const int* __restrict__ cbase,
                                               unsigned int* __restrict__ packed){
  __shared__ int lcur[NBUCK];
  for (int i = threadIdx.x; i < NBUCK; i += 256) lcur[i] = 0;
  __syncthreads();
  int e0 = blockIdx.x * EPB1 + threadIdx.x;
  #pragma unroll
  for (int i = 0; i < 8; ++i){
    int e = e0 + i * 256;
    if (e < NEDGE){
      int s = ei[e], d = ei[NEDGE + e];
      int b = d >> 8;
      int r = atomicAdd(&lcur[b], 1);
      int pos = gbase[b] + cbase[(size_t)b * NB1 + blockIdx.x] + r;
      packed[pos] = ((unsigned)d << 16) | (unsigned)s;
    }
  }
}

__global__ __launch_bounds__(256) void build_k(const int* __restrict__ gbase,
                                               const unsigned int* __restrict__ packed,
                                               int* __restrict__ rp,
                                               unsigned short* __restrict__ es){
  __shared__ int h[256], sd[256], cur[256];
  int b = blockIdx.x, t = threadIdx.x;
  int s0 = gbase[b], s1 = gbase[b + 1];
  h[t] = 0; __syncthreads();
  for (int i = s0 + t; i < s1; i += 256)
    atomicAdd(&h[(packed[i] >> 16) & 255], 1);
  __syncthreads();
  int v = h[t]; sd[t] = v; __syncthreads();
  #pragma unroll
  for (int off = 1; off < 256; off <<= 1){
    int u = (t >= off) ? sd[t - off] : 0;
    __syncthreads();
    sd[t] += u;
    __syncthreads();
  }
  int ex = sd[t] - v;
  cur[t] = ex;
  int d = b * 256 + t;
  if (d < NNODE) rp[d] = s0 + ex;
  __syncthreads();
  for (int i = s0 + t; i < s1; i += 256){
    unsigned int p = packed[i];
    int ld = (p >> 16) & 255;
    int pos = atomicAdd(&cur[ld], 1);
    es[s0 + pos] = (unsigned short)(p & 0xffffu);
  }
}

// ------- prepA: swizzle Wf1=[w0s;wl0], Wf2=[w1;wl1] (256x128) -> B-frag bf16 -------
// layout: Wz[((ct*8+q)*64+lane)*8 + j], k = q*32 + (lane>>4)*8 + j, c = ct*16 + (lane&15)
__global__ __launch_bounds__(256) void prepA_k(const float* __restrict__ w0s,
                                               const float* __restrict__ wl0,
                                               const float* __restrict__ w1,
                                               const float* __restrict__ wl1,
                                               unsigned short* __restrict__ Wz1,
                                               unsigned short* __restrict__ Wz2){
  int g = blockIdx.x * 256 + threadIdx.x;    // 0..8191
  int layer = g >> 12;
  int rem = g & 4095;
  int ct = rem >> 9, q = (rem >> 6) & 7, lane = rem & 63;
  int quad = lane >> 4;
  int c = ct * 16 + (lane & 15);
  const float* wA = layer ? w1 : w0s;
  const float* wB = layer ? wl1 : wl0;
  unsigned short* dst = (layer ? Wz2 : Wz1) + ((size_t)(ct * 8 + q) * 64 + lane) * 8;
  #pragma unroll
  for (int j = 0; j < 8; ++j){
    int k = q * 32 + quad * 8 + j;
    float v = (k < 128) ? wA[k * 128 + c] : wB[(k - 128) * 128 + c];
    dst[j] = f2bf(v);
  }
}

// ------- prepH: Wf3 = [w2;wl2]@wh (256x64) swizzled bf16; block 8: bf3 -------
__global__ __launch_bounds__(256) void prepH_k(const float* __restrict__ w2,
                                               const float* __restrict__ wl2,
                                               const float* __restrict__ wh,
                                               const float* __restrict__ bc2,
                                               const float* __restrict__ bl2,
                                               const float* __restrict__ bh,
                                               unsigned short* __restrict__ Wz3,
                                               float* __restrict__ bf3){
  if (blockIdx.x == 8){
    int c = threadIdx.x;
    if (c < 64){
      float s = bh[c];
      for (int t = 0; t < 128; ++t) s += (bc2[t] + bl2[t]) * wh[t * 64 + c];
      bf3[c] = s;
    }
    return;
  }
  int g = blockIdx.x * 256 + threadIdx.x;    // 0..2047
  int ct = g >> 9, q = (g >> 6) & 7, lane = g & 63;
  int quad = lane >> 4;
  int c = ct * 16 + (lane & 15);             // < 64
  unsigned short* dst = Wz3 + ((size_t)(ct * 8 + q) * 64 + lane) * 8;
  #pragma unroll
  for (int j = 0; j < 8; ++j){
    int k = q * 32 + quad * 8 + j;
    const float* src = (k < 128) ? (w2 + k * 128) : (wl2 + (k - 128) * 128);
    float s = 0.f;
    for (int t = 0; t < 128; ++t) s += src[t] * wh[t * 64 + c];
    dst[j] = f2bf(s);
  }
}

// ------- mv6 + fused biases: u = W@a for 6 (W,a) pairs; blocks 192: bf1,bf2 -------
__global__ void mv6_k(const float* __restrict__ w0s, const float* __restrict__ a0s,
                      const float* __restrict__ w0d, const float* __restrict__ a0d,
                      const float* __restrict__ w1,  const float* __restrict__ a1s,
                      const float* __restrict__ a1d,
                      const float* __restrict__ w2,  const float* __restrict__ a2s,
                      const float* __restrict__ a2d,
                      const float* __restrict__ bc0, const float* __restrict__ bl0,
                      const float* __restrict__ bc1, const float* __restrict__ bl1,
                      float* __restrict__ uv,        // 6*128: u0 v0 u1 v1 u2 v2
                      float* __restrict__ bf1, float* __restrict__ bf2){
  if (blockIdx.x == 192){
    int t = threadIdx.x;
    if (t < 128) bf1[t] = bc0[t] + bl0[t];
    else bf2[t - 128] = bc1[t - 128] + bl1[t - 128];
    return;
  }
  int lane = threadIdx.x & 63;
  int idx = blockIdx.x * 4 + (threadIdx.x >> 6);   // 0..767
  int grp = idx >> 7, r = idx & 127;
  const float* W; const float* a;
  switch (grp){
    case 0: W = w0s; a = a0s; break;
    case 1: W = w0d; a = a0d; break;
    case 2: W = w1;  a = a1s; break;
    case 3: W = w1;  a = a1d; break;
    case 4: W = w2;  a = a2s; break;
    default: W = w2; a = a2d; break;
  }
  float2 w = ((const float2*)(W + r * DIM))[lane];
  float2 av = ((const float2*)a)[lane];
  float s = wsum(w.x * av.x + w.y * av.y);
  if (lane == 0) uv[grp * 128 + r] = s;
}

// ------- cvt + layer-0 logits: Xb = bf16(x); als/ald = x@u0, x@v0 -------
__global__ __launch_bounds__(256) void cvtdual_k(const float* __restrict__ X,
                                                 const float* __restrict__ uv,
                                                 unsigned int* __restrict__ Xb,
                                                 float* __restrict__ als,
                                                 float* __restrict__ ald){
  int lane = threadIdx.x & 63;
  int n = blockIdx.x * 4 + (threadIdx.x >> 6);
  if (n >= NNODE) return;
  float2 xv = ((const float2*)(X + (size_t)n * DIM))[lane];
  Xb[(size_t)n * 64 + lane] = (unsigned)f2bf(xv.x) | ((unsigned)f2bf(xv.y) << 16);
  float2 uu = ((const float2*)uv)[lane];
  float2 vv = ((const float2*)(uv + 128))[lane];
  float s1 = wsum(xv.x * uu.x + xv.y * uu.y);
  float s2 = wsum(xv.x * vv.x + xv.y * vv.y);
  if (lane == 0){ als[n] = s1; ald[n] = s2; }
}

// ---------------- GAT: Mb[n] = sum_e alpha * Hsrc[s]  (bf16 in/out, no bias) ----------------
__global__ __launch_bounds__(256) void gat_k(const int* __restrict__ rp,
                                             const unsigned short* __restrict__ es,
                                             const float* __restrict__ als,
                                             const float* __restrict__ ald,
                                             const unsigned int* __restrict__ A,
                                             unsigned int* __restrict__ Mb){
  int lane = threadIdx.x & 63;
  int n = blockIdx.x * 4 + (threadIdx.x >> 6);
  if (n >= NNODE) return;
  int start = rp[n], end = rp[n + 1];
  int deg = end - start;
  float ad = ald[n];
  float2 acc = make_float2(0.f, 0.f);
  float rinv = 0.f;

  if (deg <= 64){
    int s = 0; float z = -3.0e38f;
    if (lane < deg){
      s = es[start + lane];
      float t = als[s] + ad;
      z = t > 0.f ? t : NEG * t;
    }
    float m = wmax(z);
    float e = (lane < deg) ? __expf(z - m) : 0.f;
    float denom = wsum(e);
    rinv = (deg > 0) ? 1.f / denom : 0.f;
    int dq = (deg + 7) & ~7;
    for (int j = 0; j < dq; j += 8){
      int   s0 = __shfl(s, j),     s1 = __shfl(s, j + 1);
      int   s2 = __shfl(s, j + 2), s3 = __shfl(s, j + 3);
      int   s4 = __shfl(s, j + 4), s5 = __shfl(s, j + 5);
      int   s6 = __shfl(s, j + 6), s7 = __shfl(s, j + 7);
      float w0 = __shfl(e, j),     w1 = __shfl(e, j + 1);
      float w2 = __shfl(e, j + 2), w3 = __shfl(e, j + 3);
      float w4 = __shfl(e, j + 4), w5 = __shfl(e, j + 5);
      float w6 = __shfl(e, j + 6), w7 = __shfl(e, j + 7);
      unsigned p0 = A[(size_t)s0 * 64 + lane];
      unsigned p1 = A[(size_t)s1 * 64 + lane];
      unsigned p2 = A[(size_t)s2 * 64 + lane];
      unsigned p3 = A[(size_t)s3 * 64 + lane];
      unsigned p4 = A[(size_t)s4 * 64 + lane];
      unsigned p5 = A[(size_t)s5 * 64 + lane];
      unsigned p6 = A[(size_t)s6 * 64 + lane];
      unsigned p7 = A[(size_t)s7 * 64 + lane];
      acc.x = fmaf(w0, bflo(p0), acc.x); acc.y = fmaf(w0, bfhi(p0), acc.y);
      acc.x = fmaf(w1, bflo(p1), acc.x); acc.y = fmaf(w1, bfhi(p1), acc.y);
      acc.x = fmaf(w2, bflo(p2), acc.x); acc.y = fmaf(w2, bfhi(p2), acc.y);
      acc.x = fmaf(w3, bflo(p3), acc.x); acc.y = fmaf(w3, bfhi(p3), acc.y);
      acc.x = fmaf(w4, bflo(p4), acc.x); acc.y = fmaf(w4, bfhi(p4), acc.y);
      acc.x = fmaf(w5, bflo(p5), acc.x); acc.y = fmaf(w5, bfhi(p5), acc.y);
      acc.x = fmaf(w6, bflo(p6), acc.x); acc.y = fmaf(w6, bfhi(p6), acc.y);
      acc.x = fmaf(w7, bflo(p7), acc.x); acc.y = fmaf(w7, bfhi(p7), acc.y);
    }
  } else {
    float mloc = -3.0e38f;
    for (int i = start + lane; i < end; i += 64){
      int s = es[i];
      float zz = als[s] + ad;
      zz = zz > 0.f ? zz : NEG * zz;
      mloc = fmaxf(mloc, zz);
    }
    float m = wmax(mloc);
    float dloc = 0.f;
    for (int i = start + lane; i < end; i += 64){
      int s = es[i];
      float zz = als[s] + ad;
      zz = zz > 0.f ? zz : NEG * zz;
      dloc += __expf(zz - m);
    }
    rinv = 1.f / wsum(dloc);
    for (int i = start; i < end; ++i){
      int s = es[i];
      float zz = als[s] + ad;
      zz = zz > 0.f ? zz : NEG * zz;
      float w = __expf(zz - m);
      unsigned p = A[(size_t)s * 64 + lane];
      acc.x = fmaf(w, bflo(p), acc.x);
      acc.y = fmaf(w, bfhi(p), acc.y);
    }
  }

  Mb[(size_t)n * 64 + lane] =
      (unsigned)f2bf(acc.x * rinv) | ((unsigned)f2bf(acc.y * rinv) << 16);
}

// ------- K=256 fused MFMA: out = [Mb | Hin] @ Wz + bias ------------------
// FINAL=0: h = relu(.), store bf16 to Hout (128 cols), logits via u/v.
// FINAL=1: store f32 to outf (64 cols), no relu.
template<int FINAL>
__global__ __launch_bounds__(256) void mfma_k(const unsigned int* __restrict__ Mb,
                                              const unsigned int* __restrict__ Hin,
                                              const unsigned short* __restrict__ Wz,
                                              const float* __restrict__ bias,
                                              const float* __restrict__ u,
                                              const float* __restrict__ v,
                                              unsigned short* __restrict__ Hout,
                                              float* __restrict__ outf,
                                              float* __restrict__ als,
                                              float* __restrict__ ald){
  int lane = threadIdx.x & 63;
  int wid  = threadIdx.x >> 6;
  int r0   = blockIdx.x * 64 + wid * 16;
  int quad = lane >> 4;
  int col  = lane & 15;

  int rA = r0 + col; if (rA > NNODE - 1) rA = NNODE - 1;
  const bf16x8* mrow = (const bf16x8*)(Mb + (size_t)rA * 64);
  const bf16x8* hrow = (const bf16x8*)(Hin + (size_t)rA * 64);
  bf16x8 a[8];
  #pragma unroll
  for (int q = 0; q < 4; ++q){
    a[q]     = mrow[q * 4 + quad];
    a[q + 4] = hrow[q * 4 + quad];
  }

  const bf16x8* wz = (const bf16x8*)Wz;
  int rowq = r0 + quad * 4;
  float alsp[4] = {0.f, 0.f, 0.f, 0.f};
  float aldp[4] = {0.f, 0.f, 0.f, 0.f};
  const int NCT = FINAL ? 4 : 8;

  #pragma unroll
  for (int ct = 0; ct < NCT; ++ct){
    f32x4 acc = {0.f, 0.f, 0.f, 0.f};
    #pragma unroll
    for (int q = 0; q < 8; ++q){
      bf16x8 bfr = wz[(ct * 8 + q) * 64 + lane];
      acc = __builtin_amdgcn_mfma_f32_16x16x32_bf16(a[q], bfr, acc, 0, 0, 0);
    }
    int c = ct * 16 + col;
    float bb = bias[c];
    if (FINAL){
      #pragma unroll
      for (int r = 0; r < 4; ++r){
        int row = rowq + r;
        if (row < NNODE) outf[(size_t)row * 64 + c] = acc[r] + bb;
      }
    } else {
      float uc = u[c], vc = v[c];
      #pragma unroll
      for (int r = 0; r < 4; ++r){
        float h = fmaxf(acc[r] + bb, 0.f);
        alsp[r] = fmaf(h, uc, alsp[r]);
        aldp[r] = fmaf(h, vc, aldp[r]);
        int row = rowq + r;
        if (row < NNODE) Hout[(size_t)row * 128 + c] = f2bf(h);
      }
    }
  }

  if (!FINAL){
    #pragma unroll
    for (int m = 1; m < 16; m <<= 1){
      #pragma unroll
      for (int r = 0; r < 4; ++r){
        alsp[r] += __shfl_xor(alsp[r], m);
        aldp[r] += __shfl_xor(aldp[r], m);
      }
    }
    if (col == 0){
      #pragma unroll
      for (int r = 0; r < 4; ++r){
        int row = rowq + r;
        if (row < NNODE){ als[row] = alsp[r]; ald[row] = aldp[r]; }
      }
    }
  }
}

extern "C" void kernel_launch(void* const* d_in, const int* in_sizes, int n_in,
                              void* d_out, int out_size, void* d_ws, size_t ws_size,
                              hipStream_t stream){
  const float* x   = (const float*)d_in[0];
  const int*   ei  = (const int*)d_in[1];
  const float* w0s = (const float*)d_in[2];
  const float* w0d = (const float*)d_in[3];
  const float* a0s = (const float*)d_in[4];
  const float* a0d = (const float*)d_in[5];
  const float* bc0 = (const float*)d_in[6];
  const float* wl0 = (const float*)d_in[7];
  const float* bl0 = (const float*)d_in[8];
  const float* w1  = (const float*)d_in[9];
  const float* a1s = (const float*)d_in[10];
  const float* a1d = (const float*)d_in[11];
  const float* bc1 = (const float*)d_in[12];
  const float* wl1 = (const float*)d_in[13];
  const float* bl1 = (const float*)d_in[14];
  const float* w2  = (const float*)d_in[15];
  const float* a2s = (const float*)d_in[16];
  const float* a2d = (const float*)d_in[17];
  const float* bc2 = (const float*)d_in[18];
  const float* wl2 = (const float*)d_in[19];
  const float* bl2 = (const float*)d_in[20];
  const float* wh  = (const float*)d_in[21];
  const float* bh  = (const float*)d_in[22];
  float* out = (float*)d_out;

  unsigned int* Mb = (unsigned int*)d_ws;                        // [N,128] bf16
  unsigned int* Xb = Mb + (size_t)NNODE * 64;                    // [N,128] bf16
  unsigned int* Ha = Xb + (size_t)NNODE * 64;                    // [N,128] bf16
  unsigned int* Hb = Ha + (size_t)NNODE * 64;                    // [N,128] bf16
  float* als  = (float*)(Hb + (size_t)NNODE * 64);
  float* ald  = als + NNODE;
  float* uv   = ald + NNODE;                 // 6*128
  float* bf1  = uv + 6 * 128;                // 128
  float* bf2  = bf1 + 128;                   // 128
  float* bf3  = bf2 + 128;                   // 64
  unsigned short* Wz1 = (unsigned short*)(bf3 + 64);             // 256*128
  unsigned short* Wz2 = Wz1 + 256 * 128;                         // 256*128
  unsigned short* Wz3 = Wz2 + 256 * 128;                         // 256*64
  int*   rp    = (int*)(Wz3 + 256 * 64);     // NNODE+1
  int*   cnt   = rp + (NNODE + 1);           // NBUCK*NB1
  int*   cbase = cnt + NBUCK * NB1;          // NBUCK*NB1
  int*   btot  = cbase + NBUCK * NB1;        // NBUCK
  int*   gbase = btot + NBUCK;               // NBUCK+1
  unsigned int* packed = (unsigned int*)(gbase + (NBUCK + 1));   // NEDGE
  unsigned short* es   = (unsigned short*)(packed + NEDGE);      // NEDGE

  // ---- CSR by dst: radix-style, zero global atomics ----
  bhist2_k<<<NB1, 256, 0, stream>>>(ei + NEDGE, cnt);
  scan196_k<<<NBUCK, 256, 0, stream>>>(cnt, cbase, btot);
  bscan2_k<<<1, 256, 0, stream>>>(btot, gbase, rp);
  scat2_k<<<NB1, 256, 0, stream>>>(ei, gbase, cbase, packed);
  build_k<<<NBUCK, 256, 0, stream>>>(gbase, packed, rp, es);

  dim3 b(256);
  dim3 gn((NNODE + 3) / 4);

  // ---- prep: fused weights, logit vectors, fused biases ----
  prepA_k<<<32, b, 0, stream>>>(w0s, wl0, w1, wl1, Wz1, Wz2);
  prepH_k<<<9, b, 0, stream>>>(w2, wl2, wh, bc2, bl2, bh, Wz3, bf3);
  mv6_k<<<193, b, 0, stream>>>(w0s, a0s, w0d, a0d, w1, a1s, a1d, w2, a2s, a2d,
                               bc0, bl0, bc1, bl1, uv, bf1, bf2);
  cvtdual_k<<<gn, b, 0, stream>>>(x, uv, Xb, als, ald);

  // ---- layer 0: gather x -> M0; h1 = relu([M0|x]@Wf1 + bf1); logits1 ----
  gat_k<<<gn, b, 0, stream>>>(rp, es, als, ald, Xb, Mb);
  mfma_k<0><<<GBLK, b, 0, stream>>>(Mb, Xb, Wz1, bf1, uv + 2 * 128, uv + 3 * 128,
                                    (unsigned short*)Ha, nullptr, als, ald);

  // ---- layer 1: gather h1 -> M1; h2 = relu([M1|h1]@Wf2 + bf2); logits2 ----
  gat_k<<<gn, b, 0, stream>>>(rp, es, als, ald, Ha, Mb);
  mfma_k<0><<<GBLK, b, 0, stream>>>(Mb, Ha, Wz2, bf2, uv + 4 * 128, uv + 5 * 128,
                                    (unsigned short*)Hb, nullptr, als, ald);

  // ---- layer 2 + head: gather h2 -> M2; out = [M2|h2]@Wf3 + bf3 ----
  gat_k<<<gn, b, 0, stream>>>(rp, es, als, ald, Hb, Mb);
  mfma_k<1><<<GBLK, b, 0, stream>>>(Mb, Hb, Wz3, bf3, nullptr, nullptr,
                                    nullptr, out, nullptr, nullptr);
}